// Round 8
// baseline (3738.948 us; speedup 1.0000x reference)
//
#include <hip/hip_runtime.h>
#include <hip/hip_bf16.h>
#include <math.h>

// B=32, T=256, D=1024, A=64, H=512, NA=20
#define DEV __device__ __forceinline__

typedef __bf16 bf16_t;
typedef bf16_t bf16x8 __attribute__((ext_vector_type(8)));
typedef float f32x4 __attribute__((ext_vector_type(4)));
typedef int i32x4 __attribute__((ext_vector_type(4)));

DEV void async16(const void* g, void* l) {
  __builtin_amdgcn_global_load_lds((const __attribute__((address_space(1))) void*)g,
                                   (__attribute__((address_space(3))) void*)l, 16, 0, 0);
}
DEV float sigmoidf_(float x) { return 1.f / (1.f + expf(-x)); }
DEV bf16x8 as_bf(i32x4 v) { union { i32x4 i; bf16x8 b; } u; u.i = v; return u.b; }

// ---- fine-grained device-coherent ops (bypass L1+L2, hit Infinity Cache) ----
DEV unsigned flag_load(const unsigned* p) {
  unsigned v;
  asm volatile("global_load_dword %0, %1, off sc0 sc1\ns_waitcnt vmcnt(0)"
               : "=v"(v) : "v"(p) : "memory");
  return v;
}
DEV void store16_sys(void* p, i32x4 v) {
  asm volatile("global_store_dwordx4 %0, %1, off sc0 sc1" :: "v"(p), "v"(v) : "memory");
}

#define WAITV(N) do { asm volatile("s_waitcnt vmcnt(" #N ")" ::: "memory"); \
                      __builtin_amdgcn_sched_barrier(0); } while (0)

template<int KB>
DEV void loads8(i32x4* dst, const __hip_bfloat16* arow) {
#pragma unroll
  for (int i = 0; i < 8; ++i)
    asm volatile("global_load_dwordx4 %0, %1, off offset:%2 sc0 sc1"
                 : "=v"(dst[i]) : "v"(arow), "i"((KB + i) * 64));
}
DEV void loads8rt(i32x4* dst, const __hip_bfloat16* arow, int kbase) {
#pragma unroll
  for (int i = 0; i < 8; ++i)
    asm volatile("global_load_dwordx4 %0, %1, off sc0 sc1"
                 : "=v"(dst[i]) : "v"(arow + (size_t)(kbase + i) * 32) : "memory");
}

template<int C>
DEV void ldsb8(bf16x8* b0, bf16x8* b1, const __hip_bfloat16* Wl,
               int sw, int kof, int r0, int r1) {
#pragma unroll
  for (int i = 0; i < 8; ++i) {
    const int kk = (C * 8 + i) * 32 + kof;
    b0[i] = *(const bf16x8*)&Wl[r0 * 1024 + (kk ^ sw)];
    b1[i] = *(const bf16x8*)&Wl[r1 * 1024 + (kk ^ sw)];
  }
}
DEV void mfma8x(const i32x4* a, const bf16x8* b0, const bf16x8* b1,
                f32x4& acc0, f32x4& acc1) {
#pragma unroll
  for (int i = 0; i < 8; ++i) {
    bf16x8 av = as_bf(a[i]);
    acc0 = __builtin_amdgcn_mfma_f32_16x16x32_bf16(av, b0[i], acc0, 0, 0, 0);
    acc1 = __builtin_amdgcn_mfma_f32_16x16x32_bf16(av, b1[i], acc1, 0, 0, 0);
  }
}

// K=1024 recurrent GEMM: A (h-state, bypass loads, all issued upfront) x W (LDS)
DEV void mfma_step(const __hip_bfloat16* Ap, const __hip_bfloat16* Wl,
                   int mh, int nh, int l, f32x4& acc0, f32x4& acc1) {
  const __hip_bfloat16* arow = Ap + (mh * 16 + (l & 15)) * 1024 + (l >> 4) * 8;
  const int sw = (l & 7) << 3, kof = (l >> 4) * 8;
  const int r0 = nh * 32 + (l & 15), r1 = r0 + 16;
  i32x4 A0[8], A1[8], A2[8], A3[8];
  bf16x8 Ba0[8], Ba1[8], Bb0[8], Bb1[8];
  loads8<0>(A0, arow);
  loads8<8>(A1, arow);
  loads8<16>(A2, arow);
  loads8<24>(A3, arow);
  ldsb8<0>(Ba0, Ba1, Wl, sw, kof, r0, r1);
  WAITV(24);
  mfma8x(A0, Ba0, Ba1, acc0, acc1);
  ldsb8<1>(Bb0, Bb1, Wl, sw, kof, r0, r1);
  WAITV(16);
  mfma8x(A1, Bb0, Bb1, acc0, acc1);
  ldsb8<2>(Ba0, Ba1, Wl, sw, kof, r0, r1);
  WAITV(8);
  mfma8x(A2, Ba0, Ba1, acc0, acc1);
  ldsb8<3>(Bb0, Bb1, Wl, sw, kof, r0, r1);
  WAITV(0);
  mfma8x(A3, Bb0, Bb1, acc0, acc1);
}

// final-phase pass: A bypass loads, W from global (cached)
DEV void mfma_pass_glb(const __hip_bfloat16* Ap, const __hip_bfloat16* __restrict__ Wg,
                       int d0, int mh, int nh, int l, f32x4& acc0, f32x4& acc1) {
  const __hip_bfloat16* arow = Ap + (mh * 16 + (l & 15)) * 1024 + (l >> 4) * 8;
  const size_t g0 = ((size_t)(2 * nh) * 1024 + d0 + (l & 15)) * 1024;
  const size_t g1 = g0 + 1048576;
  const int kof = (l >> 4) * 8;
  i32x4 A[8];
  for (int c = 0; c < 4; ++c) {
    loads8rt(A, arow, c * 8);
    WAITV(0);
#pragma unroll
    for (int i = 0; i < 8; ++i) {
      const int kk = (c * 8 + i) * 32 + kof;
      bf16x8 b0 = *(const bf16x8*)&Wg[g0 + kk];
      bf16x8 b1 = *(const bf16x8*)&Wg[g1 + kk];
      bf16x8 av = as_bf(A[i]);
      acc0 = __builtin_amdgcn_mfma_f32_16x16x32_bf16(av, b0, acc0, 0, 0, 0);
      acc1 = __builtin_amdgcn_mfma_f32_16x16x32_bf16(av, b1, acc1, 0, 0, 0);
    }
  }
}

// ---------------- generic bf16 MFMA GEMM: C[M,N] = A[M,K] @ Bw[N,K]^T + bias ----------------
// mode 0: outF = acc+bias (f32); mode 1: outBF = bf16(acc+bias)
// mode 2: outBF = bf16(sigmoid(acc+bias)*tanh(aux))
// mode 3: outBF is blk layout [slot][256 t][2048] chunk [g*512 + b*16 + dd]; rows must be t*32+b
__global__ __launch_bounds__(256) void gemm_bt_kernel(
    const __hip_bfloat16* __restrict__ A, const __hip_bfloat16* __restrict__ Bw,
    float* __restrict__ outF, __hip_bfloat16* __restrict__ outBF,
    const float* __restrict__ bias, const float* __restrict__ aux,
    int M, int N, int K, int remap, int mode)
{
  __shared__ __hip_bfloat16 As[128 * 64];
  __shared__ __hip_bfloat16 Bs[128 * 64];
  __shared__ __hip_bfloat16 Cs[128 * 128];   // mode-3 staging only
  const int tid = threadIdx.x;
  const int w = tid >> 6, l = tid & 63;
  const int m0 = blockIdx.x * 128, n0 = blockIdx.y * 128;
  const int wm = (w >> 1) * 64, wn = (w & 1) * 64;
  const int row_s = tid >> 3, kc = tid & 7;
  f32x4 acc[4][4] = {};
  for (int k0 = 0; k0 < K; k0 += 64) {
    const __hip_bfloat16* ga = A + (size_t)(m0 + row_s) * K + k0 + kc * 8;
    const __hip_bfloat16* gb = Bw + (size_t)(n0 + row_s) * K + k0 + kc * 8;
    __hip_bfloat16* la = As + w * 512;
    __hip_bfloat16* lb = Bs + w * 512;
#pragma unroll
    for (int p = 0; p < 4; ++p) {
      async16(ga + (size_t)p * 32 * K, la + p * 2048);
      async16(gb + (size_t)p * 32 * K, lb + p * 2048);
    }
    __syncthreads();
#pragma unroll
    for (int kb = 0; kb < 2; ++kb) {
      bf16x8 af[4], bfr[4];
#pragma unroll
      for (int i = 0; i < 4; ++i)
        af[i] = *(const bf16x8*)&As[(wm + i * 16 + (l & 15)) * 64 + kb * 32 + (l >> 4) * 8];
#pragma unroll
      for (int j = 0; j < 4; ++j)
        bfr[j] = *(const bf16x8*)&Bs[(wn + j * 16 + (l & 15)) * 64 + kb * 32 + (l >> 4) * 8];
#pragma unroll
      for (int i = 0; i < 4; ++i)
#pragma unroll
        for (int j = 0; j < 4; ++j)
          acc[i][j] = __builtin_amdgcn_mfma_f32_16x16x32_bf16(af[i], bfr[j], acc[i][j], 0, 0, 0);
    }
    __syncthreads();
  }
  if (mode == 3) {
#pragma unroll
    for (int i = 0; i < 4; ++i)
#pragma unroll
      for (int j = 0; j < 4; ++j) {
        const int ncol = n0 + wn + j * 16 + (l & 15);
        const float bv = bias[ncol];
#pragma unroll
        for (int r = 0; r < 4; ++r) {
          const int lr = wm + i * 16 + (l >> 4) * 4 + r;
          Cs[lr * 128 + wn + j * 16 + (l & 15)] = __float2bfloat16(acc[i][j][r] + bv);
        }
      }
    __syncthreads();
    const int t0 = m0 >> 5, g = n0 >> 10, slot0 = (n0 & 1023) >> 4;
    const int grp = tid >> 6, li = tid & 63;
    const int b = li >> 1, half = li & 1;
#pragma unroll
    for (int sl = 0; sl < 8; ++sl) {
      bf16x8 vv = *(const bf16x8*)&Cs[(grp * 32 + b) * 128 + sl * 16 + half * 8];
      *(bf16x8*)&outBF[(((size_t)(slot0 + sl)) * 256 + t0 + grp) * 2048 +
                       g * 512 + b * 16 + half * 8] = vv;
    }
    return;
  }
#pragma unroll
  for (int i = 0; i < 4; ++i) {
#pragma unroll
    for (int j = 0; j < 4; ++j) {
      const int ncol = n0 + wn + j * 16 + (l & 15);
      const float bv = bias ? bias[ncol] : 0.f;
#pragma unroll
      for (int r = 0; r < 4; ++r) {
        int m = m0 + wm + i * 16 + (l >> 4) * 4 + r;
        int row = remap ? (((m & 255) << 5) | (m >> 8)) : m;
        float v = acc[i][j][r] + bv;
        if (mode == 0) {
          outF[(size_t)row * N + ncol] = v;
        } else if (mode == 1) {
          outBF[(size_t)row * N + ncol] = __float2bfloat16(v);
        } else {
          float cv = aux[(size_t)row * N + ncol];
          outBF[(size_t)row * N + ncol] = __float2bfloat16(sigmoidf_(v) * tanhf(cv));
        }
      }
    }
  }
}

// cell [8192][1024] f32 (rows t*32+b) -> blk [64 slot][256 t][32 b][16 dd] bf16
__global__ __launch_bounds__(256) void cellblk_kernel(const float* __restrict__ cell,
                                                      __hip_bfloat16* __restrict__ blk)
{
  __shared__ __hip_bfloat16 ls[32 * 1024];   // 64 KB
  const int t = blockIdx.x, tid = threadIdx.x;
  for (int i = tid; i < 32 * 1024; i += 256)
    ls[i] = __float2bfloat16(cell[(size_t)t * 32768 + i]);
  __syncthreads();
  const int e = tid * 2;
  const int b = e >> 4, dd = e & 15;
  for (int sl = 0; sl < 64; ++sl) {
    union { __hip_bfloat16 h[2]; unsigned u; } pk;
    pk.h[0] = ls[b * 1024 + sl * 16 + dd];
    pk.h[1] = ls[b * 1024 + sl * 16 + dd + 1];
    *(unsigned*)&blk[((size_t)sl * 256 + t) * 512 + e] = pk.u;
  }
}

// ---------------- persistent scan ----------------
struct PP {
  const __hip_bfloat16* hid;     // [8192][1024]  rows t*32+b
  const float* cell;             // [8192][1024]  rows t*32+b (f32, creg init only)
  const __hip_bfloat16 *Whh_s, *Wih_s, *Whh_r, *Whh_a;  // [4096][1024]
  const __hip_bfloat16 *xgs_blk, *xgr_blk;  // [64][256][2048] blk-layout x-gates
  const __hip_bfloat16* cellblk; // [64][256][512] blk-layout bf16 cell
  const float* table;            // [20][4096]
  const int* actions;            // [32][256]
  const float *stack_c0, *act_c0, *sbias;
  __hip_bfloat16 *sb0, *sb1, *rb0, *rb1, *ab0, *ab1;    // h dbuf [32][1024] bf16
  float *s1, *s2, *s3, *atop;    // [32][1024] f32
  unsigned int* flags;           // [0..2] per-scan arrival counters
};

__global__ __launch_bounds__(256, 1) void scan_persist(PP P)
{
  __shared__ __hip_bfloat16 Wl[64 * 1024];             // 128 KB, XOR-swizzled
  __shared__ float gsm[32][16][4];                     // 8 KB gate exchange
  __shared__ __align__(16) __hip_bfloat16 hstage[32][16];  // 1 KB packed h staging
  const int bid = blockIdx.x;
  const int scan = bid >> 6;                 // 0 stack, 1 reduce, 2 action
  const int slot = bid & 63;
  const int d0 = slot * 16;
  const int tid = threadIdx.x;
  const int l = tid & 63, w = tid >> 6;
  const int mh = w >> 1, nh = w & 1;

  const __hip_bfloat16* Wg = (scan == 0) ? P.Whh_s : ((scan == 1) ? P.Whh_r : P.Whh_a);
  for (int idx = tid; idx < 64 * 128; idx += 256) {
    int r = idx >> 7, k = (idx & 127) * 8;
    int grow = ((r >> 4) << 10) + d0 + (r & 15);
    bf16x8 v = *(const bf16x8*)&Wg[(size_t)grow * 1024 + k];
    *(bf16x8*)&Wl[r * 1024 + (k ^ ((r & 7) << 3))] = v;
  }
  const int e0 = tid, e1 = tid + 256;
  const int b0_ = e0 >> 4, dd0 = e0 & 15, b1_ = e1 >> 4, dd1 = e1 & 15;
  float creg0, creg1;
  if (scan == 0)      { creg0 = P.stack_c0[d0 + dd0]; creg1 = P.stack_c0[d0 + dd1]; }
  else if (scan == 1) { creg0 = P.cell[b0_ * 1024 + d0 + dd0]; creg1 = P.cell[b1_ * 1024 + d0 + dd1]; }
  else                { creg0 = P.act_c0[d0 + dd0]; creg1 = P.act_c0[d0 + dd1]; }
  __syncthreads();

  __hip_bfloat16 *bufA, *bufB;
  if (scan == 0)      { bufA = P.sb0; bufB = P.sb1; }
  else if (scan == 1) { bufA = P.rb0; bufB = P.rb1; }
  else                { bufA = P.ab0; bufB = P.ab1; }
  unsigned int* ctr = P.flags + scan;
  const int Ns = (scan == 1) ? 255 : 256;
  const int mbase = mh * 16 + (l >> 4) * 4;

  for (int s = 0; s < Ns; ++s) {
    const __hip_bfloat16* Ap = (s & 1) ? bufB : bufA;
    if (scan == 1 && s == 0) Ap = P.hid;           // hid_t[0]
    __hip_bfloat16* Hout = (s & 1) ? bufA : bufB;
    f32x4 acc0 = {}, acc1 = {};
    mfma_step(Ap, Wl, mh, nh, l, acc0, acc1);
#pragma unroll
    for (int r = 0; r < 4; ++r) {
      gsm[mbase + r][l & 15][nh * 2 + 0] = acc0[r];
      gsm[mbase + r][l & 15][nh * 2 + 1] = acc1[r];
    }
    __syncthreads();
#pragma unroll
    for (int q = 0; q < 2; ++q) {
      const int b = q ? b1_ : b0_, dd = q ? dd1 : dd0;
      const int d = d0 + dd;
      float& creg = q ? creg1 : creg0;
      float g0 = gsm[b][dd][0], g1 = gsm[b][dd][1], g2 = gsm[b][dd][2], g3 = gsm[b][dd][3];
      if (scan == 1) {
        const __hip_bfloat16* xr = P.xgr_blk + ((size_t)slot * 256 + s + 1) * 2048 + b * 16 + dd;
        float ig = sigmoidf_(g0 + __bfloat162float(xr[0]));
        float lg = sigmoidf_(g1 + __bfloat162float(xr[512]));
        float rg = sigmoidf_(g2 + __bfloat162float(xr[1024]));
        float cand = tanhf(g3 + __bfloat162float(xr[1536]));
        float rcv = __bfloat162float(P.cellblk[((size_t)slot * 256 + s + 1) * 512 + b * 16 + dd]);
        float c2 = ig * cand + lg * creg + rg * rcv;
        creg = c2;
        hstage[b][dd] = __float2bfloat16(tanhf(c2));
      } else {
        float bi0, bi1, bi2, bi3;
        if (scan == 0) {
          const __hip_bfloat16* xr = P.xgs_blk + ((size_t)slot * 256 + s) * 2048 + b * 16 + dd;
          bi0 = __bfloat162float(xr[0]);    bi1 = __bfloat162float(xr[512]);
          bi2 = __bfloat162float(xr[1024]); bi3 = __bfloat162float(xr[1536]);
        } else {
          int a = P.actions[b * 256 + s];
          const float* tb = P.table + a * 4096;
          bi0 = tb[d]; bi1 = tb[1024 + d]; bi2 = tb[2048 + d]; bi3 = tb[3072 + d];
        }
        float c2 = sigmoidf_(g1 + bi1) * creg + sigmoidf_(g0 + bi0) * tanhf(g2 + bi2);
        float h2 = sigmoidf_(g3 + bi3) * tanhf(c2);
        creg = c2;
        hstage[b][dd] = __float2bfloat16(h2);
        if (scan == 0 && s == 254) P.s3[b * 1024 + d] = h2;
        if (scan == 0 && s == 255) P.s2[b * 1024 + d] = h2;
        if (scan == 2 && s == 255) P.atop[b * 1024 + d] = h2;
      }
    }
    __syncthreads();
    // ---- packed 16B device-coherent h stores (wave 0 only) ----
    if (tid < 64) {
      const int bb = tid >> 1, hf = tid & 1;
      union { bf16x8 b8; i32x4 i4; } u;
      u.b8 = *(const bf16x8*)&hstage[bb][hf * 8];
      store16_sys(Hout + bb * 1024 + d0 + hf * 8, u.i4);
    }
    asm volatile("s_waitcnt vmcnt(0)" ::: "memory");
    __syncthreads();
    // ---- aggregated barrier: 1 relaxed atomic arrival + 1 polling lane ----
    if (tid == 0) {
      __hip_atomic_fetch_add(ctr, 1u, __ATOMIC_RELAXED, __HIP_MEMORY_SCOPE_AGENT);
      const unsigned tgt = 64u * (unsigned)(s + 1);
      while (flag_load(ctr) < tgt) __builtin_amdgcn_s_sleep(2);
    }
    __syncthreads();
  }

  if (scan == 0) {
    if (tid == 0) {
      while (flag_load(P.flags + 1) < 64u * 255u) __builtin_amdgcn_s_sleep(2);
    }
    __syncthreads();
    f32x4 acc0 = {}, acc1 = {};
    mfma_step(P.sb0, Wl, mh, nh, l, acc0, acc1);              // hf @ Whh^T
    mfma_pass_glb(P.rb1, P.Wih_s, d0, mh, nh, l, acc0, acc1); // red_h @ Wih^T
#pragma unroll
    for (int r = 0; r < 4; ++r) {
      gsm[mbase + r][l & 15][nh * 2 + 0] = acc0[r];
      gsm[mbase + r][l & 15][nh * 2 + 1] = acc1[r];
    }
    __syncthreads();
#pragma unroll
    for (int q = 0; q < 2; ++q) {
      const int b = q ? b1_ : b0_, dd = q ? dd1 : dd0;
      const int d = d0 + dd;
      float creg = q ? creg1 : creg0;   // cf
      float g0 = gsm[b][dd][0], g1 = gsm[b][dd][1], g2 = gsm[b][dd][2], g3 = gsm[b][dd][3];
      float bi0 = P.sbias[d], bi1 = P.sbias[1024 + d], bi2 = P.sbias[2048 + d], bi3 = P.sbias[3072 + d];
      float c2 = sigmoidf_(g1 + bi1) * creg + sigmoidf_(g0 + bi0) * tanhf(g2 + bi2);
      float h2 = sigmoidf_(g3 + bi3) * tanhf(c2);
      P.s1[b * 1024 + d] = h2;
    }
  }
}

// ---------------- small utility kernels ----------------
__global__ void cast_kernel(__hip_bfloat16* dst, const float* src, int n) {
  int i = blockIdx.x * 256 + threadIdx.x;
  if (i < n) dst[i] = __float2bfloat16(src[i]);
}
__global__ void extract_half_kernel(__hip_bfloat16* dst, const float* src, int n,
                                    int src_stride, int src_off) {
  int i = blockIdx.x * 256 + threadIdx.x;
  if (i < n) {
    int r = i >> 10, k = i & 1023;
    dst[i] = __float2bfloat16(src[(size_t)r * src_stride + src_off + k]);
  }
}
__global__ void bias_kernel(float* dst, const float* a, const float* b, int n) {
  int i = blockIdx.x * 256 + threadIdx.x;
  if (i < n) dst[i] = a[i] + b[i];
}
__global__ void act_table_kernel(const float* emb, const float* Wih, const float* bih,
                                 const float* bhh, float* table) {
  int i = blockIdx.x * 256 + threadIdx.x;
  int a = i >> 12, n = i & 4095;
  float acc = bih[n] + bhh[n];
  const float* er = emb + a * 64;
  const float* wr = Wih + (size_t)n * 64;
  for (int k = 0; k < 64; ++k) acc += er[k] * wr[k];
  table[i] = acc;
}
__global__ void init_states_kernel(const float* stack_h0, const float* act_h0,
                                   __hip_bfloat16* sb0, __hip_bfloat16* ab0,
                                   unsigned int* flags)
{
  int i = blockIdx.x * 256 + threadIdx.x;
  int d = i & 1023;
  sb0[i] = __float2bfloat16(stack_h0[d]);
  ab0[i] = __float2bfloat16(act_h0[d]);
  if (i < 192) flags[i] = 0u;
}

// ---------------- attention ----------------
__global__ __launch_bounds__(256) void att_q_kernel(
    const float* s1, const float* s2, const float* s3, const float* attW, float* q)
{
  int eb = blockIdx.x, bg = blockIdx.y, j = blockIdx.z;
  const float* sj = (j == 0) ? s1 : ((j == 1) ? s2 : s3);
  __shared__ float ls[4][1024];
  int tid = threadIdx.x;
  for (int i = tid; i < 4096; i += 256)
    ls[i >> 10][i & 1023] = sj[(size_t)(bg * 4 + (i >> 10)) * 1024 + (i & 1023)];
  __syncthreads();
  int e = eb * 256 + tid;
  const float* Wj = attW + (size_t)j * 1024 * 1024;
  float a0 = 0, a1 = 0, a2 = 0, a3 = 0;
  for (int d = 0; d < 1024; ++d) {
    float wv = Wj[(size_t)d * 1024 + e];
    a0 += ls[0][d] * wv; a1 += ls[1][d] * wv; a2 += ls[2][d] * wv; a3 += ls[3][d] * wv;
  }
  q[((size_t)j * 32 + bg * 4 + 0) * 1024 + e] = a0;
  q[((size_t)j * 32 + bg * 4 + 1) * 1024 + e] = a1;
  q[((size_t)j * 32 + bg * 4 + 2) * 1024 + e] = a2;
  q[((size_t)j * 32 + bg * 4 + 3) * 1024 + e] = a3;
}

__global__ __launch_bounds__(256) void att_sc_kernel(const float* q, const float* sent, float* att)
{
  int b = blockIdx.x, j = blockIdx.y;
  __shared__ float qs[1024];
  __shared__ float wsm[256];
  __shared__ float red[8];
  int tid = threadIdx.x, w = tid >> 6, l = tid & 63;
  for (int i = tid; i < 1024; i += 256) qs[i] = q[((size_t)j * 32 + b) * 1024 + i];
  __syncthreads();
  const float* sp = sent + ((size_t)b * 256 + tid) * 1024;
  float dot = 0;
  for (int k = 0; k < 1024; ++k) dot += qs[k] * sp[k];
  float v = dot;
  for (int off = 32; off; off >>= 1) v = fmaxf(v, __shfl_xor(v, off));
  if (l == 0) red[w] = v;
  __syncthreads();
  float m = fmaxf(fmaxf(red[0], red[1]), fmaxf(red[2], red[3]));
  float ex = expf(dot - m);
  float sv = ex;
  for (int off = 32; off; off >>= 1) sv += __shfl_xor(sv, off);
  if (l == 0) red[4 + w] = sv;
  __syncthreads();
  float ssum = red[4] + red[5] + red[6] + red[7];
  wsm[tid] = ex / ssum;
  __syncthreads();
  for (int it = 0; it < 4; ++it) {
    int e = it * 256 + tid;
    float a = 0;
    for (int t2 = 0; t2 < 256; ++t2) a += wsm[t2] * sent[((size_t)b * 256 + t2) * 1024 + e];
    att[((size_t)j * 32 + b) * 1024 + e] = a;
  }
}

// ---------------- head ----------------
__global__ void feat_kernel(const float* s1, const float* s2, const float* s3,
                            const float* tok, const float* atop, const float* att, float* feat)
{
  int i = blockIdx.x * 256 + threadIdx.x;
  int b = i >> 13, jj = (i >> 10) & 7, d = i & 1023;
  int sidx = b * 1024 + d;
  float v;
  switch (jj) {
    case 0: v = s1[sidx]; break;
    case 1: v = s2[sidx]; break;
    case 2: v = s3[sidx]; break;
    case 3: v = tok[d]; break;
    case 4: v = atop[sidx]; break;
    default: v = att[((size_t)(jj - 5) * 32 + b) * 1024 + d];
  }
  feat[i] = v;
}
__global__ __launch_bounds__(256) void head_kernel(const float* feat, const float* W,
                                                   const float* bias, float* fbuf)
{
  int i = blockIdx.x * 256 + threadIdx.x;
  int b = i >> 9, h = i & 511;
  const float* fr = feat + (size_t)b * 8192;
  const float* wr = W + (size_t)h * 8192;
  float a = bias[h];
  for (int k = 0; k < 8192; ++k) a += fr[k] * wr[k];
  fbuf[i] = tanhf(a);
}
__global__ void logits_kernel(const float* fbuf, const float* W, const float* bias, float* out)
{
  int b = blockIdx.x, tid = threadIdx.x;
  __shared__ float lg[20];
  __shared__ float mred, lsred;
  if (tid < 20) {
    const float* fr = fbuf + b * 512;
    const float* wr = W + tid * 512;
    float a = bias[tid];
    for (int k = 0; k < 512; ++k) a += fr[k] * wr[k];
    lg[tid] = a;
  }
  __syncthreads();
  if (tid == 0) {
    float m = lg[0];
    for (int i = 1; i < 20; ++i) m = fmaxf(m, lg[i]);
    float ssum = 0;
    for (int i = 0; i < 20; ++i) ssum += expf(lg[i] - m);
    mred = m; lsred = logf(ssum);
  }
  __syncthreads();
  if (tid < 20) out[b * 20 + tid] = lg[tid] - mred - lsred;
}

// ---------------- host ----------------
extern "C" void kernel_launch(void* const* d_in, const int* in_sizes, int n_in,
                              void* d_out, int out_size, void* d_ws, size_t ws_size,
                              hipStream_t stream)
{
  const float* sentence = (const float*)d_in[0];
  const int* actions = (const int*)d_in[1];
  const float* token_empty = (const float*)d_in[2];
  const float* leaf_Wi = (const float*)d_in[3];
  const float* leaf_bi = (const float*)d_in[4];
  const float* leaf_Wo = (const float*)d_in[5];
  const float* leaf_bo = (const float*)d_in[6];
  const float* lstm_Wih = (const float*)d_in[7];
  const float* lstm_Whh = (const float*)d_in[8];
  const float* lstm_bih = (const float*)d_in[9];
  const float* lstm_bhh = (const float*)d_in[10];
  const float* stack_h0 = (const float*)d_in[11];
  const float* stack_c0 = (const float*)d_in[12];
  const float* act_emb = (const float*)d_in[13];
  const float* act_Wih = (const float*)d_in[14];
  const float* act_Whh = (const float*)d_in[15];
  const float* act_bih = (const float*)d_in[16];
  const float* act_bhh = (const float*)d_in[17];
  const float* act_h0 = (const float*)d_in[18];
  const float* act_c0 = (const float*)d_in[19];
  const float* red_W = (const float*)d_in[20];
  const float* red_b = (const float*)d_in[21];
  const float* h2f_W = (const float*)d_in[22];
  const float* h2f_b = (const float*)d_in[23];
  const float* f2a_W = (const float*)d_in[24];
  const float* f2a_b = (const float*)d_in[25];
  const float* att_W = (const float*)d_in[26];
  float* out = (float*)d_out;
  (void)in_sizes; (void)n_in; (void)out_size; (void)ws_size;

  char* ws = (char*)d_ws;
  size_t off = 0;
  auto alloc = [&](size_t bytes) -> void* {
    void* ptr = ws + off;
    off += (bytes + 255) & ~(size_t)255;
    return ptr;
  };
  __hip_bfloat16* sent_bf = (__hip_bfloat16*)alloc(16777216);   // [8192][1024] (b*256+t)
  __hip_bfloat16* hid_bf  = (__hip_bfloat16*)alloc(16777216);   // [8192][1024] (t*32+b)
  float* cell_f32 = (float*)alloc(33554432);                    // [8192][1024] (t*32+b)
  __hip_bfloat16* lWi_bf = (__hip_bfloat16*)alloc(2097152);
  __hip_bfloat16* lWo_bf = (__hip_bfloat16*)alloc(2097152);
  __hip_bfloat16* Whh_s = (__hip_bfloat16*)alloc(8388608);
  __hip_bfloat16* Wih_s = (__hip_bfloat16*)alloc(8388608);
  __hip_bfloat16* Whh_r = (__hip_bfloat16*)alloc(8388608);
  __hip_bfloat16* Wx_r  = (__hip_bfloat16*)alloc(8388608);
  __hip_bfloat16* Whh_a = (__hip_bfloat16*)alloc(8388608);
  __hip_bfloat16* xgs_blk = (__hip_bfloat16*)alloc(67108864);   // [64][256][2048]
  __hip_bfloat16* xgr_blk = (__hip_bfloat16*)alloc(67108864);
  __hip_bfloat16* cellblk = (__hip_bfloat16*)alloc(16777216);   // [64][256][512]
  float* table = (float*)alloc(327680);
  float* sbias = (float*)alloc(16384);
  __hip_bfloat16* sb0 = (__hip_bfloat16*)alloc(65536);
  __hip_bfloat16* sb1 = (__hip_bfloat16*)alloc(65536);
  __hip_bfloat16* rb0 = (__hip_bfloat16*)alloc(65536);
  __hip_bfloat16* rb1 = (__hip_bfloat16*)alloc(65536);
  __hip_bfloat16* ab0 = (__hip_bfloat16*)alloc(65536);
  __hip_bfloat16* ab1 = (__hip_bfloat16*)alloc(65536);
  float* s1 = (float*)alloc(131072);
  float* s2 = (float*)alloc(131072);
  float* s3 = (float*)alloc(131072);
  float* atop = (float*)alloc(131072);
  unsigned int* flags = (unsigned int*)alloc(1024);
  float* qbuf = (float*)alloc(393216);
  float* attbuf = (float*)alloc(393216);
  float* feat = (float*)alloc(1048576);
  float* fbuf = (float*)alloc(65536);

  // conversions
  cast_kernel<<<32768, 256, 0, stream>>>(sent_bf, sentence, 8388608);
  cast_kernel<<<4096, 256, 0, stream>>>(lWi_bf, leaf_Wi, 1048576);
  cast_kernel<<<4096, 256, 0, stream>>>(lWo_bf, leaf_Wo, 1048576);
  cast_kernel<<<16384, 256, 0, stream>>>(Whh_s, lstm_Whh, 4194304);
  cast_kernel<<<16384, 256, 0, stream>>>(Wih_s, lstm_Wih, 4194304);
  cast_kernel<<<16384, 256, 0, stream>>>(Whh_a, act_Whh, 4194304);
  extract_half_kernel<<<16384, 256, 0, stream>>>(Whh_r, red_W, 4194304, 2048, 0);
  extract_half_kernel<<<16384, 256, 0, stream>>>(Wx_r, red_W, 4194304, 2048, 1024);
  bias_kernel<<<16, 256, 0, stream>>>(sbias, lstm_bih, lstm_bhh, 4096);
  act_table_kernel<<<320, 256, 0, stream>>>(act_emb, act_Wih, act_bih, act_bhh, table);

  // leaf module
  gemm_bt_kernel<<<dim3(64, 8), 256, 0, stream>>>(sent_bf, lWi_bf, cell_f32, nullptr,
                                                  leaf_bi, nullptr, 8192, 1024, 1024, 1, 0);
  gemm_bt_kernel<<<dim3(64, 8), 256, 0, stream>>>(sent_bf, lWo_bf, nullptr, hid_bf,
                                                  leaf_bo, cell_f32, 8192, 1024, 1024, 1, 2);
  cellblk_kernel<<<256, 256, 0, stream>>>(cell_f32, cellblk);

  // precomputed x-gates in blk layout (bias folded)
  gemm_bt_kernel<<<dim3(64, 32), 256, 0, stream>>>(hid_bf, Wih_s, nullptr, xgs_blk,
                                                   sbias, nullptr, 8192, 4096, 1024, 0, 3);
  gemm_bt_kernel<<<dim3(64, 32), 256, 0, stream>>>(hid_bf, Wx_r, nullptr, xgr_blk,
                                                   red_b, nullptr, 8192, 4096, 1024, 0, 3);

  init_states_kernel<<<128, 256, 0, stream>>>(stack_h0, act_h0, sb0, ab0, flags);

  PP P;
  P.hid = hid_bf; P.cell = cell_f32;
  P.Whh_s = Whh_s; P.Wih_s = Wih_s; P.Whh_r = Whh_r; P.Whh_a = Whh_a;
  P.xgs_blk = xgs_blk; P.xgr_blk = xgr_blk; P.cellblk = cellblk;
  P.table = table; P.actions = actions;
  P.stack_c0 = stack_c0; P.act_c0 = act_c0; P.sbias = sbias;
  P.sb0 = sb0; P.sb1 = sb1; P.rb0 = rb0; P.rb1 = rb1; P.ab0 = ab0; P.ab1 = ab1;
  P.s1 = s1; P.s2 = s2; P.s3 = s3; P.atop = atop;
  P.flags = flags;
  scan_persist<<<192, 256, 0, stream>>>(P);

  // attention: s1, s2, s3
  att_q_kernel<<<dim3(4, 8, 3), 256, 0, stream>>>(s1, s2, s3, att_W, qbuf);
  att_sc_kernel<<<dim3(32, 3), 256, 0, stream>>>(qbuf, sentence, attbuf);

  // head
  feat_kernel<<<1024, 256, 0, stream>>>(s1, s2, s3, token_empty, atop, attbuf, feat);
  head_kernel<<<64, 256, 0, stream>>>(feat, h2f_W, h2f_b, fbuf);
  logits_kernel<<<32, 64, 0, stream>>>(fbuf, f2a_W, f2a_b, out);
}

// Round 10
// 3712.518 us; speedup vs baseline: 1.0071x; 1.0071x over previous
//
#include <hip/hip_runtime.h>
#include <hip/hip_bf16.h>
#include <math.h>

// B=32, T=256, D=1024, A=64, H=512, NA=20
#define DEV __device__ __forceinline__

typedef __bf16 bf16_t;
typedef bf16_t bf16x8 __attribute__((ext_vector_type(8)));
typedef float f32x4 __attribute__((ext_vector_type(4)));
typedef int i32x4 __attribute__((ext_vector_type(4)));

DEV void async16(const void* g, void* l) {
  __builtin_amdgcn_global_load_lds((const __attribute__((address_space(1))) void*)g,
                                   (__attribute__((address_space(3))) void*)l, 16, 0, 0);
}
DEV float sigmoidf_(float x) { return 1.f / (1.f + expf(-x)); }
DEV bf16x8 as_bf(i32x4 v) { union { i32x4 i; bf16x8 b; } u; u.i = v; return u.b; }

// ---- fine-grained device-coherent ops ----
DEV unsigned flag_load(const unsigned* p) {
  unsigned v;
  asm volatile("global_load_dword %0, %1, off sc0 sc1\ns_waitcnt vmcnt(0)"
               : "=v"(v) : "v"(p) : "memory");
  return v;
}
DEV void store16_sys(void* p, i32x4 v) {
  asm volatile("global_store_dwordx4 %0, %1, off sc0 sc1" :: "v"(p), "v"(v) : "memory");
}

#define WAITV(N) do { asm volatile("s_waitcnt vmcnt(" #N ")" ::: "memory"); \
                      __builtin_amdgcn_sched_barrier(0); } while (0)

// NORMAL cached loads (L1/L2 path). h_hist slots are write-once-before-read per
// dispatch (and bit-identical across graph replays), so no stale-line hazard;
// L2 turns the 64-block h broadcast into ~one L3 fetch per XCD instead of 64
// bypass fetches hitting the same L3 slices.
template<int KB>
DEV void loads8(i32x4* dst, const __hip_bfloat16* arow) {
#pragma unroll
  for (int i = 0; i < 8; ++i)
    asm volatile("global_load_dwordx4 %0, %1, off offset:%2"
                 : "=v"(dst[i]) : "v"(arow), "i"((KB + i) * 64));
}
DEV void loads8rt(i32x4* dst, const __hip_bfloat16* arow, int kbase) {
#pragma unroll
  for (int i = 0; i < 8; ++i)
    asm volatile("global_load_dwordx4 %0, %1, off"
                 : "=v"(dst[i]) : "v"(arow + (size_t)(kbase + i) * 32) : "memory");
}

template<int C>
DEV void ldsb8(bf16x8* b0, bf16x8* b1, const __hip_bfloat16* Wl,
               int sw, int kof, int r0, int r1) {
#pragma unroll
  for (int i = 0; i < 8; ++i) {
    const int kk = (C * 8 + i) * 32 + kof;
    b0[i] = *(const bf16x8*)&Wl[r0 * 1024 + (kk ^ sw)];
    b1[i] = *(const bf16x8*)&Wl[r1 * 1024 + (kk ^ sw)];
  }
}
DEV void mfma8x(const i32x4* a, const bf16x8* b0, const bf16x8* b1,
                f32x4& acc0, f32x4& acc1) {
#pragma unroll
  for (int i = 0; i < 8; ++i) {
    bf16x8 av = as_bf(a[i]);
    acc0 = __builtin_amdgcn_mfma_f32_16x16x32_bf16(av, b0[i], acc0, 0, 0, 0);
    acc1 = __builtin_amdgcn_mfma_f32_16x16x32_bf16(av, b1[i], acc1, 0, 0, 0);
  }
}

// K=1024 recurrent GEMM: A (h-state, cached loads, all issued upfront) x W (LDS)
DEV void mfma_step(const __hip_bfloat16* Ap, const __hip_bfloat16* Wl,
                   int mh, int nh, int l, f32x4& acc0, f32x4& acc1) {
  const __hip_bfloat16* arow = Ap + (mh * 16 + (l & 15)) * 1024 + (l >> 4) * 8;
  const int sw = (l & 7) << 3, kof = (l >> 4) * 8;
  const int r0 = nh * 32 + (l & 15), r1 = r0 + 16;
  i32x4 A0[8], A1[8], A2[8], A3[8];
  bf16x8 Ba0[8], Ba1[8], Bb0[8], Bb1[8];
  loads8<0>(A0, arow);
  loads8<8>(A1, arow);
  loads8<16>(A2, arow);
  loads8<24>(A3, arow);
  ldsb8<0>(Ba0, Ba1, Wl, sw, kof, r0, r1);
  WAITV(24);
  mfma8x(A0, Ba0, Ba1, acc0, acc1);
  ldsb8<1>(Bb0, Bb1, Wl, sw, kof, r0, r1);
  WAITV(16);
  mfma8x(A1, Bb0, Bb1, acc0, acc1);
  ldsb8<2>(Ba0, Ba1, Wl, sw, kof, r0, r1);
  WAITV(8);
  mfma8x(A2, Ba0, Ba1, acc0, acc1);
  ldsb8<3>(Bb0, Bb1, Wl, sw, kof, r0, r1);
  WAITV(0);
  mfma8x(A3, Bb0, Bb1, acc0, acc1);
}

// final-phase pass: A cached loads, W from global (cached)
DEV void mfma_pass_glb(const __hip_bfloat16* Ap, const __hip_bfloat16* __restrict__ Wg,
                       int d0, int mh, int nh, int l, f32x4& acc0, f32x4& acc1) {
  const __hip_bfloat16* arow = Ap + (mh * 16 + (l & 15)) * 1024 + (l >> 4) * 8;
  const size_t g0 = ((size_t)(2 * nh) * 1024 + d0 + (l & 15)) * 1024;
  const size_t g1 = g0 + 1048576;
  const int kof = (l >> 4) * 8;
  i32x4 A[8];
  for (int c = 0; c < 4; ++c) {
    loads8rt(A, arow, c * 8);
    WAITV(0);
#pragma unroll
    for (int i = 0; i < 8; ++i) {
      const int kk = (c * 8 + i) * 32 + kof;
      bf16x8 b0 = *(const bf16x8*)&Wg[g0 + kk];
      bf16x8 b1 = *(const bf16x8*)&Wg[g1 + kk];
      bf16x8 av = as_bf(A[i]);
      acc0 = __builtin_amdgcn_mfma_f32_16x16x32_bf16(av, b0, acc0, 0, 0, 0);
      acc1 = __builtin_amdgcn_mfma_f32_16x16x32_bf16(av, b1, acc1, 0, 0, 0);
    }
  }
}

// ---------------- generic bf16 MFMA GEMM: C[M,N] = A[M,K] @ Bw[N,K]^T + bias ----------------
// mode 0: outF = acc+bias (f32); mode 1: outBF = bf16(acc+bias)
// mode 2: outBF = bf16(sigmoid(acc+bias)*tanh(aux))
// mode 3: outBF is blk layout [slot][256 t][2048] chunk [g*512 + b*16 + dd]; rows must be t*32+b
__global__ __launch_bounds__(256) void gemm_bt_kernel(
    const __hip_bfloat16* __restrict__ A, const __hip_bfloat16* __restrict__ Bw,
    float* __restrict__ outF, __hip_bfloat16* __restrict__ outBF,
    const float* __restrict__ bias, const float* __restrict__ aux,
    int M, int N, int K, int remap, int mode)
{
  __shared__ __hip_bfloat16 As[128 * 64];
  __shared__ __hip_bfloat16 Bs[128 * 64];
  __shared__ __hip_bfloat16 Cs[128 * 128];   // mode-3 staging only
  const int tid = threadIdx.x;
  const int w = tid >> 6, l = tid & 63;
  const int m0 = blockIdx.x * 128, n0 = blockIdx.y * 128;
  const int wm = (w >> 1) * 64, wn = (w & 1) * 64;
  const int row_s = tid >> 3, kc = tid & 7;
  f32x4 acc[4][4] = {};
  for (int k0 = 0; k0 < K; k0 += 64) {
    const __hip_bfloat16* ga = A + (size_t)(m0 + row_s) * K + k0 + kc * 8;
    const __hip_bfloat16* gb = Bw + (size_t)(n0 + row_s) * K + k0 + kc * 8;
    __hip_bfloat16* la = As + w * 512;
    __hip_bfloat16* lb = Bs + w * 512;
#pragma unroll
    for (int p = 0; p < 4; ++p) {
      async16(ga + (size_t)p * 32 * K, la + p * 2048);
      async16(gb + (size_t)p * 32 * K, lb + p * 2048);
    }
    __syncthreads();
#pragma unroll
    for (int kb = 0; kb < 2; ++kb) {
      bf16x8 af[4], bfr[4];
#pragma unroll
      for (int i = 0; i < 4; ++i)
        af[i] = *(const bf16x8*)&As[(wm + i * 16 + (l & 15)) * 64 + kb * 32 + (l >> 4) * 8];
#pragma unroll
      for (int j = 0; j < 4; ++j)
        bfr[j] = *(const bf16x8*)&Bs[(wn + j * 16 + (l & 15)) * 64 + kb * 32 + (l >> 4) * 8];
#pragma unroll
      for (int i = 0; i < 4; ++i)
#pragma unroll
        for (int j = 0; j < 4; ++j)
          acc[i][j] = __builtin_amdgcn_mfma_f32_16x16x32_bf16(af[i], bfr[j], acc[i][j], 0, 0, 0);
    }
    __syncthreads();
  }
  if (mode == 3) {
#pragma unroll
    for (int i = 0; i < 4; ++i)
#pragma unroll
      for (int j = 0; j < 4; ++j) {
        const int ncol = n0 + wn + j * 16 + (l & 15);
        const float bv = bias[ncol];
#pragma unroll
        for (int r = 0; r < 4; ++r) {
          const int lr = wm + i * 16 + (l >> 4) * 4 + r;
          Cs[lr * 128 + wn + j * 16 + (l & 15)] = __float2bfloat16(acc[i][j][r] + bv);
        }
      }
    __syncthreads();
    const int t0 = m0 >> 5, g = n0 >> 10, slot0 = (n0 & 1023) >> 4;
    const int grp = tid >> 6, li = tid & 63;
    const int b = li >> 1, half = li & 1;
#pragma unroll
    for (int sl = 0; sl < 8; ++sl) {
      bf16x8 vv = *(const bf16x8*)&Cs[(grp * 32 + b) * 128 + sl * 16 + half * 8];
      *(bf16x8*)&outBF[(((size_t)(slot0 + sl)) * 256 + t0 + grp) * 2048 +
                       g * 512 + b * 16 + half * 8] = vv;
    }
    return;
  }
#pragma unroll
  for (int i = 0; i < 4; ++i) {
#pragma unroll
    for (int j = 0; j < 4; ++j) {
      const int ncol = n0 + wn + j * 16 + (l & 15);
      const float bv = bias ? bias[ncol] : 0.f;
#pragma unroll
      for (int r = 0; r < 4; ++r) {
        int m = m0 + wm + i * 16 + (l >> 4) * 4 + r;
        int row = remap ? (((m & 255) << 5) | (m >> 8)) : m;
        float v = acc[i][j][r] + bv;
        if (mode == 0) {
          outF[(size_t)row * N + ncol] = v;
        } else if (mode == 1) {
          outBF[(size_t)row * N + ncol] = __float2bfloat16(v);
        } else {
          float cv = aux[(size_t)row * N + ncol];
          outBF[(size_t)row * N + ncol] = __float2bfloat16(sigmoidf_(v) * tanhf(cv));
        }
      }
    }
  }
}

// cell [8192][1024] f32 (rows t*32+b) -> blk [64 slot][256 t][32 b][16 dd] bf16
__global__ __launch_bounds__(256) void cellblk_kernel(const float* __restrict__ cell,
                                                      __hip_bfloat16* __restrict__ blk)
{
  __shared__ __hip_bfloat16 ls[32 * 1024];   // 64 KB
  const int t = blockIdx.x, tid = threadIdx.x;
  for (int i = tid; i < 32 * 1024; i += 256)
    ls[i] = __float2bfloat16(cell[(size_t)t * 32768 + i]);
  __syncthreads();
  const int e = tid * 2;
  const int b = e >> 4, dd = e & 15;
  for (int sl = 0; sl < 64; ++sl) {
    union { __hip_bfloat16 h[2]; unsigned u; } pk;
    pk.h[0] = ls[b * 1024 + sl * 16 + dd];
    pk.h[1] = ls[b * 1024 + sl * 16 + dd + 1];
    *(unsigned*)&blk[((size_t)sl * 256 + t) * 512 + e] = pk.u;
  }
}

// ---------------- persistent scan ----------------
struct PP {
  const __hip_bfloat16 *Whh_s, *Wih_s, *Whh_r, *Whh_a;  // [4096][1024]
  const __hip_bfloat16 *xgs_blk, *xgr_blk;  // [64][256][2048] blk-layout x-gates
  const __hip_bfloat16* cellblk; // [64][256][512] blk-layout bf16 cell
  const float* table;            // [20][4096]
  const int* actions;            // [32][256]
  const float *stack_c0, *act_c0, *sbias;
  __hip_bfloat16 *sh_hist, *rh_hist, *ah_hist;  // [257][32][1024] h history (slot s = h after step s-1)
  float *s1, *s2, *s3, *atop;    // [32][1024] f32
  unsigned int* flags;           // [0..2] per-scan arrival counters
};

__global__ __launch_bounds__(256, 1) void scan_persist(PP P)
{
  __shared__ __hip_bfloat16 Wl[64 * 1024];             // 128 KB, XOR-swizzled
  __shared__ float gsm[32][16][4];                     // 8 KB gate exchange
  __shared__ __align__(16) __hip_bfloat16 hstage[32][16];  // 1 KB packed h staging
  const int bid = blockIdx.x;
  const int scan = bid >> 6;                 // 0 stack, 1 reduce, 2 action
  const int slot = bid & 63;
  const int d0 = slot * 16;
  const int tid = threadIdx.x;
  const int l = tid & 63, w = tid >> 6;
  const int mh = w >> 1, nh = w & 1;

  const __hip_bfloat16* Wg = (scan == 0) ? P.Whh_s : ((scan == 1) ? P.Whh_r : P.Whh_a);
  for (int idx = tid; idx < 64 * 128; idx += 256) {
    int r = idx >> 7, k = (idx & 127) * 8;
    int grow = ((r >> 4) << 10) + d0 + (r & 15);
    bf16x8 v = *(const bf16x8*)&Wg[(size_t)grow * 1024 + k];
    *(bf16x8*)&Wl[r * 1024 + (k ^ ((r & 7) << 3))] = v;
  }
  const int e0 = tid, e1 = tid + 256;
  const int b0_ = e0 >> 4, dd0 = e0 & 15, b1_ = e1 >> 4, dd1 = e1 & 15;
  float creg0, creg1;
  if (scan == 0)      { creg0 = P.stack_c0[d0 + dd0]; creg1 = P.stack_c0[d0 + dd1]; }
  else if (scan == 1) {
    creg0 = __bfloat162float(P.cellblk[(size_t)slot * 256 * 512 + b0_ * 16 + dd0]);
    creg1 = __bfloat162float(P.cellblk[(size_t)slot * 256 * 512 + b1_ * 16 + dd1]);
  }
  else                { creg0 = P.act_c0[d0 + dd0]; creg1 = P.act_c0[d0 + dd1]; }
  __syncthreads();

  __hip_bfloat16* hist = (scan == 0) ? P.sh_hist : ((scan == 1) ? P.rh_hist : P.ah_hist);
  unsigned int* ctr = P.flags + scan;
  const int Ns = (scan == 1) ? 255 : 256;
  const int mbase = mh * 16 + (l >> 4) * 4;

  for (int s = 0; s < Ns; ++s) {
    const __hip_bfloat16* Ap = hist + (size_t)s * 32768;
    __hip_bfloat16* Hout = hist + (size_t)(s + 1) * 32768;
    f32x4 acc0 = {}, acc1 = {};
    mfma_step(Ap, Wl, mh, nh, l, acc0, acc1);
#pragma unroll
    for (int r = 0; r < 4; ++r) {
      gsm[mbase + r][l & 15][nh * 2 + 0] = acc0[r];
      gsm[mbase + r][l & 15][nh * 2 + 1] = acc1[r];
    }
    __syncthreads();
#pragma unroll
    for (int q = 0; q < 2; ++q) {
      const int b = q ? b1_ : b0_, dd = q ? dd1 : dd0;
      const int d = d0 + dd;
      float& creg = q ? creg1 : creg0;
      float g0 = gsm[b][dd][0], g1 = gsm[b][dd][1], g2 = gsm[b][dd][2], g3 = gsm[b][dd][3];
      if (scan == 1) {
        const __hip_bfloat16* xr = P.xgr_blk + ((size_t)slot * 256 + s + 1) * 2048 + b * 16 + dd;
        float ig = sigmoidf_(g0 + __bfloat162float(xr[0]));
        float lg = sigmoidf_(g1 + __bfloat162float(xr[512]));
        float rg = sigmoidf_(g2 + __bfloat162float(xr[1024]));
        float cand = tanhf(g3 + __bfloat162float(xr[1536]));
        float rcv = __bfloat162float(P.cellblk[((size_t)slot * 256 + s + 1) * 512 + b * 16 + dd]);
        float c2 = ig * cand + lg * creg + rg * rcv;
        creg = c2;
        hstage[b][dd] = __float2bfloat16(tanhf(c2));
      } else {
        float bi0, bi1, bi2, bi3;
        if (scan == 0) {
          const __hip_bfloat16* xr = P.xgs_blk + ((size_t)slot * 256 + s) * 2048 + b * 16 + dd;
          bi0 = __bfloat162float(xr[0]);    bi1 = __bfloat162float(xr[512]);
          bi2 = __bfloat162float(xr[1024]); bi3 = __bfloat162float(xr[1536]);
        } else {
          int a = P.actions[b * 256 + s];
          const float* tb = P.table + a * 4096;
          bi0 = tb[d]; bi1 = tb[1024 + d]; bi2 = tb[2048 + d]; bi3 = tb[3072 + d];
        }
        float c2 = sigmoidf_(g1 + bi1) * creg + sigmoidf_(g0 + bi0) * tanhf(g2 + bi2);
        float h2 = sigmoidf_(g3 + bi3) * tanhf(c2);
        creg = c2;
        hstage[b][dd] = __float2bfloat16(h2);
        if (scan == 0 && s == 254) P.s3[b * 1024 + d] = h2;
        if (scan == 0 && s == 255) P.s2[b * 1024 + d] = h2;
        if (scan == 2 && s == 255) P.atop[b * 1024 + d] = h2;
      }
    }
    __syncthreads();
    // ---- packed 16B device-coherent h stores (wave 0 only) ----
    if (tid < 64) {
      const int bb = tid >> 1, hf = tid & 1;
      union { bf16x8 b8; i32x4 i4; } u;
      u.b8 = *(const bf16x8*)&hstage[bb][hf * 8];
      store16_sys(Hout + bb * 1024 + d0 + hf * 8, u.i4);
    }
    asm volatile("s_waitcnt vmcnt(0)" ::: "memory");
    __syncthreads();
    // ---- aggregated barrier: 1 relaxed atomic arrival + 1 polling lane ----
    if (tid == 0) {
      __hip_atomic_fetch_add(ctr, 1u, __ATOMIC_RELAXED, __HIP_MEMORY_SCOPE_AGENT);
      const unsigned tgt = 64u * (unsigned)(s + 1);
      while (flag_load(ctr) < tgt) __builtin_amdgcn_s_sleep(2);
    }
    __syncthreads();
  }

  if (scan == 0) {
    if (tid == 0) {
      while (flag_load(P.flags + 1) < 64u * 255u) __builtin_amdgcn_s_sleep(2);
    }
    __syncthreads();
    f32x4 acc0 = {}, acc1 = {};
    mfma_step(P.sh_hist + (size_t)256 * 32768, Wl, mh, nh, l, acc0, acc1);       // hf @ Whh^T
    mfma_pass_glb(P.rh_hist + (size_t)255 * 32768, P.Wih_s, d0, mh, nh, l, acc0, acc1); // red_h @ Wih^T
#pragma unroll
    for (int r = 0; r < 4; ++r) {
      gsm[mbase + r][l & 15][nh * 2 + 0] = acc0[r];
      gsm[mbase + r][l & 15][nh * 2 + 1] = acc1[r];
    }
    __syncthreads();
#pragma unroll
    for (int q = 0; q < 2; ++q) {
      const int b = q ? b1_ : b0_, dd = q ? dd1 : dd0;
      const int d = d0 + dd;
      float creg = q ? creg1 : creg0;   // cf
      float g0 = gsm[b][dd][0], g1 = gsm[b][dd][1], g2 = gsm[b][dd][2], g3 = gsm[b][dd][3];
      float bi0 = P.sbias[d], bi1 = P.sbias[1024 + d], bi2 = P.sbias[2048 + d], bi3 = P.sbias[3072 + d];
      float c2 = sigmoidf_(g1 + bi1) * creg + sigmoidf_(g0 + bi0) * tanhf(g2 + bi2);
      float h2 = sigmoidf_(g3 + bi3) * tanhf(c2);
      P.s1[b * 1024 + d] = h2;
    }
  }
}

// ---------------- small utility kernels ----------------
__global__ void cast_kernel(__hip_bfloat16* dst, const float* src, int n) {
  int i = blockIdx.x * 256 + threadIdx.x;
  if (i < n) dst[i] = __float2bfloat16(src[i]);
}
__global__ void extract_half_kernel(__hip_bfloat16* dst, const float* src, int n,
                                    int src_stride, int src_off) {
  int i = blockIdx.x * 256 + threadIdx.x;
  if (i < n) {
    int r = i >> 10, k = i & 1023;
    dst[i] = __float2bfloat16(src[(size_t)r * src_stride + src_off + k]);
  }
}
__global__ void bias_kernel(float* dst, const float* a, const float* b, int n) {
  int i = blockIdx.x * 256 + threadIdx.x;
  if (i < n) dst[i] = a[i] + b[i];
}
__global__ void act_table_kernel(const float* emb, const float* Wih, const float* bih,
                                 const float* bhh, float* table) {
  int i = blockIdx.x * 256 + threadIdx.x;
  int a = i >> 12, n = i & 4095;
  float acc = bih[n] + bhh[n];
  const float* er = emb + a * 64;
  const float* wr = Wih + (size_t)n * 64;
  for (int k = 0; k < 64; ++k) acc += er[k] * wr[k];
  table[i] = acc;
}
// fills history slot 0 for all three scans: stack h0, action h0, reduce = hid_t[0]
__global__ void init_states_kernel(const float* stack_h0, const float* act_h0,
                                   const __hip_bfloat16* hid,
                                   __hip_bfloat16* sh0, __hip_bfloat16* ah0,
                                   __hip_bfloat16* rh0, unsigned int* flags)
{
  int i = blockIdx.x * 256 + threadIdx.x;  // 32768
  int d = i & 1023;
  sh0[i] = __float2bfloat16(stack_h0[d]);
  ah0[i] = __float2bfloat16(act_h0[d]);
  rh0[i] = hid[i];
  if (i < 192) flags[i] = 0u;
}

// ---------------- attention ----------------
__global__ __launch_bounds__(256) void att_q_kernel(
    const float* s1, const float* s2, const float* s3, const float* attW, float* q)
{
  int eb = blockIdx.x, bg = blockIdx.y, j = blockIdx.z;
  const float* sj = (j == 0) ? s1 : ((j == 1) ? s2 : s3);
  __shared__ float ls[4][1024];
  int tid = threadIdx.x;
  for (int i = tid; i < 4096; i += 256)
    ls[i >> 10][i & 1023] = sj[(size_t)(bg * 4 + (i >> 10)) * 1024 + (i & 1023)];
  __syncthreads();
  int e = eb * 256 + tid;
  const float* Wj = attW + (size_t)j * 1024 * 1024;
  float a0 = 0, a1 = 0, a2 = 0, a3 = 0;
  for (int d = 0; d < 1024; ++d) {
    float wv = Wj[(size_t)d * 1024 + e];
    a0 += ls[0][d] * wv; a1 += ls[1][d] * wv; a2 += ls[2][d] * wv; a3 += ls[3][d] * wv;
  }
  q[((size_t)j * 32 + bg * 4 + 0) * 1024 + e] = a0;
  q[((size_t)j * 32 + bg * 4 + 1) * 1024 + e] = a1;
  q[((size_t)j * 32 + bg * 4 + 2) * 1024 + e] = a2;
  q[((size_t)j * 32 + bg * 4 + 3) * 1024 + e] = a3;
}

__global__ __launch_bounds__(256) void att_sc_kernel(const float* q, const float* sent, float* att)
{
  int b = blockIdx.x, j = blockIdx.y;
  __shared__ float qs[1024];
  __shared__ float wsm[256];
  __shared__ float red[8];
  int tid = threadIdx.x, w = tid >> 6, l = tid & 63;
  for (int i = tid; i < 1024; i += 256) qs[i] = q[((size_t)j * 32 + b) * 1024 + i];
  __syncthreads();
  const float* sp = sent + ((size_t)b * 256 + tid) * 1024;
  float dot = 0;
  for (int k = 0; k < 1024; ++k) dot += qs[k] * sp[k];
  float v = dot;
  for (int off = 32; off; off >>= 1) v = fmaxf(v, __shfl_xor(v, off));
  if (l == 0) red[w] = v;
  __syncthreads();
  float m = fmaxf(fmaxf(red[0], red[1]), fmaxf(red[2], red[3]));
  float ex = expf(dot - m);
  float sv = ex;
  for (int off = 32; off; off >>= 1) sv += __shfl_xor(sv, off);
  if (l == 0) red[4 + w] = sv;
  __syncthreads();
  float ssum = red[4] + red[5] + red[6] + red[7];
  wsm[tid] = ex / ssum;
  __syncthreads();
  for (int it = 0; it < 4; ++it) {
    int e = it * 256 + tid;
    float a = 0;
    for (int t2 = 0; t2 < 256; ++t2) a += wsm[t2] * sent[((size_t)b * 256 + t2) * 1024 + e];
    att[((size_t)j * 32 + b) * 1024 + e] = a;
  }
}

// ---------------- head ----------------
__global__ void feat_kernel(const float* s1, const float* s2, const float* s3,
                            const float* tok, const float* atop, const float* att, float* feat)
{
  int i = blockIdx.x * 256 + threadIdx.x;
  int b = i >> 13, jj = (i >> 10) & 7, d = i & 1023;
  int sidx = b * 1024 + d;
  float v;
  switch (jj) {
    case 0: v = s1[sidx]; break;
    case 1: v = s2[sidx]; break;
    case 2: v = s3[sidx]; break;
    case 3: v = tok[d]; break;
    case 4: v = atop[sidx]; break;
    default: v = att[((size_t)(jj - 5) * 32 + b) * 1024 + d];
  }
  feat[i] = v;
}
__global__ __launch_bounds__(256) void head_kernel(const float* feat, const float* W,
                                                   const float* bias, float* fbuf)
{
  int i = blockIdx.x * 256 + threadIdx.x;
  int b = i >> 9, h = i & 511;
  const float* fr = feat + (size_t)b * 8192;
  const float* wr = W + (size_t)h * 8192;
  float a = bias[h];
  for (int k = 0; k < 8192; ++k) a += fr[k] * wr[k];
  fbuf[i] = tanhf(a);
}
__global__ void logits_kernel(const float* fbuf, const float* W, const float* bias, float* out)
{
  int b = blockIdx.x, tid = threadIdx.x;
  __shared__ float lg[20];
  __shared__ float mred, lsred;
  if (tid < 20) {
    const float* fr = fbuf + b * 512;
    const float* wr = W + tid * 512;
    float a = bias[tid];
    for (int k = 0; k < 512; ++k) a += fr[k] * wr[k];
    lg[tid] = a;
  }
  __syncthreads();
  if (tid == 0) {
    float m = lg[0];
    for (int i = 1; i < 20; ++i) m = fmaxf(m, lg[i]);
    float ssum = 0;
    for (int i = 0; i < 20; ++i) ssum += expf(lg[i] - m);
    mred = m; lsred = logf(ssum);
  }
  __syncthreads();
  if (tid < 20) out[b * 20 + tid] = lg[tid] - mred - lsred;
}

// ---------------- host ----------------
extern "C" void kernel_launch(void* const* d_in, const int* in_sizes, int n_in,
                              void* d_out, int out_size, void* d_ws, size_t ws_size,
                              hipStream_t stream)
{
  const float* sentence = (const float*)d_in[0];
  const int* actions = (const int*)d_in[1];
  const float* token_empty = (const float*)d_in[2];
  const float* leaf_Wi = (const float*)d_in[3];
  const float* leaf_bi = (const float*)d_in[4];
  const float* leaf_Wo = (const float*)d_in[5];
  const float* leaf_bo = (const float*)d_in[6];
  const float* lstm_Wih = (const float*)d_in[7];
  const float* lstm_Whh = (const float*)d_in[8];
  const float* lstm_bih = (const float*)d_in[9];
  const float* lstm_bhh = (const float*)d_in[10];
  const float* stack_h0 = (const float*)d_in[11];
  const float* stack_c0 = (const float*)d_in[12];
  const float* act_emb = (const float*)d_in[13];
  const float* act_Wih = (const float*)d_in[14];
  const float* act_Whh = (const float*)d_in[15];
  const float* act_bih = (const float*)d_in[16];
  const float* act_bhh = (const float*)d_in[17];
  const float* act_h0 = (const float*)d_in[18];
  const float* act_c0 = (const float*)d_in[19];
  const float* red_W = (const float*)d_in[20];
  const float* red_b = (const float*)d_in[21];
  const float* h2f_W = (const float*)d_in[22];
  const float* h2f_b = (const float*)d_in[23];
  const float* f2a_W = (const float*)d_in[24];
  const float* f2a_b = (const float*)d_in[25];
  const float* att_W = (const float*)d_in[26];
  float* out = (float*)d_out;
  (void)in_sizes; (void)n_in; (void)out_size; (void)ws_size;

  char* ws = (char*)d_ws;
  size_t off = 0;
  auto alloc = [&](size_t bytes) -> void* {
    void* ptr = ws + off;
    off += (bytes + 255) & ~(size_t)255;
    return ptr;
  };
  // ---- aliased arena (56 MB): phase 1 holds sent_bf|cell_f32|Wx_r (all dead
  // before init_states); phase 2 holds the three h-history buffers (50.5 MB).
  char* arena = (char*)alloc(58720256);
  __hip_bfloat16* sent_bf = (__hip_bfloat16*)arena;                 // 16 MB [8192][1024] (b*256+t)
  float* cell_f32 = (float*)(arena + 16777216);                     // 32 MB [8192][1024] (t*32+b)
  __hip_bfloat16* Wx_r = (__hip_bfloat16*)(arena + 50331648);       //  8 MB
  __hip_bfloat16* sh_hist = (__hip_bfloat16*)arena;                 // [257][32][1024]
  __hip_bfloat16* rh_hist = (__hip_bfloat16*)(arena + 16843008);
  __hip_bfloat16* ah_hist = (__hip_bfloat16*)(arena + 33686016);

  __hip_bfloat16* hid_bf  = (__hip_bfloat16*)alloc(16777216);   // [8192][1024] (t*32+b)
  __hip_bfloat16* lWi_bf = (__hip_bfloat16*)alloc(2097152);
  __hip_bfloat16* lWo_bf = (__hip_bfloat16*)alloc(2097152);
  __hip_bfloat16* Whh_s = (__hip_bfloat16*)alloc(8388608);
  __hip_bfloat16* Wih_s = (__hip_bfloat16*)alloc(8388608);
  __hip_bfloat16* Whh_r = (__hip_bfloat16*)alloc(8388608);
  __hip_bfloat16* Whh_a = (__hip_bfloat16*)alloc(8388608);
  __hip_bfloat16* xgs_blk = (__hip_bfloat16*)alloc(67108864);   // [64][256][2048]
  __hip_bfloat16* xgr_blk = (__hip_bfloat16*)alloc(67108864);
  __hip_bfloat16* cellblk = (__hip_bfloat16*)alloc(16777216);   // [64][256][512]
  float* table = (float*)alloc(327680);
  float* sbias = (float*)alloc(16384);
  float* s1 = (float*)alloc(131072);
  float* s2 = (float*)alloc(131072);
  float* s3 = (float*)alloc(131072);
  float* atop = (float*)alloc(131072);
  unsigned int* flags = (unsigned int*)alloc(1024);
  float* qbuf = (float*)alloc(393216);
  float* attbuf = (float*)alloc(393216);
  float* feat = (float*)alloc(1048576);
  float* fbuf = (float*)alloc(65536);

  // conversions (phase 1 of arena)
  cast_kernel<<<32768, 256, 0, stream>>>(sent_bf, sentence, 8388608);
  cast_kernel<<<4096, 256, 0, stream>>>(lWi_bf, leaf_Wi, 1048576);
  cast_kernel<<<4096, 256, 0, stream>>>(lWo_bf, leaf_Wo, 1048576);
  cast_kernel<<<16384, 256, 0, stream>>>(Whh_s, lstm_Whh, 4194304);
  cast_kernel<<<16384, 256, 0, stream>>>(Wih_s, lstm_Wih, 4194304);
  cast_kernel<<<16384, 256, 0, stream>>>(Whh_a, act_Whh, 4194304);
  extract_half_kernel<<<16384, 256, 0, stream>>>(Whh_r, red_W, 4194304, 2048, 0);
  extract_half_kernel<<<16384, 256, 0, stream>>>(Wx_r, red_W, 4194304, 2048, 1024);
  bias_kernel<<<16, 256, 0, stream>>>(sbias, lstm_bih, lstm_bhh, 4096);
  act_table_kernel<<<320, 256, 0, stream>>>(act_emb, act_Wih, act_bih, act_bhh, table);

  // leaf module (consumes sent_bf, produces+consumes cell_f32)
  gemm_bt_kernel<<<dim3(64, 8), 256, 0, stream>>>(sent_bf, lWi_bf, cell_f32, nullptr,
                                                  leaf_bi, nullptr, 8192, 1024, 1024, 1, 0);
  gemm_bt_kernel<<<dim3(64, 8), 256, 0, stream>>>(sent_bf, lWo_bf, nullptr, hid_bf,
                                                  leaf_bo, cell_f32, 8192, 1024, 1024, 1, 2);
  cellblk_kernel<<<256, 256, 0, stream>>>(cell_f32, cellblk);

  // precomputed x-gates in blk layout (bias folded); xg_r consumes Wx_r (arena)
  gemm_bt_kernel<<<dim3(64, 32), 256, 0, stream>>>(hid_bf, Wih_s, nullptr, xgs_blk,
                                                   sbias, nullptr, 8192, 4096, 1024, 0, 3);
  gemm_bt_kernel<<<dim3(64, 32), 256, 0, stream>>>(hid_bf, Wx_r, nullptr, xgr_blk,
                                                   red_b, nullptr, 8192, 4096, 1024, 0, 3);

  // phase 2 of arena begins: overwrite with history slot 0
  init_states_kernel<<<128, 256, 0, stream>>>(stack_h0, act_h0, hid_bf,
                                              sh_hist, ah_hist, rh_hist, flags);

  PP P;
  P.Whh_s = Whh_s; P.Wih_s = Wih_s; P.Whh_r = Whh_r; P.Whh_a = Whh_a;
  P.xgs_blk = xgs_blk; P.xgr_blk = xgr_blk; P.cellblk = cellblk;
  P.table = table; P.actions = actions;
  P.stack_c0 = stack_c0; P.act_c0 = act_c0; P.sbias = sbias;
  P.sh_hist = sh_hist; P.rh_hist = rh_hist; P.ah_hist = ah_hist;
  P.s1 = s1; P.s2 = s2; P.s3 = s3; P.atop = atop;
  P.flags = flags;
  scan_persist<<<192, 256, 0, stream>>>(P);

  // attention: s1, s2, s3
  att_q_kernel<<<dim3(4, 8, 3), 256, 0, stream>>>(s1, s2, s3, att_W, qbuf);
  att_sc_kernel<<<dim3(32, 3), 256, 0, stream>>>(qbuf, sentence, attbuf);

  // head
  feat_kernel<<<1024, 256, 0, stream>>>(s1, s2, s3, token_empty, atop, attbuf, feat);
  head_kernel<<<64, 256, 0, stream>>>(feat, h2f_W, h2f_b, fbuf);
  logits_kernel<<<32, 64, 0, stream>>>(fbuf, f2a_W, f2a_b, out);
}

// Round 11
// 2677.875 us; speedup vs baseline: 1.3962x; 1.3864x over previous
//
#include <hip/hip_runtime.h>
#include <hip/hip_bf16.h>
#include <math.h>

// B=32, T=256, D=1024, A=64, H=512, NA=20
#define DEV __device__ __forceinline__

typedef __bf16 bf16_t;
typedef bf16_t bf16x8 __attribute__((ext_vector_type(8)));
typedef float f32x4 __attribute__((ext_vector_type(4)));
typedef int i32x4 __attribute__((ext_vector_type(4)));

DEV void async16(const void* g, void* l) {
  __builtin_amdgcn_global_load_lds((const __attribute__((address_space(1))) void*)g,
                                   (__attribute__((address_space(3))) void*)l, 16, 0, 0);
}
DEV float sigmoidf_(float x) { return 1.f / (1.f + expf(-x)); }
DEV bf16x8 as_bf(i32x4 v) { union { i32x4 i; bf16x8 b; } u; u.i = v; return u.b; }

// ---- fine-grained device-coherent ops ----
DEV unsigned flag_load(const unsigned* p) {
  unsigned v;
  asm volatile("global_load_dword %0, %1, off sc0 sc1\ns_waitcnt vmcnt(0)"
               : "=v"(v) : "v"(p) : "memory");
  return v;
}
DEV void store16_sys(void* p, i32x4 v) {
  asm volatile("global_store_dwordx4 %0, %1, off sc0 sc1" :: "v"(p), "v"(v) : "memory");
}

#define WAITV(N) do { asm volatile("s_waitcnt vmcnt(" #N ")" ::: "memory"); \
                      __builtin_amdgcn_sched_barrier(0); } while (0)

// NORMAL cached loads (L1/L2 path). h_hist slots are write-once-before-read per
// dispatch (and bit-identical across graph replays), so no stale-line hazard.
template<int KB>
DEV void loads8(i32x4* dst, const __hip_bfloat16* arow) {
#pragma unroll
  for (int i = 0; i < 8; ++i)
    asm volatile("global_load_dwordx4 %0, %1, off offset:%2"
                 : "=v"(dst[i]) : "v"(arow), "i"((KB + i) * 64));
}
DEV void loads8rt(i32x4* dst, const __hip_bfloat16* arow, int kbase) {
#pragma unroll
  for (int i = 0; i < 8; ++i)
    asm volatile("global_load_dwordx4 %0, %1, off"
                 : "=v"(dst[i]) : "v"(arow + (size_t)(kbase + i) * 32) : "memory");
}

template<int C>
DEV void ldsb8(bf16x8* b0, bf16x8* b1, const __hip_bfloat16* Wl,
               int sw, int kof, int r0, int r1) {
#pragma unroll
  for (int i = 0; i < 8; ++i) {
    const int kk = (C * 8 + i) * 32 + kof;
    b0[i] = *(const bf16x8*)&Wl[r0 * 1024 + (kk ^ sw)];
    b1[i] = *(const bf16x8*)&Wl[r1 * 1024 + (kk ^ sw)];
  }
}
DEV void mfma8x(const i32x4* a, const bf16x8* b0, const bf16x8* b1,
                f32x4& acc0, f32x4& acc1) {
#pragma unroll
  for (int i = 0; i < 8; ++i) {
    bf16x8 av = as_bf(a[i]);
    acc0 = __builtin_amdgcn_mfma_f32_16x16x32_bf16(av, b0[i], acc0, 0, 0, 0);
    acc1 = __builtin_amdgcn_mfma_f32_16x16x32_bf16(av, b1[i], acc1, 0, 0, 0);
  }
}

// K=1024 recurrent GEMM: A (h-state, cached loads, all issued upfront) x W (LDS).
// Counted waits are prefix-agnostic: any loads issued BEFORE this retire first.
DEV void mfma_step(const __hip_bfloat16* Ap, const __hip_bfloat16* Wl,
                   int mh, int nh, int l, f32x4& acc0, f32x4& acc1) {
  const __hip_bfloat16* arow = Ap + (mh * 16 + (l & 15)) * 1024 + (l >> 4) * 8;
  const int sw = (l & 7) << 3, kof = (l >> 4) * 8;
  const int r0 = nh * 32 + (l & 15), r1 = r0 + 16;
  i32x4 A0[8], A1[8], A2[8], A3[8];
  bf16x8 Ba0[8], Ba1[8], Bb0[8], Bb1[8];
  loads8<0>(A0, arow);
  loads8<8>(A1, arow);
  loads8<16>(A2, arow);
  loads8<24>(A3, arow);
  ldsb8<0>(Ba0, Ba1, Wl, sw, kof, r0, r1);
  WAITV(24);
  mfma8x(A0, Ba0, Ba1, acc0, acc1);
  ldsb8<1>(Bb0, Bb1, Wl, sw, kof, r0, r1);
  WAITV(16);
  mfma8x(A1, Bb0, Bb1, acc0, acc1);
  ldsb8<2>(Ba0, Ba1, Wl, sw, kof, r0, r1);
  WAITV(8);
  mfma8x(A2, Ba0, Ba1, acc0, acc1);
  ldsb8<3>(Bb0, Bb1, Wl, sw, kof, r0, r1);
  WAITV(0);
  mfma8x(A3, Bb0, Bb1, acc0, acc1);
}

// final-phase pass: A cached loads, W from global (cached)
DEV void mfma_pass_glb(const __hip_bfloat16* Ap, const __hip_bfloat16* __restrict__ Wg,
                       int d0, int mh, int nh, int l, f32x4& acc0, f32x4& acc1) {
  const __hip_bfloat16* arow = Ap + (mh * 16 + (l & 15)) * 1024 + (l >> 4) * 8;
  const size_t g0 = ((size_t)(2 * nh) * 1024 + d0 + (l & 15)) * 1024;
  const size_t g1 = g0 + 1048576;
  const int kof = (l >> 4) * 8;
  i32x4 A[8];
  for (int c = 0; c < 4; ++c) {
    loads8rt(A, arow, c * 8);
    WAITV(0);
#pragma unroll
    for (int i = 0; i < 8; ++i) {
      const int kk = (c * 8 + i) * 32 + kof;
      bf16x8 b0 = *(const bf16x8*)&Wg[g0 + kk];
      bf16x8 b1 = *(const bf16x8*)&Wg[g1 + kk];
      bf16x8 av = as_bf(A[i]);
      acc0 = __builtin_amdgcn_mfma_f32_16x16x32_bf16(av, b0, acc0, 0, 0, 0);
      acc1 = __builtin_amdgcn_mfma_f32_16x16x32_bf16(av, b1, acc1, 0, 0, 0);
    }
  }
}

// ---------------- generic bf16 MFMA GEMM: C[M,N] = A[M,K] @ Bw[N,K]^T + bias ----------------
// mode 0: outF = acc+bias (f32); mode 1: outBF = bf16(acc+bias)
// mode 2: outBF = bf16(sigmoid(acc+bias)*tanh(aux))
// mode 3: outBF is blk layout [slot][256 t][2048] chunk [g*512 + b*16 + dd]; rows must be t*32+b
__global__ __launch_bounds__(256) void gemm_bt_kernel(
    const __hip_bfloat16* __restrict__ A, const __hip_bfloat16* __restrict__ Bw,
    float* __restrict__ outF, __hip_bfloat16* __restrict__ outBF,
    const float* __restrict__ bias, const float* __restrict__ aux,
    int M, int N, int K, int remap, int mode)
{
  __shared__ __hip_bfloat16 As[128 * 64];
  __shared__ __hip_bfloat16 Bs[128 * 64];
  __shared__ __hip_bfloat16 Cs[128 * 128];   // mode-3 staging only
  const int tid = threadIdx.x;
  const int w = tid >> 6, l = tid & 63;
  const int m0 = blockIdx.x * 128, n0 = blockIdx.y * 128;
  const int wm = (w >> 1) * 64, wn = (w & 1) * 64;
  const int row_s = tid >> 3, kc = tid & 7;
  f32x4 acc[4][4] = {};
  for (int k0 = 0; k0 < K; k0 += 64) {
    const __hip_bfloat16* ga = A + (size_t)(m0 + row_s) * K + k0 + kc * 8;
    const __hip_bfloat16* gb = Bw + (size_t)(n0 + row_s) * K + k0 + kc * 8;
    __hip_bfloat16* la = As + w * 512;
    __hip_bfloat16* lb = Bs + w * 512;
#pragma unroll
    for (int p = 0; p < 4; ++p) {
      async16(ga + (size_t)p * 32 * K, la + p * 2048);
      async16(gb + (size_t)p * 32 * K, lb + p * 2048);
    }
    __syncthreads();
#pragma unroll
    for (int kb = 0; kb < 2; ++kb) {
      bf16x8 af[4], bfr[4];
#pragma unroll
      for (int i = 0; i < 4; ++i)
        af[i] = *(const bf16x8*)&As[(wm + i * 16 + (l & 15)) * 64 + kb * 32 + (l >> 4) * 8];
#pragma unroll
      for (int j = 0; j < 4; ++j)
        bfr[j] = *(const bf16x8*)&Bs[(wn + j * 16 + (l & 15)) * 64 + kb * 32 + (l >> 4) * 8];
#pragma unroll
      for (int i = 0; i < 4; ++i)
#pragma unroll
        for (int j = 0; j < 4; ++j)
          acc[i][j] = __builtin_amdgcn_mfma_f32_16x16x32_bf16(af[i], bfr[j], acc[i][j], 0, 0, 0);
    }
    __syncthreads();
  }
  if (mode == 3) {
#pragma unroll
    for (int i = 0; i < 4; ++i)
#pragma unroll
      for (int j = 0; j < 4; ++j) {
        const int ncol = n0 + wn + j * 16 + (l & 15);
        const float bv = bias[ncol];
#pragma unroll
        for (int r = 0; r < 4; ++r) {
          const int lr = wm + i * 16 + (l >> 4) * 4 + r;
          Cs[lr * 128 + wn + j * 16 + (l & 15)] = __float2bfloat16(acc[i][j][r] + bv);
        }
      }
    __syncthreads();
    const int t0 = m0 >> 5, g = n0 >> 10, slot0 = (n0 & 1023) >> 4;
    const int grp = tid >> 6, li = tid & 63;
    const int b = li >> 1, half = li & 1;
#pragma unroll
    for (int sl = 0; sl < 8; ++sl) {
      bf16x8 vv = *(const bf16x8*)&Cs[(grp * 32 + b) * 128 + sl * 16 + half * 8];
      *(bf16x8*)&outBF[(((size_t)(slot0 + sl)) * 256 + t0 + grp) * 2048 +
                       g * 512 + b * 16 + half * 8] = vv;
    }
    return;
  }
#pragma unroll
  for (int i = 0; i < 4; ++i) {
#pragma unroll
    for (int j = 0; j < 4; ++j) {
      const int ncol = n0 + wn + j * 16 + (l & 15);
      const float bv = bias ? bias[ncol] : 0.f;
#pragma unroll
      for (int r = 0; r < 4; ++r) {
        int m = m0 + wm + i * 16 + (l >> 4) * 4 + r;
        int row = remap ? (((m & 255) << 5) | (m >> 8)) : m;
        float v = acc[i][j][r] + bv;
        if (mode == 0) {
          outF[(size_t)row * N + ncol] = v;
        } else if (mode == 1) {
          outBF[(size_t)row * N + ncol] = __float2bfloat16(v);
        } else {
          float cv = aux[(size_t)row * N + ncol];
          outBF[(size_t)row * N + ncol] = __float2bfloat16(sigmoidf_(v) * tanhf(cv));
        }
      }
    }
  }
}

// cell [8192][1024] f32 (rows t*32+b) -> blk [64 slot][256 t][32 b][16 dd] bf16
__global__ __launch_bounds__(256) void cellblk_kernel(const float* __restrict__ cell,
                                                      __hip_bfloat16* __restrict__ blk)
{
  __shared__ __hip_bfloat16 ls[32 * 1024];   // 64 KB
  const int t = blockIdx.x, tid = threadIdx.x;
  for (int i = tid; i < 32 * 1024; i += 256)
    ls[i] = __float2bfloat16(cell[(size_t)t * 32768 + i]);
  __syncthreads();
  const int e = tid * 2;
  const int b = e >> 4, dd = e & 15;
  for (int sl = 0; sl < 64; ++sl) {
    union { __hip_bfloat16 h[2]; unsigned u; } pk;
    pk.h[0] = ls[b * 1024 + sl * 16 + dd];
    pk.h[1] = ls[b * 1024 + sl * 16 + dd + 1];
    *(unsigned*)&blk[((size_t)sl * 256 + t) * 512 + e] = pk.u;
  }
}

// ---------------- persistent scan ----------------
struct PP {
  const __hip_bfloat16 *Whh_s, *Wih_s, *Whh_r, *Whh_a;  // [4096][1024]
  const __hip_bfloat16 *xgs_blk, *xgr_blk;  // [64][256][2048] blk-layout x-gates
  const __hip_bfloat16* cellblk; // [64][256][512] blk-layout bf16 cell
  const float* table;            // [20][4096]
  const int* actions;            // [32][256]
  const float *stack_c0, *act_c0, *sbias;
  __hip_bfloat16 *sh_hist, *rh_hist, *ah_hist;  // [257][32][1024] h history
  float *s1, *s2, *s3, *atop;    // [32][1024] f32
  unsigned int* flags;           // counters at flags[scan*32] (128B apart)
};

__global__ __launch_bounds__(256, 1) void scan_persist(PP P)
{
  __shared__ __hip_bfloat16 Wl[64 * 1024];             // 128 KB, XOR-swizzled
  __shared__ float gsm[32][16][4];                     // 8 KB gate exchange
  __shared__ __align__(16) __hip_bfloat16 hstage[32][16];  // 1 KB packed h staging
  const int bid = blockIdx.x;
  const int scan = bid >> 6;                 // 0 stack, 1 reduce, 2 action
  const int slot = bid & 63;
  const int d0 = slot * 16;
  const int tid = threadIdx.x;
  const int l = tid & 63, w = tid >> 6;
  const int mh = w >> 1, nh = w & 1;

  const __hip_bfloat16* Wg = (scan == 0) ? P.Whh_s : ((scan == 1) ? P.Whh_r : P.Whh_a);
  for (int idx = tid; idx < 64 * 128; idx += 256) {
    int r = idx >> 7, k = (idx & 127) * 8;
    int grow = ((r >> 4) << 10) + d0 + (r & 15);
    bf16x8 v = *(const bf16x8*)&Wg[(size_t)grow * 1024 + k];
    *(bf16x8*)&Wl[r * 1024 + (k ^ ((r & 7) << 3))] = v;
  }
  const int e0 = tid, e1 = tid + 256;
  const int b0_ = e0 >> 4, dd0 = e0 & 15, b1_ = e1 >> 4, dd1 = e1 & 15;
  float creg0, creg1;
  if (scan == 0)      { creg0 = P.stack_c0[d0 + dd0]; creg1 = P.stack_c0[d0 + dd1]; }
  else if (scan == 1) {
    creg0 = __bfloat162float(P.cellblk[(size_t)slot * 256 * 512 + b0_ * 16 + dd0]);
    creg1 = __bfloat162float(P.cellblk[(size_t)slot * 256 * 512 + b1_ * 16 + dd1]);
  }
  else                { creg0 = P.act_c0[d0 + dd0]; creg1 = P.act_c0[d0 + dd1]; }
  __syncthreads();

  __hip_bfloat16* hist = (scan == 0) ? P.sh_hist : ((scan == 1) ? P.rh_hist : P.ah_hist);
  unsigned int* ctr = P.flags + scan * 32;   // 128B-separated arrival counters
  const int Ns = (scan == 1) ? 255 : 256;
  const int mbase = mh * 16 + (l >> 4) * 4;

  for (int s = 0; s < Ns; ++s) {
    const __hip_bfloat16* Ap = hist + (size_t)s * 32768;
    __hip_bfloat16* Hout = hist + (size_t)(s + 1) * 32768;

    // ---- prefix gate prefetch: plain loads, compiler-managed waits.
    // Issued BEFORE mfma_step's A-loads (sched_barrier pins order), so the
    // hand-counted vmcnt(N) waits inside mfma_step remain suffix-correct.
    __hip_bfloat16 pg0, pg1, pg2, pg3, pg4, pg5, pg6, pg7;
    __hip_bfloat16 pcb0, pcb1;
    int pa0 = 0, pa1 = 0;
    pg0 = pg1 = pg2 = pg3 = pg4 = pg5 = pg6 = pg7 = __float2bfloat16(0.f);
    pcb0 = pcb1 = __float2bfloat16(0.f);
    if (scan == 0) {
      const __hip_bfloat16* x0 = P.xgs_blk + ((size_t)slot * 256 + s) * 2048 + b0_ * 16 + dd0;
      const __hip_bfloat16* x1 = P.xgs_blk + ((size_t)slot * 256 + s) * 2048 + b1_ * 16 + dd1;
      pg0 = x0[0]; pg1 = x0[512]; pg2 = x0[1024]; pg3 = x0[1536];
      pg4 = x1[0]; pg5 = x1[512]; pg6 = x1[1024]; pg7 = x1[1536];
    } else if (scan == 1) {
      const __hip_bfloat16* x0 = P.xgr_blk + ((size_t)slot * 256 + s + 1) * 2048 + b0_ * 16 + dd0;
      const __hip_bfloat16* x1 = P.xgr_blk + ((size_t)slot * 256 + s + 1) * 2048 + b1_ * 16 + dd1;
      pg0 = x0[0]; pg1 = x0[512]; pg2 = x0[1024]; pg3 = x0[1536];
      pg4 = x1[0]; pg5 = x1[512]; pg6 = x1[1024]; pg7 = x1[1536];
      pcb0 = P.cellblk[((size_t)slot * 256 + s + 1) * 512 + b0_ * 16 + dd0];
      pcb1 = P.cellblk[((size_t)slot * 256 + s + 1) * 512 + b1_ * 16 + dd1];
    } else {
      pa0 = P.actions[b0_ * 256 + s];
      pa1 = P.actions[b1_ * 256 + s];
    }
    __builtin_amdgcn_sched_barrier(0);

    f32x4 acc0 = {}, acc1 = {};
    mfma_step(Ap, Wl, mh, nh, l, acc0, acc1);
#pragma unroll
    for (int r = 0; r < 4; ++r) {
      gsm[mbase + r][l & 15][nh * 2 + 0] = acc0[r];
      gsm[mbase + r][l & 15][nh * 2 + 1] = acc1[r];
    }
    __syncthreads();
#pragma unroll
    for (int q = 0; q < 2; ++q) {
      const int b = q ? b1_ : b0_, dd = q ? dd1 : dd0;
      const int d = d0 + dd;
      float& creg = q ? creg1 : creg0;
      float g0 = gsm[b][dd][0], g1 = gsm[b][dd][1], g2 = gsm[b][dd][2], g3 = gsm[b][dd][3];
      if (scan == 1) {
        float ig = sigmoidf_(g0 + __bfloat162float(q ? pg4 : pg0));
        float lg = sigmoidf_(g1 + __bfloat162float(q ? pg5 : pg1));
        float rg = sigmoidf_(g2 + __bfloat162float(q ? pg6 : pg2));
        float cand = tanhf(g3 + __bfloat162float(q ? pg7 : pg3));
        float rcv = __bfloat162float(q ? pcb1 : pcb0);
        float c2 = ig * cand + lg * creg + rg * rcv;
        creg = c2;
        hstage[b][dd] = __float2bfloat16(tanhf(c2));
      } else {
        float bi0, bi1, bi2, bi3;
        if (scan == 0) {
          bi0 = __bfloat162float(q ? pg4 : pg0); bi1 = __bfloat162float(q ? pg5 : pg1);
          bi2 = __bfloat162float(q ? pg6 : pg2); bi3 = __bfloat162float(q ? pg7 : pg3);
        } else {
          int a = q ? pa1 : pa0;
          const float* tb = P.table + a * 4096;
          bi0 = tb[d]; bi1 = tb[1024 + d]; bi2 = tb[2048 + d]; bi3 = tb[3072 + d];
        }
        float c2 = sigmoidf_(g1 + bi1) * creg + sigmoidf_(g0 + bi0) * tanhf(g2 + bi2);
        float h2 = sigmoidf_(g3 + bi3) * tanhf(c2);
        creg = c2;
        hstage[b][dd] = __float2bfloat16(h2);
        if (scan == 0 && s == 254) P.s3[b * 1024 + d] = h2;
        if (scan == 0 && s == 255) P.s2[b * 1024 + d] = h2;
        if (scan == 2 && s == 255) P.atop[b * 1024 + d] = h2;
      }
    }
    __syncthreads();
    // ---- packed 16B device-coherent h stores (wave 0 only) ----
    if (tid < 64) {
      const int bb = tid >> 1, hf = tid & 1;
      union { bf16x8 b8; i32x4 i4; } u;
      u.b8 = *(const bf16x8*)&hstage[bb][hf * 8];
      store16_sys(Hout + bb * 1024 + d0 + hf * 8, u.i4);
    }
    asm volatile("s_waitcnt vmcnt(0)" ::: "memory");
    __syncthreads();
    // ---- aggregated barrier: 1 relaxed atomic arrival + 1 polling lane ----
    if (tid == 0) {
      __hip_atomic_fetch_add(ctr, 1u, __ATOMIC_RELAXED, __HIP_MEMORY_SCOPE_AGENT);
      const unsigned tgt = 64u * (unsigned)(s + 1);
      while (flag_load(ctr) < tgt) __builtin_amdgcn_s_sleep(1);
    }
    __syncthreads();
  }

  if (scan == 0) {
    if (tid == 0) {
      while (flag_load(P.flags + 32) < 64u * 255u) __builtin_amdgcn_s_sleep(1);
    }
    __syncthreads();
    f32x4 acc0 = {}, acc1 = {};
    mfma_step(P.sh_hist + (size_t)256 * 32768, Wl, mh, nh, l, acc0, acc1);       // hf @ Whh^T
    mfma_pass_glb(P.rh_hist + (size_t)255 * 32768, P.Wih_s, d0, mh, nh, l, acc0, acc1); // red_h @ Wih^T
#pragma unroll
    for (int r = 0; r < 4; ++r) {
      gsm[mbase + r][l & 15][nh * 2 + 0] = acc0[r];
      gsm[mbase + r][l & 15][nh * 2 + 1] = acc1[r];
    }
    __syncthreads();
#pragma unroll
    for (int q = 0; q < 2; ++q) {
      const int b = q ? b1_ : b0_, dd = q ? dd1 : dd0;
      const int d = d0 + dd;
      float creg = q ? creg1 : creg0;   // cf
      float g0 = gsm[b][dd][0], g1 = gsm[b][dd][1], g2 = gsm[b][dd][2], g3 = gsm[b][dd][3];
      float bi0 = P.sbias[d], bi1 = P.sbias[1024 + d], bi2 = P.sbias[2048 + d], bi3 = P.sbias[3072 + d];
      float c2 = sigmoidf_(g1 + bi1) * creg + sigmoidf_(g0 + bi0) * tanhf(g2 + bi2);
      float h2 = sigmoidf_(g3 + bi3) * tanhf(c2);
      P.s1[b * 1024 + d] = h2;
    }
  }
}

// ---------------- small utility kernels ----------------
__global__ void cast_kernel(__hip_bfloat16* dst, const float* src, int n) {
  int i = blockIdx.x * 256 + threadIdx.x;
  if (i < n) dst[i] = __float2bfloat16(src[i]);
}
__global__ void extract_half_kernel(__hip_bfloat16* dst, const float* src, int n,
                                    int src_stride, int src_off) {
  int i = blockIdx.x * 256 + threadIdx.x;
  if (i < n) {
    int r = i >> 10, k = i & 1023;
    dst[i] = __float2bfloat16(src[(size_t)r * src_stride + src_off + k]);
  }
}
__global__ void bias_kernel(float* dst, const float* a, const float* b, int n) {
  int i = blockIdx.x * 256 + threadIdx.x;
  if (i < n) dst[i] = a[i] + b[i];
}
__global__ void act_table_kernel(const float* emb, const float* Wih, const float* bih,
                                 const float* bhh, float* table) {
  int i = blockIdx.x * 256 + threadIdx.x;
  int a = i >> 12, n = i & 4095;
  float acc = bih[n] + bhh[n];
  const float* er = emb + a * 64;
  const float* wr = Wih + (size_t)n * 64;
  for (int k = 0; k < 64; ++k) acc += er[k] * wr[k];
  table[i] = acc;
}
// fills history slot 0 for all three scans: stack h0, action h0, reduce = hid_t[0]
__global__ void init_states_kernel(const float* stack_h0, const float* act_h0,
                                   const __hip_bfloat16* hid,
                                   __hip_bfloat16* sh0, __hip_bfloat16* ah0,
                                   __hip_bfloat16* rh0, unsigned int* flags)
{
  int i = blockIdx.x * 256 + threadIdx.x;  // 32768
  int d = i & 1023;
  sh0[i] = __float2bfloat16(stack_h0[d]);
  ah0[i] = __float2bfloat16(act_h0[d]);
  rh0[i] = hid[i];
  if (i < 192) flags[i] = 0u;
}

// ---------------- attention ----------------
__global__ __launch_bounds__(256) void att_q_kernel(
    const float* s1, const float* s2, const float* s3, const float* attW, float* q)
{
  int eb = blockIdx.x, bg = blockIdx.y, j = blockIdx.z;
  const float* sj = (j == 0) ? s1 : ((j == 1) ? s2 : s3);
  __shared__ float ls[4][1024];
  int tid = threadIdx.x;
  for (int i = tid; i < 4096; i += 256)
    ls[i >> 10][i & 1023] = sj[(size_t)(bg * 4 + (i >> 10)) * 1024 + (i & 1023)];
  __syncthreads();
  int e = eb * 256 + tid;
  const float* Wj = attW + (size_t)j * 1024 * 1024;
  float a0 = 0, a1 = 0, a2 = 0, a3 = 0;
  for (int d = 0; d < 1024; ++d) {
    float wv = Wj[(size_t)d * 1024 + e];
    a0 += ls[0][d] * wv; a1 += ls[1][d] * wv; a2 += ls[2][d] * wv; a3 += ls[3][d] * wv;
  }
  q[((size_t)j * 32 + bg * 4 + 0) * 1024 + e] = a0;
  q[((size_t)j * 32 + bg * 4 + 1) * 1024 + e] = a1;
  q[((size_t)j * 32 + bg * 4 + 2) * 1024 + e] = a2;
  q[((size_t)j * 32 + bg * 4 + 3) * 1024 + e] = a3;
}

__global__ __launch_bounds__(256) void att_sc_kernel(const float* q, const float* sent, float* att)
{
  int b = blockIdx.x, j = blockIdx.y;
  __shared__ float qs[1024];
  __shared__ float wsm[256];
  __shared__ float red[8];
  int tid = threadIdx.x, w = tid >> 6, l = tid & 63;
  for (int i = tid; i < 1024; i += 256) qs[i] = q[((size_t)j * 32 + b) * 1024 + i];
  __syncthreads();
  const float* sp = sent + ((size_t)b * 256 + tid) * 1024;
  float dot = 0;
  for (int k = 0; k < 1024; ++k) dot += qs[k] * sp[k];
  float v = dot;
  for (int off = 32; off; off >>= 1) v = fmaxf(v, __shfl_xor(v, off));
  if (l == 0) red[w] = v;
  __syncthreads();
  float m = fmaxf(fmaxf(red[0], red[1]), fmaxf(red[2], red[3]));
  float ex = expf(dot - m);
  float sv = ex;
  for (int off = 32; off; off >>= 1) sv += __shfl_xor(sv, off);
  if (l == 0) red[4 + w] = sv;
  __syncthreads();
  float ssum = red[4] + red[5] + red[6] + red[7];
  wsm[tid] = ex / ssum;
  __syncthreads();
  for (int it = 0; it < 4; ++it) {
    int e = it * 256 + tid;
    float a = 0;
    for (int t2 = 0; t2 < 256; ++t2) a += wsm[t2] * sent[((size_t)b * 256 + t2) * 1024 + e];
    att[((size_t)j * 32 + b) * 1024 + e] = a;
  }
}

// ---------------- head ----------------
__global__ void feat_kernel(const float* s1, const float* s2, const float* s3,
                            const float* tok, const float* atop, const float* att, float* feat)
{
  int i = blockIdx.x * 256 + threadIdx.x;
  int b = i >> 13, jj = (i >> 10) & 7, d = i & 1023;
  int sidx = b * 1024 + d;
  float v;
  switch (jj) {
    case 0: v = s1[sidx]; break;
    case 1: v = s2[sidx]; break;
    case 2: v = s3[sidx]; break;
    case 3: v = tok[d]; break;
    case 4: v = atop[sidx]; break;
    default: v = att[((size_t)(jj - 5) * 32 + b) * 1024 + d];
  }
  feat[i] = v;
}
__global__ __launch_bounds__(256) void head_kernel(const float* feat, const float* W,
                                                   const float* bias, float* fbuf)
{
  int i = blockIdx.x * 256 + threadIdx.x;
  int b = i >> 9, h = i & 511;
  const float* fr = feat + (size_t)b * 8192;
  const float* wr = W + (size_t)h * 8192;
  float a = bias[h];
  for (int k = 0; k < 8192; ++k) a += fr[k] * wr[k];
  fbuf[i] = tanhf(a);
}
__global__ void logits_kernel(const float* fbuf, const float* W, const float* bias, float* out)
{
  int b = blockIdx.x, tid = threadIdx.x;
  __shared__ float lg[20];
  __shared__ float mred, lsred;
  if (tid < 20) {
    const float* fr = fbuf + b * 512;
    const float* wr = W + tid * 512;
    float a = bias[tid];
    for (int k = 0; k < 512; ++k) a += fr[k] * wr[k];
    lg[tid] = a;
  }
  __syncthreads();
  if (tid == 0) {
    float m = lg[0];
    for (int i = 1; i < 20; ++i) m = fmaxf(m, lg[i]);
    float ssum = 0;
    for (int i = 0; i < 20; ++i) ssum += expf(lg[i] - m);
    mred = m; lsred = logf(ssum);
  }
  __syncthreads();
  if (tid < 20) out[b * 20 + tid] = lg[tid] - mred - lsred;
}

// ---------------- host ----------------
extern "C" void kernel_launch(void* const* d_in, const int* in_sizes, int n_in,
                              void* d_out, int out_size, void* d_ws, size_t ws_size,
                              hipStream_t stream)
{
  const float* sentence = (const float*)d_in[0];
  const int* actions = (const int*)d_in[1];
  const float* token_empty = (const float*)d_in[2];
  const float* leaf_Wi = (const float*)d_in[3];
  const float* leaf_bi = (const float*)d_in[4];
  const float* leaf_Wo = (const float*)d_in[5];
  const float* leaf_bo = (const float*)d_in[6];
  const float* lstm_Wih = (const float*)d_in[7];
  const float* lstm_Whh = (const float*)d_in[8];
  const float* lstm_bih = (const float*)d_in[9];
  const float* lstm_bhh = (const float*)d_in[10];
  const float* stack_h0 = (const float*)d_in[11];
  const float* stack_c0 = (const float*)d_in[12];
  const float* act_emb = (const float*)d_in[13];
  const float* act_Wih = (const float*)d_in[14];
  const float* act_Whh = (const float*)d_in[15];
  const float* act_bih = (const float*)d_in[16];
  const float* act_bhh = (const float*)d_in[17];
  const float* act_h0 = (const float*)d_in[18];
  const float* act_c0 = (const float*)d_in[19];
  const float* red_W = (const float*)d_in[20];
  const float* red_b = (const float*)d_in[21];
  const float* h2f_W = (const float*)d_in[22];
  const float* h2f_b = (const float*)d_in[23];
  const float* f2a_W = (const float*)d_in[24];
  const float* f2a_b = (const float*)d_in[25];
  const float* att_W = (const float*)d_in[26];
  float* out = (float*)d_out;
  (void)in_sizes; (void)n_in; (void)out_size; (void)ws_size;

  char* ws = (char*)d_ws;
  size_t off = 0;
  auto alloc = [&](size_t bytes) -> void* {
    void* ptr = ws + off;
    off += (bytes + 255) & ~(size_t)255;
    return ptr;
  };
  // ---- aliased arena (56 MB): phase 1 holds sent_bf|cell_f32|Wx_r (all dead
  // before init_states); phase 2 holds the three h-history buffers (50.5 MB).
  char* arena = (char*)alloc(58720256);
  __hip_bfloat16* sent_bf = (__hip_bfloat16*)arena;                 // 16 MB
  float* cell_f32 = (float*)(arena + 16777216);                     // 32 MB
  __hip_bfloat16* Wx_r = (__hip_bfloat16*)(arena + 50331648);       //  8 MB
  __hip_bfloat16* sh_hist = (__hip_bfloat16*)arena;                 // [257][32][1024]
  __hip_bfloat16* rh_hist = (__hip_bfloat16*)(arena + 16843008);
  __hip_bfloat16* ah_hist = (__hip_bfloat16*)(arena + 33686016);

  __hip_bfloat16* hid_bf  = (__hip_bfloat16*)alloc(16777216);   // [8192][1024] (t*32+b)
  __hip_bfloat16* lWi_bf = (__hip_bfloat16*)alloc(2097152);
  __hip_bfloat16* lWo_bf = (__hip_bfloat16*)alloc(2097152);
  __hip_bfloat16* Whh_s = (__hip_bfloat16*)alloc(8388608);
  __hip_bfloat16* Wih_s = (__hip_bfloat16*)alloc(8388608);
  __hip_bfloat16* Whh_r = (__hip_bfloat16*)alloc(8388608);
  __hip_bfloat16* Whh_a = (__hip_bfloat16*)alloc(8388608);
  __hip_bfloat16* xgs_blk = (__hip_bfloat16*)alloc(67108864);   // [64][256][2048]
  __hip_bfloat16* xgr_blk = (__hip_bfloat16*)alloc(67108864);
  __hip_bfloat16* cellblk = (__hip_bfloat16*)alloc(16777216);   // [64][256][512]
  float* table = (float*)alloc(327680);
  float* sbias = (float*)alloc(16384);
  float* s1 = (float*)alloc(131072);
  float* s2 = (float*)alloc(131072);
  float* s3 = (float*)alloc(131072);
  float* atop = (float*)alloc(131072);
  unsigned int* flags = (unsigned int*)alloc(1024);
  float* qbuf = (float*)alloc(393216);
  float* attbuf = (float*)alloc(393216);
  float* feat = (float*)alloc(1048576);
  float* fbuf = (float*)alloc(65536);

  // conversions (phase 1 of arena)
  cast_kernel<<<32768, 256, 0, stream>>>(sent_bf, sentence, 8388608);
  cast_kernel<<<4096, 256, 0, stream>>>(lWi_bf, leaf_Wi, 1048576);
  cast_kernel<<<4096, 256, 0, stream>>>(lWo_bf, leaf_Wo, 1048576);
  cast_kernel<<<16384, 256, 0, stream>>>(Whh_s, lstm_Whh, 4194304);
  cast_kernel<<<16384, 256, 0, stream>>>(Wih_s, lstm_Wih, 4194304);
  cast_kernel<<<16384, 256, 0, stream>>>(Whh_a, act_Whh, 4194304);
  extract_half_kernel<<<16384, 256, 0, stream>>>(Whh_r, red_W, 4194304, 2048, 0);
  extract_half_kernel<<<16384, 256, 0, stream>>>(Wx_r, red_W, 4194304, 2048, 1024);
  bias_kernel<<<16, 256, 0, stream>>>(sbias, lstm_bih, lstm_bhh, 4096);
  act_table_kernel<<<320, 256, 0, stream>>>(act_emb, act_Wih, act_bih, act_bhh, table);

  // leaf module (consumes sent_bf, produces+consumes cell_f32)
  gemm_bt_kernel<<<dim3(64, 8), 256, 0, stream>>>(sent_bf, lWi_bf, cell_f32, nullptr,
                                                  leaf_bi, nullptr, 8192, 1024, 1024, 1, 0);
  gemm_bt_kernel<<<dim3(64, 8), 256, 0, stream>>>(sent_bf, lWo_bf, nullptr, hid_bf,
                                                  leaf_bo, cell_f32, 8192, 1024, 1024, 1, 2);
  cellblk_kernel<<<256, 256, 0, stream>>>(cell_f32, cellblk);

  // precomputed x-gates in blk layout (bias folded); xg_r consumes Wx_r (arena)
  gemm_bt_kernel<<<dim3(64, 32), 256, 0, stream>>>(hid_bf, Wih_s, nullptr, xgs_blk,
                                                   sbias, nullptr, 8192, 4096, 1024, 0, 3);
  gemm_bt_kernel<<<dim3(64, 32), 256, 0, stream>>>(hid_bf, Wx_r, nullptr, xgr_blk,
                                                   red_b, nullptr, 8192, 4096, 1024, 0, 3);

  // phase 2 of arena begins: overwrite with history slot 0
  init_states_kernel<<<128, 256, 0, stream>>>(stack_h0, act_h0, hid_bf,
                                              sh_hist, ah_hist, rh_hist, flags);

  PP P;
  P.Whh_s = Whh_s; P.Wih_s = Wih_s; P.Whh_r = Whh_r; P.Whh_a = Whh_a;
  P.xgs_blk = xgs_blk; P.xgr_blk = xgr_blk; P.cellblk = cellblk;
  P.table = table; P.actions = actions;
  P.stack_c0 = stack_c0; P.act_c0 = act_c0; P.sbias = sbias;
  P.sh_hist = sh_hist; P.rh_hist = rh_hist; P.ah_hist = ah_hist;
  P.s1 = s1; P.s2 = s2; P.s3 = s3; P.atop = atop;
  P.flags = flags;
  scan_persist<<<192, 256, 0, stream>>>(P);

  // attention: s1, s2, s3
  att_q_kernel<<<dim3(4, 8, 3), 256, 0, stream>>>(s1, s2, s3, att_W, qbuf);
  att_sc_kernel<<<dim3(32, 3), 256, 0, stream>>>(qbuf, sentence, attbuf);

  // head
  feat_kernel<<<1024, 256, 0, stream>>>(s1, s2, s3, token_empty, atop, attbuf, feat);
  head_kernel<<<64, 256, 0, stream>>>(feat, h2f_W, h2f_b, fbuf);
  logits_kernel<<<32, 64, 0, stream>>>(fbuf, f2a_W, f2a_b, out);
}

// Round 12
// 2586.141 us; speedup vs baseline: 1.4458x; 1.0355x over previous
//
#include <hip/hip_runtime.h>
#include <hip/hip_bf16.h>
#include <math.h>

// B=32, T=256, D=1024, A=64, H=512, NA=20
#define DEV __device__ __forceinline__

typedef __bf16 bf16_t;
typedef bf16_t bf16x8 __attribute__((ext_vector_type(8)));
typedef float f32x4 __attribute__((ext_vector_type(4)));
typedef int i32x4 __attribute__((ext_vector_type(4)));

DEV void async16(const void* g, void* l) {
  __builtin_amdgcn_global_load_lds((const __attribute__((address_space(1))) void*)g,
                                   (__attribute__((address_space(3))) void*)l, 16, 0, 0);
}
DEV float sigmoidf_(float x) { return 1.f / (1.f + expf(-x)); }
DEV bf16x8 as_bf(i32x4 v) { union { i32x4 i; bf16x8 b; } u; u.i = v; return u.b; }

// ---- fine-grained device-coherent ops ----
DEV unsigned flag_load(const unsigned* p) {
  unsigned v;
  asm volatile("global_load_dword %0, %1, off sc0 sc1\ns_waitcnt vmcnt(0)"
               : "=v"(v) : "v"(p) : "memory");
  return v;
}
DEV void flag_store(unsigned* p, unsigned v) {
  asm volatile("global_store_dword %0, %1, off sc0 sc1" :: "v"(p), "v"(v) : "memory");
}
DEV void store16_sys(void* p, i32x4 v) {
  asm volatile("global_store_dwordx4 %0, %1, off sc0 sc1" :: "v"(p), "v"(v) : "memory");
}

#define WAITV(N) do { asm volatile("s_waitcnt vmcnt(" #N ")" ::: "memory"); \
                      __builtin_amdgcn_sched_barrier(0); } while (0)

// NORMAL cached loads (L1/L2 path). h_hist slots are write-once-before-read per
// dispatch (and bit-identical across graph replays), so no stale-line hazard.
template<int KB>
DEV void loads8(i32x4* dst, const __hip_bfloat16* arow) {
#pragma unroll
  for (int i = 0; i < 8; ++i)
    asm volatile("global_load_dwordx4 %0, %1, off offset:%2"
                 : "=v"(dst[i]) : "v"(arow), "i"((KB + i) * 64));
}
DEV void loads8rt(i32x4* dst, const __hip_bfloat16* arow, int kbase) {
#pragma unroll
  for (int i = 0; i < 8; ++i)
    asm volatile("global_load_dwordx4 %0, %1, off"
                 : "=v"(dst[i]) : "v"(arow + (size_t)(kbase + i) * 32) : "memory");
}

template<int C>
DEV void ldsb8(bf16x8* b0, bf16x8* b1, const __hip_bfloat16* Wl,
               int sw, int kof, int r0, int r1) {
#pragma unroll
  for (int i = 0; i < 8; ++i) {
    const int kk = (C * 8 + i) * 32 + kof;
    b0[i] = *(const bf16x8*)&Wl[r0 * 1024 + (kk ^ sw)];
    b1[i] = *(const bf16x8*)&Wl[r1 * 1024 + (kk ^ sw)];
  }
}
DEV void mfma8x(const i32x4* a, const bf16x8* b0, const bf16x8* b1,
                f32x4& acc0, f32x4& acc1) {
#pragma unroll
  for (int i = 0; i < 8; ++i) {
    bf16x8 av = as_bf(a[i]);
    acc0 = __builtin_amdgcn_mfma_f32_16x16x32_bf16(av, b0[i], acc0, 0, 0, 0);
    acc1 = __builtin_amdgcn_mfma_f32_16x16x32_bf16(av, b1[i], acc1, 0, 0, 0);
  }
}

// K=1024 recurrent GEMM: A (h-state, cached loads, all issued upfront) x W (LDS).
// Counted waits are prefix-agnostic: any loads issued BEFORE this retire first.
DEV void mfma_step(const __hip_bfloat16* Ap, const __hip_bfloat16* Wl,
                   int mh, int nh, int l, f32x4& acc0, f32x4& acc1) {
  const __hip_bfloat16* arow = Ap + (mh * 16 + (l & 15)) * 1024 + (l >> 4) * 8;
  const int sw = (l & 7) << 3, kof = (l >> 4) * 8;
  const int r0 = nh * 32 + (l & 15), r1 = r0 + 16;
  i32x4 A0[8], A1[8], A2[8], A3[8];
  bf16x8 Ba0[8], Ba1[8], Bb0[8], Bb1[8];
  loads8<0>(A0, arow);
  loads8<8>(A1, arow);
  loads8<16>(A2, arow);
  loads8<24>(A3, arow);
  ldsb8<0>(Ba0, Ba1, Wl, sw, kof, r0, r1);
  WAITV(24);
  mfma8x(A0, Ba0, Ba1, acc0, acc1);
  ldsb8<1>(Bb0, Bb1, Wl, sw, kof, r0, r1);
  WAITV(16);
  mfma8x(A1, Bb0, Bb1, acc0, acc1);
  ldsb8<2>(Ba0, Ba1, Wl, sw, kof, r0, r1);
  WAITV(8);
  mfma8x(A2, Ba0, Ba1, acc0, acc1);
  ldsb8<3>(Bb0, Bb1, Wl, sw, kof, r0, r1);
  WAITV(0);
  mfma8x(A3, Bb0, Bb1, acc0, acc1);
}

// final-phase pass: A cached loads, W from global (cached)
DEV void mfma_pass_glb(const __hip_bfloat16* Ap, const __hip_bfloat16* __restrict__ Wg,
                       int d0, int mh, int nh, int l, f32x4& acc0, f32x4& acc1) {
  const __hip_bfloat16* arow = Ap + (mh * 16 + (l & 15)) * 1024 + (l >> 4) * 8;
  const size_t g0 = ((size_t)(2 * nh) * 1024 + d0 + (l & 15)) * 1024;
  const size_t g1 = g0 + 1048576;
  const int kof = (l >> 4) * 8;
  i32x4 A[8];
  for (int c = 0; c < 4; ++c) {
    loads8rt(A, arow, c * 8);
    WAITV(0);
#pragma unroll
    for (int i = 0; i < 8; ++i) {
      const int kk = (c * 8 + i) * 32 + kof;
      bf16x8 b0 = *(const bf16x8*)&Wg[g0 + kk];
      bf16x8 b1 = *(const bf16x8*)&Wg[g1 + kk];
      bf16x8 av = as_bf(A[i]);
      acc0 = __builtin_amdgcn_mfma_f32_16x16x32_bf16(av, b0, acc0, 0, 0, 0);
      acc1 = __builtin_amdgcn_mfma_f32_16x16x32_bf16(av, b1, acc1, 0, 0, 0);
    }
  }
}

// ---------------- generic bf16 MFMA GEMM: C[M,N] = A[M,K] @ Bw[N,K]^T + bias ----------------
// mode 0: outF = acc+bias (f32); mode 1: outBF = bf16(acc+bias)
// mode 2: outBF = bf16(sigmoid(acc+bias)*tanh(aux))
// mode 3: outBF is blk layout [slot][256 t][2048] chunk [g*512 + b*16 + dd]; rows must be t*32+b
__global__ __launch_bounds__(256) void gemm_bt_kernel(
    const __hip_bfloat16* __restrict__ A, const __hip_bfloat16* __restrict__ Bw,
    float* __restrict__ outF, __hip_bfloat16* __restrict__ outBF,
    const float* __restrict__ bias, const float* __restrict__ aux,
    int M, int N, int K, int remap, int mode)
{
  __shared__ __hip_bfloat16 As[128 * 64];
  __shared__ __hip_bfloat16 Bs[128 * 64];
  __shared__ __hip_bfloat16 Cs[128 * 128];   // mode-3 staging only
  const int tid = threadIdx.x;
  const int w = tid >> 6, l = tid & 63;
  const int m0 = blockIdx.x * 128, n0 = blockIdx.y * 128;
  const int wm = (w >> 1) * 64, wn = (w & 1) * 64;
  const int row_s = tid >> 3, kc = tid & 7;
  f32x4 acc[4][4] = {};
  for (int k0 = 0; k0 < K; k0 += 64) {
    const __hip_bfloat16* ga = A + (size_t)(m0 + row_s) * K + k0 + kc * 8;
    const __hip_bfloat16* gb = Bw + (size_t)(n0 + row_s) * K + k0 + kc * 8;
    __hip_bfloat16* la = As + w * 512;
    __hip_bfloat16* lb = Bs + w * 512;
#pragma unroll
    for (int p = 0; p < 4; ++p) {
      async16(ga + (size_t)p * 32 * K, la + p * 2048);
      async16(gb + (size_t)p * 32 * K, lb + p * 2048);
    }
    __syncthreads();
#pragma unroll
    for (int kb = 0; kb < 2; ++kb) {
      bf16x8 af[4], bfr[4];
#pragma unroll
      for (int i = 0; i < 4; ++i)
        af[i] = *(const bf16x8*)&As[(wm + i * 16 + (l & 15)) * 64 + kb * 32 + (l >> 4) * 8];
#pragma unroll
      for (int j = 0; j < 4; ++j)
        bfr[j] = *(const bf16x8*)&Bs[(wn + j * 16 + (l & 15)) * 64 + kb * 32 + (l >> 4) * 8];
#pragma unroll
      for (int i = 0; i < 4; ++i)
#pragma unroll
        for (int j = 0; j < 4; ++j)
          acc[i][j] = __builtin_amdgcn_mfma_f32_16x16x32_bf16(af[i], bfr[j], acc[i][j], 0, 0, 0);
    }
    __syncthreads();
  }
  if (mode == 3) {
#pragma unroll
    for (int i = 0; i < 4; ++i)
#pragma unroll
      for (int j = 0; j < 4; ++j) {
        const int ncol = n0 + wn + j * 16 + (l & 15);
        const float bv = bias[ncol];
#pragma unroll
        for (int r = 0; r < 4; ++r) {
          const int lr = wm + i * 16 + (l >> 4) * 4 + r;
          Cs[lr * 128 + wn + j * 16 + (l & 15)] = __float2bfloat16(acc[i][j][r] + bv);
        }
      }
    __syncthreads();
    const int t0 = m0 >> 5, g = n0 >> 10, slot0 = (n0 & 1023) >> 4;
    const int grp = tid >> 6, li = tid & 63;
    const int b = li >> 1, half = li & 1;
#pragma unroll
    for (int sl = 0; sl < 8; ++sl) {
      bf16x8 vv = *(const bf16x8*)&Cs[(grp * 32 + b) * 128 + sl * 16 + half * 8];
      *(bf16x8*)&outBF[(((size_t)(slot0 + sl)) * 256 + t0 + grp) * 2048 +
                       g * 512 + b * 16 + half * 8] = vv;
    }
    return;
  }
#pragma unroll
  for (int i = 0; i < 4; ++i) {
#pragma unroll
    for (int j = 0; j < 4; ++j) {
      const int ncol = n0 + wn + j * 16 + (l & 15);
      const float bv = bias ? bias[ncol] : 0.f;
#pragma unroll
      for (int r = 0; r < 4; ++r) {
        int m = m0 + wm + i * 16 + (l >> 4) * 4 + r;
        int row = remap ? (((m & 255) << 5) | (m >> 8)) : m;
        float v = acc[i][j][r] + bv;
        if (mode == 0) {
          outF[(size_t)row * N + ncol] = v;
        } else if (mode == 1) {
          outBF[(size_t)row * N + ncol] = __float2bfloat16(v);
        } else {
          float cv = aux[(size_t)row * N + ncol];
          outBF[(size_t)row * N + ncol] = __float2bfloat16(sigmoidf_(v) * tanhf(cv));
        }
      }
    }
  }
}

// cell [8192][1024] f32 (rows t*32+b) -> blk [64 slot][256 t][32 b][16 dd] bf16
__global__ __launch_bounds__(256) void cellblk_kernel(const float* __restrict__ cell,
                                                      __hip_bfloat16* __restrict__ blk)
{
  __shared__ __hip_bfloat16 ls[32 * 1024];   // 64 KB
  const int t = blockIdx.x, tid = threadIdx.x;
  for (int i = tid; i < 32 * 1024; i += 256)
    ls[i] = __float2bfloat16(cell[(size_t)t * 32768 + i]);
  __syncthreads();
  const int e = tid * 2;
  const int b = e >> 4, dd = e & 15;
  for (int sl = 0; sl < 64; ++sl) {
    union { __hip_bfloat16 h[2]; unsigned u; } pk;
    pk.h[0] = ls[b * 1024 + sl * 16 + dd];
    pk.h[1] = ls[b * 1024 + sl * 16 + dd + 1];
    *(unsigned*)&blk[((size_t)sl * 256 + t) * 512 + e] = pk.u;
  }
}

// ---------------- persistent scan ----------------
struct PP {
  const __hip_bfloat16 *Whh_s, *Wih_s, *Whh_r, *Whh_a;  // [4096][1024]
  const __hip_bfloat16 *xgs_blk, *xgr_blk;  // [64][256][2048] blk-layout x-gates
  const __hip_bfloat16* cellblk; // [64][256][512] blk-layout bf16 cell
  const float* table;            // [20][4096]
  const int* actions;            // [32][256]
  const float *stack_c0, *act_c0, *sbias;
  __hip_bfloat16 *sh_hist, *rh_hist, *ah_hist;  // [257][32][1024] h history
  float *s1, *s2, *s3, *atop;    // [32][1024] f32
  unsigned int* flags;           // [scan*1024 + slot*16]: per-block flags, 64B apart
};

__global__ __launch_bounds__(256, 1) void scan_persist(PP P)
{
  __shared__ __hip_bfloat16 Wl[64 * 1024];             // 128 KB, XOR-swizzled
  __shared__ float gsm[32][16][4];                     // 8 KB gate exchange
  __shared__ __align__(16) __hip_bfloat16 hstage[32][16];  // 1 KB packed h staging
  const int bid = blockIdx.x;
  const int scan = bid >> 6;                 // 0 stack, 1 reduce, 2 action
  const int slot = bid & 63;
  const int d0 = slot * 16;
  const int tid = threadIdx.x;
  const int l = tid & 63, w = tid >> 6;
  const int mh = w >> 1, nh = w & 1;

  const __hip_bfloat16* Wg = (scan == 0) ? P.Whh_s : ((scan == 1) ? P.Whh_r : P.Whh_a);
  for (int idx = tid; idx < 64 * 128; idx += 256) {
    int r = idx >> 7, k = (idx & 127) * 8;
    int grow = ((r >> 4) << 10) + d0 + (r & 15);
    bf16x8 v = *(const bf16x8*)&Wg[(size_t)grow * 1024 + k];
    *(bf16x8*)&Wl[r * 1024 + (k ^ ((r & 7) << 3))] = v;
  }
  const int e0 = tid, e1 = tid + 256;
  const int b0_ = e0 >> 4, dd0 = e0 & 15, b1_ = e1 >> 4, dd1 = e1 & 15;
  float creg0, creg1;
  if (scan == 0)      { creg0 = P.stack_c0[d0 + dd0]; creg1 = P.stack_c0[d0 + dd1]; }
  else if (scan == 1) {
    creg0 = __bfloat162float(P.cellblk[(size_t)slot * 256 * 512 + b0_ * 16 + dd0]);
    creg1 = __bfloat162float(P.cellblk[(size_t)slot * 256 * 512 + b1_ * 16 + dd1]);
  }
  else                { creg0 = P.act_c0[d0 + dd0]; creg1 = P.act_c0[d0 + dd1]; }
  __syncthreads();

  __hip_bfloat16* hist = (scan == 0) ? P.sh_hist : ((scan == 1) ? P.rh_hist : P.ah_hist);
  unsigned int* Fb = P.flags + scan * 1024;   // 64 flags, 64B apart
  const int Ns = (scan == 1) ? 255 : 256;
  const int mbase = mh * 16 + (l >> 4) * 4;

  for (int s = 0; s < Ns; ++s) {
    const __hip_bfloat16* Ap = hist + (size_t)s * 32768;
    __hip_bfloat16* Hout = hist + (size_t)(s + 1) * 32768;

    // ---- prefix gate prefetch: plain loads, compiler-managed waits ----
    __hip_bfloat16 pg0, pg1, pg2, pg3, pg4, pg5, pg6, pg7;
    __hip_bfloat16 pcb0, pcb1;
    int pa0 = 0, pa1 = 0;
    pg0 = pg1 = pg2 = pg3 = pg4 = pg5 = pg6 = pg7 = __float2bfloat16(0.f);
    pcb0 = pcb1 = __float2bfloat16(0.f);
    if (scan == 0) {
      const __hip_bfloat16* x0 = P.xgs_blk + ((size_t)slot * 256 + s) * 2048 + b0_ * 16 + dd0;
      const __hip_bfloat16* x1 = P.xgs_blk + ((size_t)slot * 256 + s) * 2048 + b1_ * 16 + dd1;
      pg0 = x0[0]; pg1 = x0[512]; pg2 = x0[1024]; pg3 = x0[1536];
      pg4 = x1[0]; pg5 = x1[512]; pg6 = x1[1024]; pg7 = x1[1536];
    } else if (scan == 1) {
      const __hip_bfloat16* x0 = P.xgr_blk + ((size_t)slot * 256 + s + 1) * 2048 + b0_ * 16 + dd0;
      const __hip_bfloat16* x1 = P.xgr_blk + ((size_t)slot * 256 + s + 1) * 2048 + b1_ * 16 + dd1;
      pg0 = x0[0]; pg1 = x0[512]; pg2 = x0[1024]; pg3 = x0[1536];
      pg4 = x1[0]; pg5 = x1[512]; pg6 = x1[1024]; pg7 = x1[1536];
      pcb0 = P.cellblk[((size_t)slot * 256 + s + 1) * 512 + b0_ * 16 + dd0];
      pcb1 = P.cellblk[((size_t)slot * 256 + s + 1) * 512 + b1_ * 16 + dd1];
    } else {
      pa0 = P.actions[b0_ * 256 + s];
      pa1 = P.actions[b1_ * 256 + s];
    }
    __builtin_amdgcn_sched_barrier(0);

    f32x4 acc0 = {}, acc1 = {};
    mfma_step(Ap, Wl, mh, nh, l, acc0, acc1);
#pragma unroll
    for (int r = 0; r < 4; ++r) {
      gsm[mbase + r][l & 15][nh * 2 + 0] = acc0[r];
      gsm[mbase + r][l & 15][nh * 2 + 1] = acc1[r];
    }
    __syncthreads();
#pragma unroll
    for (int q = 0; q < 2; ++q) {
      const int b = q ? b1_ : b0_, dd = q ? dd1 : dd0;
      const int d = d0 + dd;
      float& creg = q ? creg1 : creg0;
      float g0 = gsm[b][dd][0], g1 = gsm[b][dd][1], g2 = gsm[b][dd][2], g3 = gsm[b][dd][3];
      if (scan == 1) {
        float ig = sigmoidf_(g0 + __bfloat162float(q ? pg4 : pg0));
        float lg = sigmoidf_(g1 + __bfloat162float(q ? pg5 : pg1));
        float rg = sigmoidf_(g2 + __bfloat162float(q ? pg6 : pg2));
        float cand = tanhf(g3 + __bfloat162float(q ? pg7 : pg3));
        float rcv = __bfloat162float(q ? pcb1 : pcb0);
        float c2 = ig * cand + lg * creg + rg * rcv;
        creg = c2;
        hstage[b][dd] = __float2bfloat16(tanhf(c2));
      } else {
        float bi0, bi1, bi2, bi3;
        if (scan == 0) {
          bi0 = __bfloat162float(q ? pg4 : pg0); bi1 = __bfloat162float(q ? pg5 : pg1);
          bi2 = __bfloat162float(q ? pg6 : pg2); bi3 = __bfloat162float(q ? pg7 : pg3);
        } else {
          int a = q ? pa1 : pa0;
          const float* tb = P.table + a * 4096;
          bi0 = tb[d]; bi1 = tb[1024 + d]; bi2 = tb[2048 + d]; bi3 = tb[3072 + d];
        }
        float c2 = sigmoidf_(g1 + bi1) * creg + sigmoidf_(g0 + bi0) * tanhf(g2 + bi2);
        float h2 = sigmoidf_(g3 + bi3) * tanhf(c2);
        creg = c2;
        hstage[b][dd] = __float2bfloat16(h2);
        if (scan == 0 && s == 254) P.s3[b * 1024 + d] = h2;
        if (scan == 0 && s == 255) P.s2[b * 1024 + d] = h2;
        if (scan == 2 && s == 255) P.atop[b * 1024 + d] = h2;
      }
    }
    __syncthreads();
    // ---- packed 16B device-coherent h stores (wave 0 only) ----
    if (tid < 64) {
      const int bb = tid >> 1, hf = tid & 1;
      union { bf16x8 b8; i32x4 i4; } u;
      u.b8 = *(const bf16x8*)&hstage[bb][hf * 8];
      store16_sys(Hout + bb * 1024 + d0 + hf * 8, u.i4);
    }
    asm volatile("s_waitcnt vmcnt(0)" ::: "memory");
    __syncthreads();
    // ---- store-based barrier: own-flag store (no RMW) + 64-lane parallel poll ----
    if (tid == 0) flag_store(Fb + slot * 16, (unsigned)(s + 1));
    if (tid < 64) {
      const unsigned tgt = (unsigned)(s + 1);
      if (flag_load(Fb + tid * 16) < tgt) {          // fast path: one check, no sleep
        while (flag_load(Fb + tid * 16) < tgt) __builtin_amdgcn_s_sleep(1);
      }
    }
    __syncthreads();
  }

  if (scan == 0) {
    if (tid < 64) {
      while (flag_load(P.flags + 1024 + tid * 16) < 255u) __builtin_amdgcn_s_sleep(1);
    }
    __syncthreads();
    f32x4 acc0 = {}, acc1 = {};
    mfma_step(P.sh_hist + (size_t)256 * 32768, Wl, mh, nh, l, acc0, acc1);       // hf @ Whh^T
    mfma_pass_glb(P.rh_hist + (size_t)255 * 32768, P.Wih_s, d0, mh, nh, l, acc0, acc1); // red_h @ Wih^T
#pragma unroll
    for (int r = 0; r < 4; ++r) {
      gsm[mbase + r][l & 15][nh * 2 + 0] = acc0[r];
      gsm[mbase + r][l & 15][nh * 2 + 1] = acc1[r];
    }
    __syncthreads();
#pragma unroll
    for (int q = 0; q < 2; ++q) {
      const int b = q ? b1_ : b0_, dd = q ? dd1 : dd0;
      const int d = d0 + dd;
      float creg = q ? creg1 : creg0;   // cf
      float g0 = gsm[b][dd][0], g1 = gsm[b][dd][1], g2 = gsm[b][dd][2], g3 = gsm[b][dd][3];
      float bi0 = P.sbias[d], bi1 = P.sbias[1024 + d], bi2 = P.sbias[2048 + d], bi3 = P.sbias[3072 + d];
      float c2 = sigmoidf_(g1 + bi1) * creg + sigmoidf_(g0 + bi0) * tanhf(g2 + bi2);
      float h2 = sigmoidf_(g3 + bi3) * tanhf(c2);
      P.s1[b * 1024 + d] = h2;
    }
  }
}

// ---------------- small utility kernels ----------------
__global__ void cast_kernel(__hip_bfloat16* dst, const float* src, int n) {
  int i = blockIdx.x * 256 + threadIdx.x;
  if (i < n) dst[i] = __float2bfloat16(src[i]);
}
__global__ void extract_half_kernel(__hip_bfloat16* dst, const float* src, int n,
                                    int src_stride, int src_off) {
  int i = blockIdx.x * 256 + threadIdx.x;
  if (i < n) {
    int r = i >> 10, k = i & 1023;
    dst[i] = __float2bfloat16(src[(size_t)r * src_stride + src_off + k]);
  }
}
__global__ void bias_kernel(float* dst, const float* a, const float* b, int n) {
  int i = blockIdx.x * 256 + threadIdx.x;
  if (i < n) dst[i] = a[i] + b[i];
}
__global__ void act_table_kernel(const float* emb, const float* Wih, const float* bih,
                                 const float* bhh, float* table) {
  int i = blockIdx.x * 256 + threadIdx.x;
  int a = i >> 12, n = i & 4095;
  float acc = bih[n] + bhh[n];
  const float* er = emb + a * 64;
  const float* wr = Wih + (size_t)n * 64;
  for (int k = 0; k < 64; ++k) acc += er[k] * wr[k];
  table[i] = acc;
}
// fills history slot 0 for all three scans: stack h0, action h0, reduce = hid_t[0]
__global__ void init_states_kernel(const float* stack_h0, const float* act_h0,
                                   const __hip_bfloat16* hid,
                                   __hip_bfloat16* sh0, __hip_bfloat16* ah0,
                                   __hip_bfloat16* rh0, unsigned int* flags)
{
  int i = blockIdx.x * 256 + threadIdx.x;  // 32768
  int d = i & 1023;
  sh0[i] = __float2bfloat16(stack_h0[d]);
  ah0[i] = __float2bfloat16(act_h0[d]);
  rh0[i] = hid[i];
  if (i < 4096) flags[i] = 0u;
}

// ---------------- attention ----------------
__global__ __launch_bounds__(256) void att_q_kernel(
    const float* s1, const float* s2, const float* s3, const float* attW, float* q)
{
  int eb = blockIdx.x, bg = blockIdx.y, j = blockIdx.z;
  const float* sj = (j == 0) ? s1 : ((j == 1) ? s2 : s3);
  __shared__ float ls[4][1024];
  int tid = threadIdx.x;
  for (int i = tid; i < 4096; i += 256)
    ls[i >> 10][i & 1023] = sj[(size_t)(bg * 4 + (i >> 10)) * 1024 + (i & 1023)];
  __syncthreads();
  int e = eb * 256 + tid;
  const float* Wj = attW + (size_t)j * 1024 * 1024;
  float a0 = 0, a1 = 0, a2 = 0, a3 = 0;
  for (int d = 0; d < 1024; ++d) {
    float wv = Wj[(size_t)d * 1024 + e];
    a0 += ls[0][d] * wv; a1 += ls[1][d] * wv; a2 += ls[2][d] * wv; a3 += ls[3][d] * wv;
  }
  q[((size_t)j * 32 + bg * 4 + 0) * 1024 + e] = a0;
  q[((size_t)j * 32 + bg * 4 + 1) * 1024 + e] = a1;
  q[((size_t)j * 32 + bg * 4 + 2) * 1024 + e] = a2;
  q[((size_t)j * 32 + bg * 4 + 3) * 1024 + e] = a3;
}

__global__ __launch_bounds__(256) void att_sc_kernel(const float* q, const float* sent, float* att)
{
  int b = blockIdx.x, j = blockIdx.y;
  __shared__ float qs[1024];
  __shared__ float wsm[256];
  __shared__ float red[8];
  int tid = threadIdx.x, w = tid >> 6, l = tid & 63;
  for (int i = tid; i < 1024; i += 256) qs[i] = q[((size_t)j * 32 + b) * 1024 + i];
  __syncthreads();
  const float* sp = sent + ((size_t)b * 256 + tid) * 1024;
  float dot = 0;
  for (int k = 0; k < 1024; ++k) dot += qs[k] * sp[k];
  float v = dot;
  for (int off = 32; off; off >>= 1) v = fmaxf(v, __shfl_xor(v, off));
  if (l == 0) red[w] = v;
  __syncthreads();
  float m = fmaxf(fmaxf(red[0], red[1]), fmaxf(red[2], red[3]));
  float ex = expf(dot - m);
  float sv = ex;
  for (int off = 32; off; off >>= 1) sv += __shfl_xor(sv, off);
  if (l == 0) red[4 + w] = sv;
  __syncthreads();
  float ssum = red[4] + red[5] + red[6] + red[7];
  wsm[tid] = ex / ssum;
  __syncthreads();
  for (int it = 0; it < 4; ++it) {
    int e = it * 256 + tid;
    float a = 0;
    for (int t2 = 0; t2 < 256; ++t2) a += wsm[t2] * sent[((size_t)b * 256 + t2) * 1024 + e];
    att[((size_t)j * 32 + b) * 1024 + e] = a;
  }
}

// ---------------- head ----------------
__global__ void feat_kernel(const float* s1, const float* s2, const float* s3,
                            const float* tok, const float* atop, const float* att, float* feat)
{
  int i = blockIdx.x * 256 + threadIdx.x;
  int b = i >> 13, jj = (i >> 10) & 7, d = i & 1023;
  int sidx = b * 1024 + d;
  float v;
  switch (jj) {
    case 0: v = s1[sidx]; break;
    case 1: v = s2[sidx]; break;
    case 2: v = s3[sidx]; break;
    case 3: v = tok[d]; break;
    case 4: v = atop[sidx]; break;
    default: v = att[((size_t)(jj - 5) * 32 + b) * 1024 + d];
  }
  feat[i] = v;
}
__global__ __launch_bounds__(256) void head_kernel(const float* feat, const float* W,
                                                   const float* bias, float* fbuf)
{
  int i = blockIdx.x * 256 + threadIdx.x;
  int b = i >> 9, h = i & 511;
  const float* fr = feat + (size_t)b * 8192;
  const float* wr = W + (size_t)h * 8192;
  float a = bias[h];
  for (int k = 0; k < 8192; ++k) a += fr[k] * wr[k];
  fbuf[i] = tanhf(a);
}
__global__ void logits_kernel(const float* fbuf, const float* W, const float* bias, float* out)
{
  int b = blockIdx.x, tid = threadIdx.x;
  __shared__ float lg[20];
  __shared__ float mred, lsred;
  if (tid < 20) {
    const float* fr = fbuf + b * 512;
    const float* wr = W + tid * 512;
    float a = bias[tid];
    for (int k = 0; k < 512; ++k) a += fr[k] * wr[k];
    lg[tid] = a;
  }
  __syncthreads();
  if (tid == 0) {
    float m = lg[0];
    for (int i = 1; i < 20; ++i) m = fmaxf(m, lg[i]);
    float ssum = 0;
    for (int i = 0; i < 20; ++i) ssum += expf(lg[i] - m);
    mred = m; lsred = logf(ssum);
  }
  __syncthreads();
  if (tid < 20) out[b * 20 + tid] = lg[tid] - mred - lsred;
}

// ---------------- host ----------------
extern "C" void kernel_launch(void* const* d_in, const int* in_sizes, int n_in,
                              void* d_out, int out_size, void* d_ws, size_t ws_size,
                              hipStream_t stream)
{
  const float* sentence = (const float*)d_in[0];
  const int* actions = (const int*)d_in[1];
  const float* token_empty = (const float*)d_in[2];
  const float* leaf_Wi = (const float*)d_in[3];
  const float* leaf_bi = (const float*)d_in[4];
  const float* leaf_Wo = (const float*)d_in[5];
  const float* leaf_bo = (const float*)d_in[6];
  const float* lstm_Wih = (const float*)d_in[7];
  const float* lstm_Whh = (const float*)d_in[8];
  const float* lstm_bih = (const float*)d_in[9];
  const float* lstm_bhh = (const float*)d_in[10];
  const float* stack_h0 = (const float*)d_in[11];
  const float* stack_c0 = (const float*)d_in[12];
  const float* act_emb = (const float*)d_in[13];
  const float* act_Wih = (const float*)d_in[14];
  const float* act_Whh = (const float*)d_in[15];
  const float* act_bih = (const float*)d_in[16];
  const float* act_bhh = (const float*)d_in[17];
  const float* act_h0 = (const float*)d_in[18];
  const float* act_c0 = (const float*)d_in[19];
  const float* red_W = (const float*)d_in[20];
  const float* red_b = (const float*)d_in[21];
  const float* h2f_W = (const float*)d_in[22];
  const float* h2f_b = (const float*)d_in[23];
  const float* f2a_W = (const float*)d_in[24];
  const float* f2a_b = (const float*)d_in[25];
  const float* att_W = (const float*)d_in[26];
  float* out = (float*)d_out;
  (void)in_sizes; (void)n_in; (void)out_size; (void)ws_size;

  char* ws = (char*)d_ws;
  size_t off = 0;
  auto alloc = [&](size_t bytes) -> void* {
    void* ptr = ws + off;
    off += (bytes + 255) & ~(size_t)255;
    return ptr;
  };
  // ---- aliased arena (56 MB): phase 1 holds sent_bf|cell_f32|Wx_r (all dead
  // before init_states); phase 2 holds the three h-history buffers (50.5 MB).
  char* arena = (char*)alloc(58720256);
  __hip_bfloat16* sent_bf = (__hip_bfloat16*)arena;                 // 16 MB
  float* cell_f32 = (float*)(arena + 16777216);                     // 32 MB
  __hip_bfloat16* Wx_r = (__hip_bfloat16*)(arena + 50331648);       //  8 MB
  __hip_bfloat16* sh_hist = (__hip_bfloat16*)arena;                 // [257][32][1024]
  __hip_bfloat16* rh_hist = (__hip_bfloat16*)(arena + 16843008);
  __hip_bfloat16* ah_hist = (__hip_bfloat16*)(arena + 33686016);

  __hip_bfloat16* hid_bf  = (__hip_bfloat16*)alloc(16777216);   // [8192][1024] (t*32+b)
  __hip_bfloat16* lWi_bf = (__hip_bfloat16*)alloc(2097152);
  __hip_bfloat16* lWo_bf = (__hip_bfloat16*)alloc(2097152);
  __hip_bfloat16* Whh_s = (__hip_bfloat16*)alloc(8388608);
  __hip_bfloat16* Wih_s = (__hip_bfloat16*)alloc(8388608);
  __hip_bfloat16* Whh_r = (__hip_bfloat16*)alloc(8388608);
  __hip_bfloat16* Whh_a = (__hip_bfloat16*)alloc(8388608);
  __hip_bfloat16* xgs_blk = (__hip_bfloat16*)alloc(67108864);   // [64][256][2048]
  __hip_bfloat16* xgr_blk = (__hip_bfloat16*)alloc(67108864);
  __hip_bfloat16* cellblk = (__hip_bfloat16*)alloc(16777216);   // [64][256][512]
  float* table = (float*)alloc(327680);
  float* sbias = (float*)alloc(16384);
  float* s1 = (float*)alloc(131072);
  float* s2 = (float*)alloc(131072);
  float* s3 = (float*)alloc(131072);
  float* atop = (float*)alloc(131072);
  unsigned int* flags = (unsigned int*)alloc(16384);  // 3*64 flags, 64B apart
  float* qbuf = (float*)alloc(393216);
  float* attbuf = (float*)alloc(393216);
  float* feat = (float*)alloc(1048576);
  float* fbuf = (float*)alloc(65536);

  // conversions (phase 1 of arena)
  cast_kernel<<<32768, 256, 0, stream>>>(sent_bf, sentence, 8388608);
  cast_kernel<<<4096, 256, 0, stream>>>(lWi_bf, leaf_Wi, 1048576);
  cast_kernel<<<4096, 256, 0, stream>>>(lWo_bf, leaf_Wo, 1048576);
  cast_kernel<<<16384, 256, 0, stream>>>(Whh_s, lstm_Whh, 4194304);
  cast_kernel<<<16384, 256, 0, stream>>>(Wih_s, lstm_Wih, 4194304);
  cast_kernel<<<16384, 256, 0, stream>>>(Whh_a, act_Whh, 4194304);
  extract_half_kernel<<<16384, 256, 0, stream>>>(Whh_r, red_W, 4194304, 2048, 0);
  extract_half_kernel<<<16384, 256, 0, stream>>>(Wx_r, red_W, 4194304, 2048, 1024);
  bias_kernel<<<16, 256, 0, stream>>>(sbias, lstm_bih, lstm_bhh, 4096);
  act_table_kernel<<<320, 256, 0, stream>>>(act_emb, act_Wih, act_bih, act_bhh, table);

  // leaf module (consumes sent_bf, produces+consumes cell_f32)
  gemm_bt_kernel<<<dim3(64, 8), 256, 0, stream>>>(sent_bf, lWi_bf, cell_f32, nullptr,
                                                  leaf_bi, nullptr, 8192, 1024, 1024, 1, 0);
  gemm_bt_kernel<<<dim3(64, 8), 256, 0, stream>>>(sent_bf, lWo_bf, nullptr, hid_bf,
                                                  leaf_bo, cell_f32, 8192, 1024, 1024, 1, 2);
  cellblk_kernel<<<256, 256, 0, stream>>>(cell_f32, cellblk);

  // precomputed x-gates in blk layout (bias folded); xg_r consumes Wx_r (arena)
  gemm_bt_kernel<<<dim3(64, 32), 256, 0, stream>>>(hid_bf, Wih_s, nullptr, xgs_blk,
                                                   sbias, nullptr, 8192, 4096, 1024, 0, 3);
  gemm_bt_kernel<<<dim3(64, 32), 256, 0, stream>>>(hid_bf, Wx_r, nullptr, xgr_blk,
                                                   red_b, nullptr, 8192, 4096, 1024, 0, 3);

  // phase 2 of arena begins: overwrite with history slot 0
  init_states_kernel<<<128, 256, 0, stream>>>(stack_h0, act_h0, hid_bf,
                                              sh_hist, ah_hist, rh_hist, flags);

  PP P;
  P.Whh_s = Whh_s; P.Wih_s = Wih_s; P.Whh_r = Whh_r; P.Whh_a = Whh_a;
  P.xgs_blk = xgs_blk; P.xgr_blk = xgr_blk; P.cellblk = cellblk;
  P.table = table; P.actions = actions;
  P.stack_c0 = stack_c0; P.act_c0 = act_c0; P.sbias = sbias;
  P.sh_hist = sh_hist; P.rh_hist = rh_hist; P.ah_hist = ah_hist;
  P.s1 = s1; P.s2 = s2; P.s3 = s3; P.atop = atop;
  P.flags = flags;
  scan_persist<<<192, 256, 0, stream>>>(P);

  // attention: s1, s2, s3
  att_q_kernel<<<dim3(4, 8, 3), 256, 0, stream>>>(s1, s2, s3, att_W, qbuf);
  att_sc_kernel<<<dim3(32, 3), 256, 0, stream>>>(qbuf, sentence, attbuf);

  // head
  feat_kernel<<<1024, 256, 0, stream>>>(s1, s2, s3, token_empty, atop, attbuf, feat);
  head_kernel<<<64, 256, 0, stream>>>(feat, h2f_W, h2f_b, fbuf);
  logits_kernel<<<32, 64, 0, stream>>>(fbuf, f2a_W, f2a_b, out);
}

// Round 13
// 2553.013 us; speedup vs baseline: 1.4645x; 1.0130x over previous
//
#include <hip/hip_runtime.h>
#include <hip/hip_bf16.h>
#include <math.h>

// B=32, T=256, D=1024, A=64, H=512, NA=20
#define DEV __device__ __forceinline__

typedef __bf16 bf16_t;
typedef bf16_t bf16x8 __attribute__((ext_vector_type(8)));
typedef float f32x4 __attribute__((ext_vector_type(4)));
typedef int i32x4 __attribute__((ext_vector_type(4)));

DEV void async16(const void* g, void* l) {
  __builtin_amdgcn_global_load_lds((const __attribute__((address_space(1))) void*)g,
                                   (__attribute__((address_space(3))) void*)l, 16, 0, 0);
}
DEV float sigmoidf_(float x) { return 1.f / (1.f + expf(-x)); }
DEV bf16x8 as_bf(i32x4 v) { union { i32x4 i; bf16x8 b; } u; u.i = v; return u.b; }

// ---- fine-grained device-coherent ops ----
DEV unsigned flag_load(const unsigned* p) {
  unsigned v;
  asm volatile("global_load_dword %0, %1, off sc0 sc1\ns_waitcnt vmcnt(0)"
               : "=v"(v) : "v"(p) : "memory");
  return v;
}
DEV void flag_store(unsigned* p, unsigned v) {
  asm volatile("global_store_dword %0, %1, off sc0 sc1" :: "v"(p), "v"(v) : "memory");
}
DEV void store16_sys(void* p, i32x4 v) {
  asm volatile("global_store_dwordx4 %0, %1, off sc0 sc1" :: "v"(p), "v"(v) : "memory");
}

#define WAITV(N) do { asm volatile("s_waitcnt vmcnt(" #N ")" ::: "memory"); \
                      __builtin_amdgcn_sched_barrier(0); } while (0)

// NORMAL cached loads (L1/L2 path). h_hist slots are write-once-before-read per
// dispatch (and bit-identical across graph replays), so no stale-line hazard.
template<int KB>
DEV void loads8(i32x4* dst, const __hip_bfloat16* arow) {
#pragma unroll
  for (int i = 0; i < 8; ++i)
    asm volatile("global_load_dwordx4 %0, %1, off offset:%2"
                 : "=v"(dst[i]) : "v"(arow), "i"((KB + i) * 64));
}
DEV void loads8rt(i32x4* dst, const __hip_bfloat16* arow, int kbase) {
#pragma unroll
  for (int i = 0; i < 8; ++i)
    asm volatile("global_load_dwordx4 %0, %1, off"
                 : "=v"(dst[i]) : "v"(arow + (size_t)(kbase + i) * 32) : "memory");
}

template<int C>
DEV void ldsb8(bf16x8* b0, bf16x8* b1, const __hip_bfloat16* Wl,
               int sw, int kof, int r0, int r1) {
#pragma unroll
  for (int i = 0; i < 8; ++i) {
    const int kk = (C * 8 + i) * 32 + kof;
    b0[i] = *(const bf16x8*)&Wl[r0 * 1024 + (kk ^ sw)];
    b1[i] = *(const bf16x8*)&Wl[r1 * 1024 + (kk ^ sw)];
  }
}
DEV void mfma8x(const i32x4* a, const bf16x8* b0, const bf16x8* b1,
                f32x4& acc0, f32x4& acc1) {
#pragma unroll
  for (int i = 0; i < 8; ++i) {
    bf16x8 av = as_bf(a[i]);
    acc0 = __builtin_amdgcn_mfma_f32_16x16x32_bf16(av, b0[i], acc0, 0, 0, 0);
    acc1 = __builtin_amdgcn_mfma_f32_16x16x32_bf16(av, b1[i], acc1, 0, 0, 0);
  }
}

// full-K step used only in the drained final phase (all vmcnt self-contained)
DEV void mfma_step(const __hip_bfloat16* Ap, const __hip_bfloat16* Wl,
                   int mh, int nh, int l, f32x4& acc0, f32x4& acc1) {
  const __hip_bfloat16* arow = Ap + (mh * 16 + (l & 15)) * 1024 + (l >> 4) * 8;
  const int sw = (l & 7) << 3, kof = (l >> 4) * 8;
  const int r0 = nh * 32 + (l & 15), r1 = r0 + 16;
  i32x4 A0[8], A1[8], A2[8], A3[8];
  bf16x8 Ba0[8], Ba1[8], Bb0[8], Bb1[8];
  loads8<0>(A0, arow);
  loads8<8>(A1, arow);
  loads8<16>(A2, arow);
  loads8<24>(A3, arow);
  ldsb8<0>(Ba0, Ba1, Wl, sw, kof, r0, r1);
  WAITV(24);
  mfma8x(A0, Ba0, Ba1, acc0, acc1);
  ldsb8<1>(Bb0, Bb1, Wl, sw, kof, r0, r1);
  WAITV(16);
  mfma8x(A1, Bb0, Bb1, acc0, acc1);
  ldsb8<2>(Ba0, Ba1, Wl, sw, kof, r0, r1);
  WAITV(8);
  mfma8x(A2, Ba0, Ba1, acc0, acc1);
  ldsb8<3>(Bb0, Bb1, Wl, sw, kof, r0, r1);
  WAITV(0);
  mfma8x(A3, Bb0, Bb1, acc0, acc1);
}

// final-phase pass: A cached loads, W from global (cached)
DEV void mfma_pass_glb(const __hip_bfloat16* Ap, const __hip_bfloat16* __restrict__ Wg,
                       int d0, int mh, int nh, int l, f32x4& acc0, f32x4& acc1) {
  const __hip_bfloat16* arow = Ap + (mh * 16 + (l & 15)) * 1024 + (l >> 4) * 8;
  const size_t g0 = ((size_t)(2 * nh) * 1024 + d0 + (l & 15)) * 1024;
  const size_t g1 = g0 + 1048576;
  const int kof = (l >> 4) * 8;
  i32x4 A[8];
  for (int c = 0; c < 4; ++c) {
    loads8rt(A, arow, c * 8);
    WAITV(0);
#pragma unroll
    for (int i = 0; i < 8; ++i) {
      const int kk = (c * 8 + i) * 32 + kof;
      bf16x8 b0 = *(const bf16x8*)&Wg[g0 + kk];
      bf16x8 b1 = *(const bf16x8*)&Wg[g1 + kk];
      bf16x8 av = as_bf(A[i]);
      acc0 = __builtin_amdgcn_mfma_f32_16x16x32_bf16(av, b0, acc0, 0, 0, 0);
      acc1 = __builtin_amdgcn_mfma_f32_16x16x32_bf16(av, b1, acc1, 0, 0, 0);
    }
  }
}

// ---------------- generic bf16 MFMA GEMM: C[M,N] = A[M,K] @ Bw[N,K]^T + bias ----------------
// mode 0: outF = acc+bias (f32); mode 1: outBF = bf16(acc+bias)
// mode 2: outBF = bf16(sigmoid(acc+bias)*tanh(aux))
// mode 3: outBF is blk layout [slot][256 t][2048] chunk [g*512 + b*16 + dd]; rows must be t*32+b
__global__ __launch_bounds__(256) void gemm_bt_kernel(
    const __hip_bfloat16* __restrict__ A, const __hip_bfloat16* __restrict__ Bw,
    float* __restrict__ outF, __hip_bfloat16* __restrict__ outBF,
    const float* __restrict__ bias, const float* __restrict__ aux,
    int M, int N, int K, int remap, int mode)
{
  __shared__ __hip_bfloat16 As[128 * 64];
  __shared__ __hip_bfloat16 Bs[128 * 64];
  __shared__ __hip_bfloat16 Cs[128 * 128];   // mode-3 staging only
  const int tid = threadIdx.x;
  const int w = tid >> 6, l = tid & 63;
  const int m0 = blockIdx.x * 128, n0 = blockIdx.y * 128;
  const int wm = (w >> 1) * 64, wn = (w & 1) * 64;
  const int row_s = tid >> 3, kc = tid & 7;
  f32x4 acc[4][4] = {};
  for (int k0 = 0; k0 < K; k0 += 64) {
    const __hip_bfloat16* ga = A + (size_t)(m0 + row_s) * K + k0 + kc * 8;
    const __hip_bfloat16* gb = Bw + (size_t)(n0 + row_s) * K + k0 + kc * 8;
    __hip_bfloat16* la = As + w * 512;
    __hip_bfloat16* lb = Bs + w * 512;
#pragma unroll
    for (int p = 0; p < 4; ++p) {
      async16(ga + (size_t)p * 32 * K, la + p * 2048);
      async16(gb + (size_t)p * 32 * K, lb + p * 2048);
    }
    __syncthreads();
#pragma unroll
    for (int kb = 0; kb < 2; ++kb) {
      bf16x8 af[4], bfr[4];
#pragma unroll
      for (int i = 0; i < 4; ++i)
        af[i] = *(const bf16x8*)&As[(wm + i * 16 + (l & 15)) * 64 + kb * 32 + (l >> 4) * 8];
#pragma unroll
      for (int j = 0; j < 4; ++j)
        bfr[j] = *(const bf16x8*)&Bs[(wn + j * 16 + (l & 15)) * 64 + kb * 32 + (l >> 4) * 8];
#pragma unroll
      for (int i = 0; i < 4; ++i)
#pragma unroll
        for (int j = 0; j < 4; ++j)
          acc[i][j] = __builtin_amdgcn_mfma_f32_16x16x32_bf16(af[i], bfr[j], acc[i][j], 0, 0, 0);
    }
    __syncthreads();
  }
  if (mode == 3) {
#pragma unroll
    for (int i = 0; i < 4; ++i)
#pragma unroll
      for (int j = 0; j < 4; ++j) {
        const int ncol = n0 + wn + j * 16 + (l & 15);
        const float bv = bias[ncol];
#pragma unroll
        for (int r = 0; r < 4; ++r) {
          const int lr = wm + i * 16 + (l >> 4) * 4 + r;
          Cs[lr * 128 + wn + j * 16 + (l & 15)] = __float2bfloat16(acc[i][j][r] + bv);
        }
      }
    __syncthreads();
    const int t0 = m0 >> 5, g = n0 >> 10, slot0 = (n0 & 1023) >> 4;
    const int grp = tid >> 6, li = tid & 63;
    const int b = li >> 1, half = li & 1;
#pragma unroll
    for (int sl = 0; sl < 8; ++sl) {
      bf16x8 vv = *(const bf16x8*)&Cs[(grp * 32 + b) * 128 + sl * 16 + half * 8];
      *(bf16x8*)&outBF[(((size_t)(slot0 + sl)) * 256 + t0 + grp) * 2048 +
                       g * 512 + b * 16 + half * 8] = vv;
    }
    return;
  }
#pragma unroll
  for (int i = 0; i < 4; ++i) {
#pragma unroll
    for (int j = 0; j < 4; ++j) {
      const int ncol = n0 + wn + j * 16 + (l & 15);
      const float bv = bias ? bias[ncol] : 0.f;
#pragma unroll
      for (int r = 0; r < 4; ++r) {
        int m = m0 + wm + i * 16 + (l >> 4) * 4 + r;
        int row = remap ? (((m & 255) << 5) | (m >> 8)) : m;
        float v = acc[i][j][r] + bv;
        if (mode == 0) {
          outF[(size_t)row * N + ncol] = v;
        } else if (mode == 1) {
          outBF[(size_t)row * N + ncol] = __float2bfloat16(v);
        } else {
          float cv = aux[(size_t)row * N + ncol];
          outBF[(size_t)row * N + ncol] = __float2bfloat16(sigmoidf_(v) * tanhf(cv));
        }
      }
    }
  }
}

// cell [8192][1024] f32 (rows t*32+b) -> blk [64 slot][256 t][32 b][16 dd] bf16
__global__ __launch_bounds__(256) void cellblk_kernel(const float* __restrict__ cell,
                                                      __hip_bfloat16* __restrict__ blk)
{
  __shared__ __hip_bfloat16 ls[32 * 1024];   // 64 KB
  const int t = blockIdx.x, tid = threadIdx.x;
  for (int i = tid; i < 32 * 1024; i += 256)
    ls[i] = __float2bfloat16(cell[(size_t)t * 32768 + i]);
  __syncthreads();
  const int e = tid * 2;
  const int b = e >> 4, dd = e & 15;
  for (int sl = 0; sl < 64; ++sl) {
    union { __hip_bfloat16 h[2]; unsigned u; } pk;
    pk.h[0] = ls[b * 1024 + sl * 16 + dd];
    pk.h[1] = ls[b * 1024 + sl * 16 + dd + 1];
    *(unsigned*)&blk[((size_t)sl * 256 + t) * 512 + e] = pk.u;
  }
}

// ---------------- persistent scan ----------------
struct PP {
  const __hip_bfloat16 *Whh_s, *Wih_s, *Whh_r, *Whh_a;  // [4096][1024]
  const __hip_bfloat16 *xgs_blk, *xgr_blk;  // [64][256][2048] blk-layout x-gates
  const __hip_bfloat16* cellblk; // [64][256][512] blk-layout bf16 cell
  const float* table;            // [20][4096]
  const int* actions;            // [32][256]
  const float *stack_c0, *act_c0, *sbias;
  __hip_bfloat16 *sh_hist, *rh_hist, *ah_hist;  // [257][32][1024] h history
  float *s1, *s2, *s3, *atop;    // [32][1024] f32
  unsigned int* flags;           // [scan*1024 + slot*16]: per-block flags, 64B apart
};

__global__ __launch_bounds__(256, 1) void scan_persist(PP P)
{
  __shared__ __hip_bfloat16 Wl[64 * 1024];             // 128 KB, XOR-swizzled
  __shared__ float gsm2[4][32][17];                    // gate exchange, conflict-free layout
  __shared__ __align__(16) __hip_bfloat16 hstage[32][16];  // 1 KB packed h staging
  const int bid = blockIdx.x;
  const int scan = bid >> 6;                 // 0 stack, 1 reduce, 2 action
  const int slot = bid & 63;
  const int d0 = slot * 16;
  const int tid = threadIdx.x;
  const int l = tid & 63, w = tid >> 6;
  const int mh = w >> 1, nh = w & 1;

  const __hip_bfloat16* Wg = (scan == 0) ? P.Whh_s : ((scan == 1) ? P.Whh_r : P.Whh_a);
  for (int idx = tid; idx < 64 * 128; idx += 256) {
    int r = idx >> 7, k = (idx & 127) * 8;
    int grow = ((r >> 4) << 10) + d0 + (r & 15);
    bf16x8 v = *(const bf16x8*)&Wg[(size_t)grow * 1024 + k];
    *(bf16x8*)&Wl[r * 1024 + (k ^ ((r & 7) << 3))] = v;
  }
  const int e0 = tid, e1 = tid + 256;
  const int b0_ = e0 >> 4, dd0 = e0 & 15, b1_ = e1 >> 4, dd1 = e1 & 15;
  float creg0, creg1;
  if (scan == 0)      { creg0 = P.stack_c0[d0 + dd0]; creg1 = P.stack_c0[d0 + dd1]; }
  else if (scan == 1) {
    creg0 = __bfloat162float(P.cellblk[(size_t)slot * 256 * 512 + b0_ * 16 + dd0]);
    creg1 = __bfloat162float(P.cellblk[(size_t)slot * 256 * 512 + b1_ * 16 + dd1]);
  }
  else                { creg0 = P.act_c0[d0 + dd0]; creg1 = P.act_c0[d0 + dd1]; }
  __syncthreads();

  __hip_bfloat16* hist = (scan == 0) ? P.sh_hist : ((scan == 1) ? P.rh_hist : P.ah_hist);
  unsigned int* Fb = P.flags + scan * 1024;   // 64 flags, 64B apart
  const int Ns = (scan == 1) ? 255 : 256;
  const int mbase = mh * 16 + (l >> 4) * 4;
  const int sw = (l & 7) << 3, kof = (l >> 4) * 8;
  const int r0 = nh * 32 + (l & 15), r1 = r0 + 16;

  for (int s = 0; s < Ns; ++s) {
    const __hip_bfloat16* Ap = hist + (size_t)s * 32768;
    __hip_bfloat16* Hout = hist + (size_t)(s + 1) * 32768;

    // ---- prefix gate prefetch: plain loads, compiler-managed waits ----
    __hip_bfloat16 pg0, pg1, pg2, pg3, pg4, pg5, pg6, pg7;
    __hip_bfloat16 pcb0, pcb1;
    int pa0 = 0, pa1 = 0;
    pg0 = pg1 = pg2 = pg3 = pg4 = pg5 = pg6 = pg7 = __float2bfloat16(0.f);
    pcb0 = pcb1 = __float2bfloat16(0.f);
    if (scan == 0) {
      const __hip_bfloat16* x0 = P.xgs_blk + ((size_t)slot * 256 + s) * 2048 + b0_ * 16 + dd0;
      const __hip_bfloat16* x1 = P.xgs_blk + ((size_t)slot * 256 + s) * 2048 + b1_ * 16 + dd1;
      pg0 = x0[0]; pg1 = x0[512]; pg2 = x0[1024]; pg3 = x0[1536];
      pg4 = x1[0]; pg5 = x1[512]; pg6 = x1[1024]; pg7 = x1[1536];
    } else if (scan == 1) {
      const __hip_bfloat16* x0 = P.xgr_blk + ((size_t)slot * 256 + s + 1) * 2048 + b0_ * 16 + dd0;
      const __hip_bfloat16* x1 = P.xgr_blk + ((size_t)slot * 256 + s + 1) * 2048 + b1_ * 16 + dd1;
      pg0 = x0[0]; pg1 = x0[512]; pg2 = x0[1024]; pg3 = x0[1536];
      pg4 = x1[0]; pg5 = x1[512]; pg6 = x1[1024]; pg7 = x1[1536];
      pcb0 = P.cellblk[((size_t)slot * 256 + s + 1) * 512 + b0_ * 16 + dd0];
      pcb1 = P.cellblk[((size_t)slot * 256 + s + 1) * 512 + b1_ * 16 + dd1];
    } else {
      pa0 = P.actions[b0_ * 256 + s];
      pa1 = P.actions[b1_ * 256 + s];
    }
    __builtin_amdgcn_sched_barrier(0);

    // ---- barrier phase A: slots 0-31 (h d 0..511 of hist[s] ready) ----
    if (s > 0 && tid < 32) {
      const unsigned tgt = (unsigned)s;
      if (flag_load(Fb + tid * 16) < tgt)
        while (flag_load(Fb + tid * 16) < tgt) __builtin_amdgcn_s_sleep(1);
    }
    __syncthreads();

    // issue A-loads for k 0..511 (covered by slots 0-31)
    const __hip_bfloat16* arow = Ap + (mh * 16 + (l & 15)) * 1024 + kof;
    i32x4 A0[8], A1[8], A2[8], A3[8];
    loads8<0>(A0, arow);
    loads8<8>(A1, arow);

    // ---- barrier phase B: slots 32-63; poll's vmcnt(0) drains A0/A1 in parallel ----
    if (s > 0 && tid < 32) {
      const unsigned tgt = (unsigned)s;
      if (flag_load(Fb + (32 + tid) * 16) < tgt)
        while (flag_load(Fb + (32 + tid) * 16) < tgt) __builtin_amdgcn_s_sleep(1);
    }
    __syncthreads();
    WAITV(0);                        // all lanes: A0/A1 resident
    loads8<16>(A2, arow);
    loads8<24>(A3, arow);

    f32x4 acc0 = {}, acc1 = {};
    bf16x8 Ba0[8], Ba1[8], Bb0[8], Bb1[8];
    ldsb8<0>(Ba0, Ba1, Wl, sw, kof, r0, r1);
    mfma8x(A0, Ba0, Ba1, acc0, acc1);
    ldsb8<1>(Bb0, Bb1, Wl, sw, kof, r0, r1);
    mfma8x(A1, Bb0, Bb1, acc0, acc1);
    ldsb8<2>(Ba0, Ba1, Wl, sw, kof, r0, r1);
    WAITV(8);
    mfma8x(A2, Ba0, Ba1, acc0, acc1);
    ldsb8<3>(Bb0, Bb1, Wl, sw, kof, r0, r1);
    WAITV(0);
    mfma8x(A3, Bb0, Bb1, acc0, acc1);

#pragma unroll
    for (int r = 0; r < 4; ++r) {
      gsm2[nh * 2 + 0][mbase + r][l & 15] = acc0[r];
      gsm2[nh * 2 + 1][mbase + r][l & 15] = acc1[r];
    }
    __syncthreads();
#pragma unroll
    for (int q = 0; q < 2; ++q) {
      const int b = q ? b1_ : b0_, dd = q ? dd1 : dd0;
      const int d = d0 + dd;
      float& creg = q ? creg1 : creg0;
      float g0 = gsm2[0][b][dd], g1 = gsm2[1][b][dd], g2 = gsm2[2][b][dd], g3 = gsm2[3][b][dd];
      if (scan == 1) {
        float ig = sigmoidf_(g0 + __bfloat162float(q ? pg4 : pg0));
        float lg = sigmoidf_(g1 + __bfloat162float(q ? pg5 : pg1));
        float rg = sigmoidf_(g2 + __bfloat162float(q ? pg6 : pg2));
        float cand = tanhf(g3 + __bfloat162float(q ? pg7 : pg3));
        float rcv = __bfloat162float(q ? pcb1 : pcb0);
        float c2 = ig * cand + lg * creg + rg * rcv;
        creg = c2;
        hstage[b][dd] = __float2bfloat16(tanhf(c2));
      } else {
        float bi0, bi1, bi2, bi3;
        if (scan == 0) {
          bi0 = __bfloat162float(q ? pg4 : pg0); bi1 = __bfloat162float(q ? pg5 : pg1);
          bi2 = __bfloat162float(q ? pg6 : pg2); bi3 = __bfloat162float(q ? pg7 : pg3);
        } else {
          int a = q ? pa1 : pa0;
          const float* tb = P.table + a * 4096;
          bi0 = tb[d]; bi1 = tb[1024 + d]; bi2 = tb[2048 + d]; bi3 = tb[3072 + d];
        }
        float c2 = sigmoidf_(g1 + bi1) * creg + sigmoidf_(g0 + bi0) * tanhf(g2 + bi2);
        float h2 = sigmoidf_(g3 + bi3) * tanhf(c2);
        creg = c2;
        hstage[b][dd] = __float2bfloat16(h2);
        if (scan == 0 && s == 254) P.s3[b * 1024 + d] = h2;
        if (scan == 0 && s == 255) P.s2[b * 1024 + d] = h2;
        if (scan == 2 && s == 255) P.atop[b * 1024 + d] = h2;
      }
    }
    __syncthreads();
    // ---- packed 16B device-coherent h stores (wave 0 only) ----
    if (tid < 64) {
      const int bb = tid >> 1, hf = tid & 1;
      union { bf16x8 b8; i32x4 i4; } u;
      u.b8 = *(const bf16x8*)&hstage[bb][hf * 8];
      store16_sys(Hout + bb * 1024 + d0 + hf * 8, u.i4);
    }
    asm volatile("s_waitcnt vmcnt(0)" ::: "memory");
    __syncthreads();
    if (tid == 0) flag_store(Fb + slot * 16, (unsigned)(s + 1));
  }

  if (scan == 0) {
    // need all stack flags == 256 (sh_hist[256] complete) and reduce flags == 255
    if (tid < 64) {
      while (flag_load(P.flags + tid * 16) < 256u) __builtin_amdgcn_s_sleep(1);
      while (flag_load(P.flags + 1024 + tid * 16) < 255u) __builtin_amdgcn_s_sleep(1);
    }
    __syncthreads();
    f32x4 acc0 = {}, acc1 = {};
    mfma_step(P.sh_hist + (size_t)256 * 32768, Wl, mh, nh, l, acc0, acc1);       // hf @ Whh^T
    mfma_pass_glb(P.rh_hist + (size_t)255 * 32768, P.Wih_s, d0, mh, nh, l, acc0, acc1); // red_h @ Wih^T
#pragma unroll
    for (int r = 0; r < 4; ++r) {
      gsm2[nh * 2 + 0][mbase + r][l & 15] = acc0[r];
      gsm2[nh * 2 + 1][mbase + r][l & 15] = acc1[r];
    }
    __syncthreads();
#pragma unroll
    for (int q = 0; q < 2; ++q) {
      const int b = q ? b1_ : b0_, dd = q ? dd1 : dd0;
      const int d = d0 + dd;
      float creg = q ? creg1 : creg0;   // cf
      float g0 = gsm2[0][b][dd], g1 = gsm2[1][b][dd], g2 = gsm2[2][b][dd], g3 = gsm2[3][b][dd];
      float bi0 = P.sbias[d], bi1 = P.sbias[1024 + d], bi2 = P.sbias[2048 + d], bi3 = P.sbias[3072 + d];
      float c2 = sigmoidf_(g1 + bi1) * creg + sigmoidf_(g0 + bi0) * tanhf(g2 + bi2);
      float h2 = sigmoidf_(g3 + bi3) * tanhf(c2);
      P.s1[b * 1024 + d] = h2;
    }
  }
}

// ---------------- small utility kernels ----------------
__global__ void cast_kernel(__hip_bfloat16* dst, const float* src, int n) {
  int i = blockIdx.x * 256 + threadIdx.x;
  if (i < n) dst[i] = __float2bfloat16(src[i]);
}
__global__ void extract_half_kernel(__hip_bfloat16* dst, const float* src, int n,
                                    int src_stride, int src_off) {
  int i = blockIdx.x * 256 + threadIdx.x;
  if (i < n) {
    int r = i >> 10, k = i & 1023;
    dst[i] = __float2bfloat16(src[(size_t)r * src_stride + src_off + k]);
  }
}
__global__ void bias_kernel(float* dst, const float* a, const float* b, int n) {
  int i = blockIdx.x * 256 + threadIdx.x;
  if (i < n) dst[i] = a[i] + b[i];
}
__global__ void act_table_kernel(const float* emb, const float* Wih, const float* bih,
                                 const float* bhh, float* table) {
  int i = blockIdx.x * 256 + threadIdx.x;
  int a = i >> 12, n = i & 4095;
  float acc = bih[n] + bhh[n];
  const float* er = emb + a * 64;
  const float* wr = Wih + (size_t)n * 64;
  for (int k = 0; k < 64; ++k) acc += er[k] * wr[k];
  table[i] = acc;
}
// fills history slot 0 for all three scans: stack h0, action h0, reduce = hid_t[0]
__global__ void init_states_kernel(const float* stack_h0, const float* act_h0,
                                   const __hip_bfloat16* hid,
                                   __hip_bfloat16* sh0, __hip_bfloat16* ah0,
                                   __hip_bfloat16* rh0, unsigned int* flags)
{
  int i = blockIdx.x * 256 + threadIdx.x;  // 32768
  int d = i & 1023;
  sh0[i] = __float2bfloat16(stack_h0[d]);
  ah0[i] = __float2bfloat16(act_h0[d]);
  rh0[i] = hid[i];
  if (i < 4096) flags[i] = 0u;
}

// ---------------- attention ----------------
__global__ __launch_bounds__(256) void att_q_kernel(
    const float* s1, const float* s2, const float* s3, const float* attW, float* q)
{
  int eb = blockIdx.x, bg = blockIdx.y, j = blockIdx.z;
  const float* sj = (j == 0) ? s1 : ((j == 1) ? s2 : s3);
  __shared__ float ls[4][1024];
  int tid = threadIdx.x;
  for (int i = tid; i < 4096; i += 256)
    ls[i >> 10][i & 1023] = sj[(size_t)(bg * 4 + (i >> 10)) * 1024 + (i & 1023)];
  __syncthreads();
  int e = eb * 256 + tid;
  const float* Wj = attW + (size_t)j * 1024 * 1024;
  float a0 = 0, a1 = 0, a2 = 0, a3 = 0;
  for (int d = 0; d < 1024; ++d) {
    float wv = Wj[(size_t)d * 1024 + e];
    a0 += ls[0][d] * wv; a1 += ls[1][d] * wv; a2 += ls[2][d] * wv; a3 += ls[3][d] * wv;
  }
  q[((size_t)j * 32 + bg * 4 + 0) * 1024 + e] = a0;
  q[((size_t)j * 32 + bg * 4 + 1) * 1024 + e] = a1;
  q[((size_t)j * 32 + bg * 4 + 2) * 1024 + e] = a2;
  q[((size_t)j * 32 + bg * 4 + 3) * 1024 + e] = a3;
}

__global__ __launch_bounds__(256) void att_sc_kernel(const float* q, const float* sent, float* att)
{
  int b = blockIdx.x, j = blockIdx.y;
  __shared__ float qs[1024];
  __shared__ float wsm[256];
  __shared__ float red[8];
  int tid = threadIdx.x, w = tid >> 6, l = tid & 63;
  for (int i = tid; i < 1024; i += 256) qs[i] = q[((size_t)j * 32 + b) * 1024 + i];
  __syncthreads();
  const float* sp = sent + ((size_t)b * 256 + tid) * 1024;
  float dot = 0;
  for (int k = 0; k < 1024; ++k) dot += qs[k] * sp[k];
  float v = dot;
  for (int off = 32; off; off >>= 1) v = fmaxf(v, __shfl_xor(v, off));
  if (l == 0) red[w] = v;
  __syncthreads();
  float m = fmaxf(fmaxf(red[0], red[1]), fmaxf(red[2], red[3]));
  float ex = expf(dot - m);
  float sv = ex;
  for (int off = 32; off; off >>= 1) sv += __shfl_xor(sv, off);
  if (l == 0) red[4 + w] = sv;
  __syncthreads();
  float ssum = red[4] + red[5] + red[6] + red[7];
  wsm[tid] = ex / ssum;
  __syncthreads();
  for (int it = 0; it < 4; ++it) {
    int e = it * 256 + tid;
    float a = 0;
    for (int t2 = 0; t2 < 256; ++t2) a += wsm[t2] * sent[((size_t)b * 256 + t2) * 1024 + e];
    att[((size_t)j * 32 + b) * 1024 + e] = a;
  }
}

// ---------------- head ----------------
__global__ void feat_kernel(const float* s1, const float* s2, const float* s3,
                            const float* tok, const float* atop, const float* att, float* feat)
{
  int i = blockIdx.x * 256 + threadIdx.x;
  int b = i >> 13, jj = (i >> 10) & 7, d = i & 1023;
  int sidx = b * 1024 + d;
  float v;
  switch (jj) {
    case 0: v = s1[sidx]; break;
    case 1: v = s2[sidx]; break;
    case 2: v = s3[sidx]; break;
    case 3: v = tok[d]; break;
    case 4: v = atop[sidx]; break;
    default: v = att[((size_t)(jj - 5) * 32 + b) * 1024 + d];
  }
  feat[i] = v;
}
__global__ __launch_bounds__(256) void head_kernel(const float* feat, const float* W,
                                                   const float* bias, float* fbuf)
{
  int i = blockIdx.x * 256 + threadIdx.x;
  int b = i >> 9, h = i & 511;
  const float4* fr = (const float4*)(feat + (size_t)b * 8192);
  const float4* wr = (const float4*)(W + (size_t)h * 8192);
  float a0 = 0, a1 = 0, a2 = 0, a3 = 0;
  for (int k = 0; k < 2048; ++k) {
    float4 f = fr[k], ww = wr[k];
    a0 += f.x * ww.x; a1 += f.y * ww.y; a2 += f.z * ww.z; a3 += f.w * ww.w;
  }
  fbuf[i] = tanhf(bias[h] + ((a0 + a1) + (a2 + a3)));
}
__global__ void logits_kernel(const float* fbuf, const float* W, const float* bias, float* out)
{
  int b = blockIdx.x, tid = threadIdx.x;
  __shared__ float lg[20];
  __shared__ float mred, lsred;
  if (tid < 20) {
    const float* fr = fbuf + b * 512;
    const float* wr = W + tid * 512;
    float a = bias[tid];
    for (int k = 0; k < 512; ++k) a += fr[k] * wr[k];
    lg[tid] = a;
  }
  __syncthreads();
  if (tid == 0) {
    float m = lg[0];
    for (int i = 1; i < 20; ++i) m = fmaxf(m, lg[i]);
    float ssum = 0;
    for (int i = 0; i < 20; ++i) ssum += expf(lg[i] - m);
    mred = m; lsred = logf(ssum);
  }
  __syncthreads();
  if (tid < 20) out[b * 20 + tid] = lg[tid] - mred - lsred;
}

// ---------------- host ----------------
extern "C" void kernel_launch(void* const* d_in, const int* in_sizes, int n_in,
                              void* d_out, int out_size, void* d_ws, size_t ws_size,
                              hipStream_t stream)
{
  const float* sentence = (const float*)d_in[0];
  const int* actions = (const int*)d_in[1];
  const float* token_empty = (const float*)d_in[2];
  const float* leaf_Wi = (const float*)d_in[3];
  const float* leaf_bi = (const float*)d_in[4];
  const float* leaf_Wo = (const float*)d_in[5];
  const float* leaf_bo = (const float*)d_in[6];
  const float* lstm_Wih = (const float*)d_in[7];
  const float* lstm_Whh = (const float*)d_in[8];
  const float* lstm_bih = (const float*)d_in[9];
  const float* lstm_bhh = (const float*)d_in[10];
  const float* stack_h0 = (const float*)d_in[11];
  const float* stack_c0 = (const float*)d_in[12];
  const float* act_emb = (const float*)d_in[13];
  const float* act_Wih = (const float*)d_in[14];
  const float* act_Whh = (const float*)d_in[15];
  const float* act_bih = (const float*)d_in[16];
  const float* act_bhh = (const float*)d_in[17];
  const float* act_h0 = (const float*)d_in[18];
  const float* act_c0 = (const float*)d_in[19];
  const float* red_W = (const float*)d_in[20];
  const float* red_b = (const float*)d_in[21];
  const float* h2f_W = (const float*)d_in[22];
  const float* h2f_b = (const float*)d_in[23];
  const float* f2a_W = (const float*)d_in[24];
  const float* f2a_b = (const float*)d_in[25];
  const float* att_W = (const float*)d_in[26];
  float* out = (float*)d_out;
  (void)in_sizes; (void)n_in; (void)out_size; (void)ws_size;

  char* ws = (char*)d_ws;
  size_t off = 0;
  auto alloc = [&](size_t bytes) -> void* {
    void* ptr = ws + off;
    off += (bytes + 255) & ~(size_t)255;
    return ptr;
  };
  // ---- aliased arena (56 MB): phase 1 holds sent_bf|cell_f32|Wx_r (all dead
  // before init_states); phase 2 holds the three h-history buffers (50.5 MB).
  char* arena = (char*)alloc(58720256);
  __hip_bfloat16* sent_bf = (__hip_bfloat16*)arena;                 // 16 MB
  float* cell_f32 = (float*)(arena + 16777216);                     // 32 MB
  __hip_bfloat16* Wx_r = (__hip_bfloat16*)(arena + 50331648);       //  8 MB
  __hip_bfloat16* sh_hist = (__hip_bfloat16*)arena;                 // [257][32][1024]
  __hip_bfloat16* rh_hist = (__hip_bfloat16*)(arena + 16843008);
  __hip_bfloat16* ah_hist = (__hip_bfloat16*)(arena + 33686016);

  __hip_bfloat16* hid_bf  = (__hip_bfloat16*)alloc(16777216);   // [8192][1024] (t*32+b)
  __hip_bfloat16* lWi_bf = (__hip_bfloat16*)alloc(2097152);
  __hip_bfloat16* lWo_bf = (__hip_bfloat16*)alloc(2097152);
  __hip_bfloat16* Whh_s = (__hip_bfloat16*)alloc(8388608);
  __hip_bfloat16* Wih_s = (__hip_bfloat16*)alloc(8388608);
  __hip_bfloat16* Whh_r = (__hip_bfloat16*)alloc(8388608);
  __hip_bfloat16* Whh_a = (__hip_bfloat16*)alloc(8388608);
  __hip_bfloat16* xgs_blk = (__hip_bfloat16*)alloc(67108864);   // [64][256][2048]
  __hip_bfloat16* xgr_blk = (__hip_bfloat16*)alloc(67108864);
  __hip_bfloat16* cellblk = (__hip_bfloat16*)alloc(16777216);   // [64][256][512]
  float* table = (float*)alloc(327680);
  float* sbias = (float*)alloc(16384);
  float* s1 = (float*)alloc(131072);
  float* s2 = (float*)alloc(131072);
  float* s3 = (float*)alloc(131072);
  float* atop = (float*)alloc(131072);
  unsigned int* flags = (unsigned int*)alloc(16384);  // 3*64 flags, 64B apart
  float* qbuf = (float*)alloc(393216);
  float* attbuf = (float*)alloc(393216);
  float* feat = (float*)alloc(1048576);
  float* fbuf = (float*)alloc(65536);

  // conversions (phase 1 of arena)
  cast_kernel<<<32768, 256, 0, stream>>>(sent_bf, sentence, 8388608);
  cast_kernel<<<4096, 256, 0, stream>>>(lWi_bf, leaf_Wi, 1048576);
  cast_kernel<<<4096, 256, 0, stream>>>(lWo_bf, leaf_Wo, 1048576);
  cast_kernel<<<16384, 256, 0, stream>>>(Whh_s, lstm_Whh, 4194304);
  cast_kernel<<<16384, 256, 0, stream>>>(Wih_s, lstm_Wih, 4194304);
  cast_kernel<<<16384, 256, 0, stream>>>(Whh_a, act_Whh, 4194304);
  extract_half_kernel<<<16384, 256, 0, stream>>>(Whh_r, red_W, 4194304, 2048, 0);
  extract_half_kernel<<<16384, 256, 0, stream>>>(Wx_r, red_W, 4194304, 2048, 1024);
  bias_kernel<<<16, 256, 0, stream>>>(sbias, lstm_bih, lstm_bhh, 4096);
  act_table_kernel<<<320, 256, 0, stream>>>(act_emb, act_Wih, act_bih, act_bhh, table);

  // leaf module (consumes sent_bf, produces+consumes cell_f32)
  gemm_bt_kernel<<<dim3(64, 8), 256, 0, stream>>>(sent_bf, lWi_bf, cell_f32, nullptr,
                                                  leaf_bi, nullptr, 8192, 1024, 1024, 1, 0);
  gemm_bt_kernel<<<dim3(64, 8), 256, 0, stream>>>(sent_bf, lWo_bf, nullptr, hid_bf,
                                                  leaf_bo, cell_f32, 8192, 1024, 1024, 1, 2);
  cellblk_kernel<<<256, 256, 0, stream>>>(cell_f32, cellblk);

  // precomputed x-gates in blk layout (bias folded); xg_r consumes Wx_r (arena)
  gemm_bt_kernel<<<dim3(64, 32), 256, 0, stream>>>(hid_bf, Wih_s, nullptr, xgs_blk,
                                                   sbias, nullptr, 8192, 4096, 1024, 0, 3);
  gemm_bt_kernel<<<dim3(64, 32), 256, 0, stream>>>(hid_bf, Wx_r, nullptr, xgr_blk,
                                                   red_b, nullptr, 8192, 4096, 1024, 0, 3);

  // phase 2 of arena begins: overwrite with history slot 0
  init_states_kernel<<<128, 256, 0, stream>>>(stack_h0, act_h0, hid_bf,
                                              sh_hist, ah_hist, rh_hist, flags);

  PP P;
  P.Whh_s = Whh_s; P.Wih_s = Wih_s; P.Whh_r = Whh_r; P.Whh_a = Whh_a;
  P.xgs_blk = xgs_blk; P.xgr_blk = xgr_blk; P.cellblk = cellblk;
  P.table = table; P.actions = actions;
  P.stack_c0 = stack_c0; P.act_c0 = act_c0; P.sbias = sbias;
  P.sh_hist = sh_hist; P.rh_hist = rh_hist; P.ah_hist = ah_hist;
  P.s1 = s1; P.s2 = s2; P.s3 = s3; P.atop = atop;
  P.flags = flags;
  scan_persist<<<192, 256, 0, stream>>>(P);

  // attention: s1, s2, s3
  att_q_kernel<<<dim3(4, 8, 3), 256, 0, stream>>>(s1, s2, s3, att_W, qbuf);
  att_sc_kernel<<<dim3(32, 3), 256, 0, stream>>>(qbuf, sentence, attbuf);

  // head
  feat_kernel<<<1024, 256, 0, stream>>>(s1, s2, s3, token_empty, atop, attbuf, feat);
  head_kernel<<<64, 256, 0, stream>>>(feat, h2f_W, h2f_b, fbuf);
  logits_kernel<<<32, 64, 0, stream>>>(fbuf, f2a_W, f2a_b, out);
}

// Round 14
// 2522.312 us; speedup vs baseline: 1.4823x; 1.0122x over previous
//
#include <hip/hip_runtime.h>
#include <hip/hip_bf16.h>
#include <math.h>

// B=32, T=256, D=1024, A=64, H=512, NA=20
#define DEV __device__ __forceinline__

typedef __bf16 bf16_t;
typedef bf16_t bf16x8 __attribute__((ext_vector_type(8)));
typedef float f32x4 __attribute__((ext_vector_type(4)));
typedef int i32x4 __attribute__((ext_vector_type(4)));

DEV void async16(const void* g, void* l) {
  __builtin_amdgcn_global_load_lds((const __attribute__((address_space(1))) void*)g,
                                   (__attribute__((address_space(3))) void*)l, 16, 0, 0);
}
DEV float sigmoidf_(float x) { return 1.f / (1.f + expf(-x)); }
DEV bf16x8 as_bf(i32x4 v) { union { i32x4 i; bf16x8 b; } u; u.i = v; return u.b; }

// ---- fine-grained device-coherent ops ----
DEV unsigned flag_load(const unsigned* p) {
  unsigned v;
  asm volatile("global_load_dword %0, %1, off sc0 sc1\ns_waitcnt vmcnt(0)"
               : "=v"(v) : "v"(p) : "memory");
  return v;
}
DEV void flag_store(unsigned* p, unsigned v) {
  asm volatile("global_store_dword %0, %1, off sc0 sc1" :: "v"(p), "v"(v) : "memory");
}
DEV void store16_sys(void* p, i32x4 v) {
  asm volatile("global_store_dwordx4 %0, %1, off sc0 sc1" :: "v"(p), "v"(v) : "memory");
}

#define WAITV(N) do { asm volatile("s_waitcnt vmcnt(" #N ")" ::: "memory"); \
                      __builtin_amdgcn_sched_barrier(0); } while (0)

template<int KB>
DEV void loads8(i32x4* dst, const __hip_bfloat16* arow) {
#pragma unroll
  for (int i = 0; i < 8; ++i)
    asm volatile("global_load_dwordx4 %0, %1, off offset:%2"
                 : "=v"(dst[i]) : "v"(arow), "i"((KB + i) * 64));
}
DEV void loads8rt(i32x4* dst, const __hip_bfloat16* arow, int kbase) {
#pragma unroll
  for (int i = 0; i < 8; ++i)
    asm volatile("global_load_dwordx4 %0, %1, off"
                 : "=v"(dst[i]) : "v"(arow + (size_t)(kbase + i) * 32) : "memory");
}

template<int C>
DEV void ldsb8(bf16x8* b0, bf16x8* b1, const __hip_bfloat16* Wl,
               int sw, int kof, int r0, int r1) {
#pragma unroll
  for (int i = 0; i < 8; ++i) {
    const int kk = (C * 8 + i) * 32 + kof;
    b0[i] = *(const bf16x8*)&Wl[r0 * 1024 + (kk ^ sw)];
    b1[i] = *(const bf16x8*)&Wl[r1 * 1024 + (kk ^ sw)];
  }
}
DEV void mfma8x(const i32x4* a, const bf16x8* b0, const bf16x8* b1,
                f32x4& acc0, f32x4& acc1) {
#pragma unroll
  for (int i = 0; i < 8; ++i) {
    bf16x8 av = as_bf(a[i]);
    acc0 = __builtin_amdgcn_mfma_f32_16x16x32_bf16(av, b0[i], acc0, 0, 0, 0);
    acc1 = __builtin_amdgcn_mfma_f32_16x16x32_bf16(av, b1[i], acc1, 0, 0, 0);
  }
}

// full-K step used only in the drained final phase (all vmcnt self-contained)
DEV void mfma_step(const __hip_bfloat16* Ap, const __hip_bfloat16* Wl,
                   int mh, int nh, int l, f32x4& acc0, f32x4& acc1) {
  const __hip_bfloat16* arow = Ap + (mh * 16 + (l & 15)) * 1024 + (l >> 4) * 8;
  const int sw = (l & 7) << 3, kof = (l >> 4) * 8;
  const int r0 = nh * 32 + (l & 15), r1 = r0 + 16;
  i32x4 A0[8], A1[8], A2[8], A3[8];
  bf16x8 Ba0[8], Ba1[8], Bb0[8], Bb1[8];
  loads8<0>(A0, arow);
  loads8<8>(A1, arow);
  loads8<16>(A2, arow);
  loads8<24>(A3, arow);
  ldsb8<0>(Ba0, Ba1, Wl, sw, kof, r0, r1);
  WAITV(24);
  mfma8x(A0, Ba0, Ba1, acc0, acc1);
  ldsb8<1>(Bb0, Bb1, Wl, sw, kof, r0, r1);
  WAITV(16);
  mfma8x(A1, Bb0, Bb1, acc0, acc1);
  ldsb8<2>(Ba0, Ba1, Wl, sw, kof, r0, r1);
  WAITV(8);
  mfma8x(A2, Ba0, Ba1, acc0, acc1);
  ldsb8<3>(Bb0, Bb1, Wl, sw, kof, r0, r1);
  WAITV(0);
  mfma8x(A3, Bb0, Bb1, acc0, acc1);
}

// final-phase pass: A cached loads, W from global (cached)
DEV void mfma_pass_glb(const __hip_bfloat16* Ap, const __hip_bfloat16* __restrict__ Wg,
                       int d0, int mh, int nh, int l, f32x4& acc0, f32x4& acc1) {
  const __hip_bfloat16* arow = Ap + (mh * 16 + (l & 15)) * 1024 + (l >> 4) * 8;
  const size_t g0 = ((size_t)(2 * nh) * 1024 + d0 + (l & 15)) * 1024;
  const size_t g1 = g0 + 1048576;
  const int kof = (l >> 4) * 8;
  i32x4 A[8];
  for (int c = 0; c < 4; ++c) {
    loads8rt(A, arow, c * 8);
    WAITV(0);
#pragma unroll
    for (int i = 0; i < 8; ++i) {
      const int kk = (c * 8 + i) * 32 + kof;
      bf16x8 b0 = *(const bf16x8*)&Wg[g0 + kk];
      bf16x8 b1 = *(const bf16x8*)&Wg[g1 + kk];
      bf16x8 av = as_bf(A[i]);
      acc0 = __builtin_amdgcn_mfma_f32_16x16x32_bf16(av, b0, acc0, 0, 0, 0);
      acc1 = __builtin_amdgcn_mfma_f32_16x16x32_bf16(av, b1, acc1, 0, 0, 0);
    }
  }
}

// ---------------- generic bf16 MFMA GEMM: C[M,N] = A[M,K] @ Bw[N,K]^T + bias ----------------
// mode 0: outF = acc+bias (f32); mode 1: outBF = bf16(acc+bias)
// mode 2: outBF = bf16(sigmoid(acc+bias)*tanh(aux))
// mode 3: outBF is blk layout [slot][256 t][2048] chunk [g*512 + b*16 + dd]; rows must be t*32+b
__global__ __launch_bounds__(256) void gemm_bt_kernel(
    const __hip_bfloat16* __restrict__ A, const __hip_bfloat16* __restrict__ Bw,
    float* __restrict__ outF, __hip_bfloat16* __restrict__ outBF,
    const float* __restrict__ bias, const float* __restrict__ aux,
    int M, int N, int K, int remap, int mode)
{
  __shared__ __hip_bfloat16 As[128 * 64];
  __shared__ __hip_bfloat16 Bs[128 * 64];
  __shared__ __hip_bfloat16 Cs[128 * 128];   // mode-3 staging only
  const int tid = threadIdx.x;
  const int w = tid >> 6, l = tid & 63;
  const int m0 = blockIdx.x * 128, n0 = blockIdx.y * 128;
  const int wm = (w >> 1) * 64, wn = (w & 1) * 64;
  const int row_s = tid >> 3, kc = tid & 7;
  f32x4 acc[4][4] = {};
  for (int k0 = 0; k0 < K; k0 += 64) {
    const __hip_bfloat16* ga = A + (size_t)(m0 + row_s) * K + k0 + kc * 8;
    const __hip_bfloat16* gb = Bw + (size_t)(n0 + row_s) * K + k0 + kc * 8;
    __hip_bfloat16* la = As + w * 512;
    __hip_bfloat16* lb = Bs + w * 512;
#pragma unroll
    for (int p = 0; p < 4; ++p) {
      async16(ga + (size_t)p * 32 * K, la + p * 2048);
      async16(gb + (size_t)p * 32 * K, lb + p * 2048);
    }
    __syncthreads();
#pragma unroll
    for (int kb = 0; kb < 2; ++kb) {
      bf16x8 af[4], bfr[4];
#pragma unroll
      for (int i = 0; i < 4; ++i)
        af[i] = *(const bf16x8*)&As[(wm + i * 16 + (l & 15)) * 64 + kb * 32 + (l >> 4) * 8];
#pragma unroll
      for (int j = 0; j < 4; ++j)
        bfr[j] = *(const bf16x8*)&Bs[(wn + j * 16 + (l & 15)) * 64 + kb * 32 + (l >> 4) * 8];
#pragma unroll
      for (int i = 0; i < 4; ++i)
#pragma unroll
        for (int j = 0; j < 4; ++j)
          acc[i][j] = __builtin_amdgcn_mfma_f32_16x16x32_bf16(af[i], bfr[j], acc[i][j], 0, 0, 0);
    }
    __syncthreads();
  }
  if (mode == 3) {
#pragma unroll
    for (int i = 0; i < 4; ++i)
#pragma unroll
      for (int j = 0; j < 4; ++j) {
        const int ncol = n0 + wn + j * 16 + (l & 15);
        const float bv = bias[ncol];
#pragma unroll
        for (int r = 0; r < 4; ++r) {
          const int lr = wm + i * 16 + (l >> 4) * 4 + r;
          Cs[lr * 128 + wn + j * 16 + (l & 15)] = __float2bfloat16(acc[i][j][r] + bv);
        }
      }
    __syncthreads();
    const int t0 = m0 >> 5, g = n0 >> 10, slot0 = (n0 & 1023) >> 4;
    const int grp = tid >> 6, li = tid & 63;
    const int b = li >> 1, half = li & 1;
#pragma unroll
    for (int sl = 0; sl < 8; ++sl) {
      bf16x8 vv = *(const bf16x8*)&Cs[(grp * 32 + b) * 128 + sl * 16 + half * 8];
      *(bf16x8*)&outBF[(((size_t)(slot0 + sl)) * 256 + t0 + grp) * 2048 +
                       g * 512 + b * 16 + half * 8] = vv;
    }
    return;
  }
#pragma unroll
  for (int i = 0; i < 4; ++i) {
#pragma unroll
    for (int j = 0; j < 4; ++j) {
      const int ncol = n0 + wn + j * 16 + (l & 15);
      const float bv = bias ? bias[ncol] : 0.f;
#pragma unroll
      for (int r = 0; r < 4; ++r) {
        int m = m0 + wm + i * 16 + (l >> 4) * 4 + r;
        int row = remap ? (((m & 255) << 5) | (m >> 8)) : m;
        float v = acc[i][j][r] + bv;
        if (mode == 0) {
          outF[(size_t)row * N + ncol] = v;
        } else if (mode == 1) {
          outBF[(size_t)row * N + ncol] = __float2bfloat16(v);
        } else {
          float cv = aux[(size_t)row * N + ncol];
          outBF[(size_t)row * N + ncol] = __float2bfloat16(sigmoidf_(v) * tanhf(cv));
        }
      }
    }
  }
}

// cell [8192][1024] f32 (rows t*32+b) -> blk [64 slot][256 t][32 b][16 dd] bf16
__global__ __launch_bounds__(256) void cellblk_kernel(const float* __restrict__ cell,
                                                      __hip_bfloat16* __restrict__ blk)
{
  __shared__ __hip_bfloat16 ls[32 * 1024];   // 64 KB
  const int t = blockIdx.x, tid = threadIdx.x;
  for (int i = tid; i < 8192; i += 256) {
    float4 v = ((const float4*)(cell + (size_t)t * 32768))[i];
    __hip_bfloat16* d = &ls[i * 4];
    d[0] = __float2bfloat16(v.x); d[1] = __float2bfloat16(v.y);
    d[2] = __float2bfloat16(v.z); d[3] = __float2bfloat16(v.w);
  }
  __syncthreads();
  const int e = tid * 2;
  const int b = e >> 4, dd = e & 15;
  for (int sl = 0; sl < 64; ++sl) {
    union { __hip_bfloat16 h[2]; unsigned u; } pk;
    pk.h[0] = ls[b * 1024 + sl * 16 + dd];
    pk.h[1] = ls[b * 1024 + sl * 16 + dd + 1];
    *(unsigned*)&blk[((size_t)sl * 256 + t) * 512 + e] = pk.u;
  }
}

// ---------------- persistent scan ----------------
struct PP {
  const __hip_bfloat16 *Whh_s, *Wih_s, *Whh_r, *Whh_a;  // [4096][1024]
  const __hip_bfloat16 *xgs_blk, *xgr_blk;  // [64][256][2048] blk-layout x-gates
  const __hip_bfloat16* cellblk; // [64][256][512] blk-layout bf16 cell
  const float* table;            // [20][4096]
  const int* actions;            // [32][256]
  const float *stack_c0, *act_c0, *sbias;
  __hip_bfloat16 *sh_hist, *rh_hist, *ah_hist;  // [257][32][1024] h history
  float *s1, *s2, *s3, *atop;    // [32][1024] f32
  unsigned int* flags;           // [scan*1024 + slot*16]: per-block flags, 64B apart
};

__global__ __launch_bounds__(256, 1) void scan_persist(PP P)
{
  __shared__ __hip_bfloat16 Wl[64 * 1024];             // 128 KB, XOR-swizzled
  __shared__ float gsm2[4][32][17];                    // gate exchange, conflict-free layout
  __shared__ __align__(16) __hip_bfloat16 hstage[32][16];  // 1 KB packed h staging
  const int bid = blockIdx.x;
  const int scan = bid >> 6;                 // 0 stack, 1 reduce, 2 action
  const int slot = bid & 63;
  const int d0 = slot * 16;
  const int tid = threadIdx.x;
  const int l = tid & 63, w = tid >> 6;
  const int mh = w >> 1, nh = w & 1;

  const __hip_bfloat16* Wg = (scan == 0) ? P.Whh_s : ((scan == 1) ? P.Whh_r : P.Whh_a);
  for (int idx = tid; idx < 64 * 128; idx += 256) {
    int r = idx >> 7, k = (idx & 127) * 8;
    int grow = ((r >> 4) << 10) + d0 + (r & 15);
    bf16x8 v = *(const bf16x8*)&Wg[(size_t)grow * 1024 + k];
    *(bf16x8*)&Wl[r * 1024 + (k ^ ((r & 7) << 3))] = v;
  }
  const int e0 = tid, e1 = tid + 256;
  const int b0_ = e0 >> 4, dd0 = e0 & 15, b1_ = e1 >> 4, dd1 = e1 & 15;
  float creg0, creg1;
  if (scan == 0)      { creg0 = P.stack_c0[d0 + dd0]; creg1 = P.stack_c0[d0 + dd1]; }
  else if (scan == 1) {
    creg0 = __bfloat162float(P.cellblk[(size_t)slot * 256 * 512 + b0_ * 16 + dd0]);
    creg1 = __bfloat162float(P.cellblk[(size_t)slot * 256 * 512 + b1_ * 16 + dd1]);
  }
  else                { creg0 = P.act_c0[d0 + dd0]; creg1 = P.act_c0[d0 + dd1]; }
  __syncthreads();

  __hip_bfloat16* hist = (scan == 0) ? P.sh_hist : ((scan == 1) ? P.rh_hist : P.ah_hist);
  unsigned int* Fb = P.flags + scan * 1024;   // 64 flags, 64B apart
  const int Ns = (scan == 1) ? 255 : 256;
  const int mbase = mh * 16 + (l >> 4) * 4;
  const int sw = (l & 7) << 3, kof = (l >> 4) * 8;
  const int r0 = nh * 32 + (l & 15), r1 = r0 + 16;

  for (int s = 0; s < Ns; ++s) {
    const __hip_bfloat16* Ap = hist + (size_t)s * 32768;
    __hip_bfloat16* Hout = hist + (size_t)(s + 1) * 32768;

    // ---- prefix gate prefetch: plain loads, compiler-managed waits ----
    __hip_bfloat16 pg0, pg1, pg2, pg3, pg4, pg5, pg6, pg7;
    __hip_bfloat16 pcb0, pcb1;
    int pa0 = 0, pa1 = 0;
    pg0 = pg1 = pg2 = pg3 = pg4 = pg5 = pg6 = pg7 = __float2bfloat16(0.f);
    pcb0 = pcb1 = __float2bfloat16(0.f);
    if (scan == 0) {
      const __hip_bfloat16* x0 = P.xgs_blk + ((size_t)slot * 256 + s) * 2048 + b0_ * 16 + dd0;
      const __hip_bfloat16* x1 = P.xgs_blk + ((size_t)slot * 256 + s) * 2048 + b1_ * 16 + dd1;
      pg0 = x0[0]; pg1 = x0[512]; pg2 = x0[1024]; pg3 = x0[1536];
      pg4 = x1[0]; pg5 = x1[512]; pg6 = x1[1024]; pg7 = x1[1536];
    } else if (scan == 1) {
      const __hip_bfloat16* x0 = P.xgr_blk + ((size_t)slot * 256 + s + 1) * 2048 + b0_ * 16 + dd0;
      const __hip_bfloat16* x1 = P.xgr_blk + ((size_t)slot * 256 + s + 1) * 2048 + b1_ * 16 + dd1;
      pg0 = x0[0]; pg1 = x0[512]; pg2 = x0[1024]; pg3 = x0[1536];
      pg4 = x1[0]; pg5 = x1[512]; pg6 = x1[1024]; pg7 = x1[1536];
      pcb0 = P.cellblk[((size_t)slot * 256 + s + 1) * 512 + b0_ * 16 + dd0];
      pcb1 = P.cellblk[((size_t)slot * 256 + s + 1) * 512 + b1_ * 16 + dd1];
    } else {
      pa0 = P.actions[b0_ * 256 + s];
      pa1 = P.actions[b1_ * 256 + s];
    }
    __builtin_amdgcn_sched_barrier(0);

    // ---- barrier phase A: slots 0-31 (h d 0..511 of hist[s] ready) ----
    if (s > 0 && tid < 32) {
      const unsigned tgt = (unsigned)s;
      if (flag_load(Fb + tid * 16) < tgt)
        while (flag_load(Fb + tid * 16) < tgt) __builtin_amdgcn_s_sleep(1);
    }
    __syncthreads();

    // issue A-loads for k 0..511 (covered by slots 0-31)
    const __hip_bfloat16* arow = Ap + (mh * 16 + (l & 15)) * 1024 + kof;
    i32x4 A0[8], A1[8], A2[8], A3[8];
    loads8<0>(A0, arow);
    loads8<8>(A1, arow);

    // ---- barrier phase B: slots 32-63; poll's vmcnt(0) drains A0/A1 in parallel ----
    if (s > 0 && tid < 32) {
      const unsigned tgt = (unsigned)s;
      if (flag_load(Fb + (32 + tid) * 16) < tgt)
        while (flag_load(Fb + (32 + tid) * 16) < tgt) __builtin_amdgcn_s_sleep(1);
    }
    __syncthreads();
    WAITV(0);                        // all lanes: A0/A1 resident
    loads8<16>(A2, arow);
    loads8<24>(A3, arow);

    f32x4 acc0 = {}, acc1 = {};
    bf16x8 Ba0[8], Ba1[8], Bb0[8], Bb1[8];
    ldsb8<0>(Ba0, Ba1, Wl, sw, kof, r0, r1);
    mfma8x(A0, Ba0, Ba1, acc0, acc1);
    ldsb8<1>(Bb0, Bb1, Wl, sw, kof, r0, r1);
    mfma8x(A1, Bb0, Bb1, acc0, acc1);
    ldsb8<2>(Ba0, Ba1, Wl, sw, kof, r0, r1);
    WAITV(8);
    mfma8x(A2, Ba0, Ba1, acc0, acc1);
    ldsb8<3>(Bb0, Bb1, Wl, sw, kof, r0, r1);
    WAITV(0);
    mfma8x(A3, Bb0, Bb1, acc0, acc1);

#pragma unroll
    for (int r = 0; r < 4; ++r) {
      gsm2[nh * 2 + 0][mbase + r][l & 15] = acc0[r];
      gsm2[nh * 2 + 1][mbase + r][l & 15] = acc1[r];
    }
    __syncthreads();
#pragma unroll
    for (int q = 0; q < 2; ++q) {
      const int b = q ? b1_ : b0_, dd = q ? dd1 : dd0;
      const int d = d0 + dd;
      float& creg = q ? creg1 : creg0;
      float g0 = gsm2[0][b][dd], g1 = gsm2[1][b][dd], g2 = gsm2[2][b][dd], g3 = gsm2[3][b][dd];
      if (scan == 1) {
        float ig = sigmoidf_(g0 + __bfloat162float(q ? pg4 : pg0));
        float lg = sigmoidf_(g1 + __bfloat162float(q ? pg5 : pg1));
        float rg = sigmoidf_(g2 + __bfloat162float(q ? pg6 : pg2));
        float cand = tanhf(g3 + __bfloat162float(q ? pg7 : pg3));
        float rcv = __bfloat162float(q ? pcb1 : pcb0);
        float c2 = ig * cand + lg * creg + rg * rcv;
        creg = c2;
        hstage[b][dd] = __float2bfloat16(tanhf(c2));
      } else {
        float bi0, bi1, bi2, bi3;
        if (scan == 0) {
          bi0 = __bfloat162float(q ? pg4 : pg0); bi1 = __bfloat162float(q ? pg5 : pg1);
          bi2 = __bfloat162float(q ? pg6 : pg2); bi3 = __bfloat162float(q ? pg7 : pg3);
        } else {
          int a = q ? pa1 : pa0;
          const float* tb = P.table + a * 4096;
          bi0 = tb[d]; bi1 = tb[1024 + d]; bi2 = tb[2048 + d]; bi3 = tb[3072 + d];
        }
        float c2 = sigmoidf_(g1 + bi1) * creg + sigmoidf_(g0 + bi0) * tanhf(g2 + bi2);
        float h2 = sigmoidf_(g3 + bi3) * tanhf(c2);
        creg = c2;
        hstage[b][dd] = __float2bfloat16(h2);
        if (scan == 0 && s == 254) P.s3[b * 1024 + d] = h2;
        if (scan == 0 && s == 255) P.s2[b * 1024 + d] = h2;
        if (scan == 2 && s == 255) P.atop[b * 1024 + d] = h2;
      }
    }
    __syncthreads();
    // ---- packed 16B device-coherent h stores (wave 0 only) ----
    if (tid < 64) {
      const int bb = tid >> 1, hf = tid & 1;
      union { bf16x8 b8; i32x4 i4; } u;
      u.b8 = *(const bf16x8*)&hstage[bb][hf * 8];
      store16_sys(Hout + bb * 1024 + d0 + hf * 8, u.i4);
    }
    asm volatile("s_waitcnt vmcnt(0)" ::: "memory");
    __syncthreads();
    if (tid == 0) flag_store(Fb + slot * 16, (unsigned)(s + 1));
  }

  if (scan == 0) {
    // need all stack flags == 256 (sh_hist[256] complete) and reduce flags == 255
    if (tid < 64) {
      while (flag_load(P.flags + tid * 16) < 256u) __builtin_amdgcn_s_sleep(1);
      while (flag_load(P.flags + 1024 + tid * 16) < 255u) __builtin_amdgcn_s_sleep(1);
    }
    __syncthreads();
    f32x4 acc0 = {}, acc1 = {};
    mfma_step(P.sh_hist + (size_t)256 * 32768, Wl, mh, nh, l, acc0, acc1);       // hf @ Whh^T
    mfma_pass_glb(P.rh_hist + (size_t)255 * 32768, P.Wih_s, d0, mh, nh, l, acc0, acc1); // red_h @ Wih^T
#pragma unroll
    for (int r = 0; r < 4; ++r) {
      gsm2[nh * 2 + 0][mbase + r][l & 15] = acc0[r];
      gsm2[nh * 2 + 1][mbase + r][l & 15] = acc1[r];
    }
    __syncthreads();
#pragma unroll
    for (int q = 0; q < 2; ++q) {
      const int b = q ? b1_ : b0_, dd = q ? dd1 : dd0;
      const int d = d0 + dd;
      float creg = q ? creg1 : creg0;   // cf
      float g0 = gsm2[0][b][dd], g1 = gsm2[1][b][dd], g2 = gsm2[2][b][dd], g3 = gsm2[3][b][dd];
      float bi0 = P.sbias[d], bi1 = P.sbias[1024 + d], bi2 = P.sbias[2048 + d], bi3 = P.sbias[3072 + d];
      float c2 = sigmoidf_(g1 + bi1) * creg + sigmoidf_(g0 + bi0) * tanhf(g2 + bi2);
      float h2 = sigmoidf_(g3 + bi3) * tanhf(c2);
      P.s1[b * 1024 + d] = h2;
    }
  }
}

// ---------------- small utility kernels ----------------
// vectorized f32 -> bf16 cast: 4 elems/thread
__global__ void cast4_kernel(__hip_bfloat16* dst, const float* src, int n4) {
  int i = blockIdx.x * 256 + threadIdx.x;
  if (i < n4) {
    float4 v = ((const float4*)src)[i];
    union { __hip_bfloat16 h[4]; unsigned long long u; } pk;
    pk.h[0] = __float2bfloat16(v.x); pk.h[1] = __float2bfloat16(v.y);
    pk.h[2] = __float2bfloat16(v.z); pk.h[3] = __float2bfloat16(v.w);
    *(unsigned long long*)&dst[i * 4] = pk.u;
  }
}
// vectorized half-extract from red_W [4096][2048]: dst[r][k] = bf16(src[r*2048+off+k])
__global__ void extract_half4_kernel(__hip_bfloat16* dst, const float* src, int n4,
                                     int src_off) {
  int i = blockIdx.x * 256 + threadIdx.x;   // n4 = 4096*1024/4
  if (i < n4) {
    int r = i >> 8, k4 = i & 255;
    float4 v = *(const float4*)(src + (size_t)r * 2048 + src_off + k4 * 4);
    union { __hip_bfloat16 h[4]; unsigned long long u; } pk;
    pk.h[0] = __float2bfloat16(v.x); pk.h[1] = __float2bfloat16(v.y);
    pk.h[2] = __float2bfloat16(v.z); pk.h[3] = __float2bfloat16(v.w);
    *(unsigned long long*)&dst[i * 4] = pk.u;
  }
}
__global__ void bias_kernel(float* dst, const float* a, const float* b, int n) {
  int i = blockIdx.x * 256 + threadIdx.x;
  if (i < n) dst[i] = a[i] + b[i];
}
__global__ void act_table_kernel(const float* emb, const float* Wih, const float* bih,
                                 const float* bhh, float* table) {
  int i = blockIdx.x * 256 + threadIdx.x;
  int a = i >> 12, n = i & 4095;
  float acc = bih[n] + bhh[n];
  const float* er = emb + a * 64;
  const float* wr = Wih + (size_t)n * 64;
  for (int k = 0; k < 64; ++k) acc += er[k] * wr[k];
  table[i] = acc;
}
// fills history slot 0 for all three scans: stack h0, action h0, reduce = hid_t[0]
__global__ void init_states_kernel(const float* stack_h0, const float* act_h0,
                                   const __hip_bfloat16* hid,
                                   __hip_bfloat16* sh0, __hip_bfloat16* ah0,
                                   __hip_bfloat16* rh0, unsigned int* flags)
{
  int i = blockIdx.x * 256 + threadIdx.x;  // 32768
  int d = i & 1023;
  sh0[i] = __float2bfloat16(stack_h0[d]);
  ah0[i] = __float2bfloat16(act_h0[d]);
  rh0[i] = hid[i];
  if (i < 4096) flags[i] = 0u;
}

// ---------------- attention ----------------
__global__ __launch_bounds__(256) void att_q_kernel(
    const float* s1, const float* s2, const float* s3, const float* attW, float* q)
{
  int eb = blockIdx.x, bg = blockIdx.y, j = blockIdx.z;
  const float* sj = (j == 0) ? s1 : ((j == 1) ? s2 : s3);
  __shared__ float ls[4][1024];
  int tid = threadIdx.x;
  for (int i = tid; i < 4096; i += 256)
    ls[i >> 10][i & 1023] = sj[(size_t)(bg * 4 + (i >> 10)) * 1024 + (i & 1023)];
  __syncthreads();
  int e = eb * 256 + tid;
  const float* Wj = attW + (size_t)j * 1024 * 1024;
  float a0 = 0, a1 = 0, a2 = 0, a3 = 0;
  for (int d = 0; d < 1024; ++d) {
    float wv = Wj[(size_t)d * 1024 + e];
    a0 += ls[0][d] * wv; a1 += ls[1][d] * wv; a2 += ls[2][d] * wv; a3 += ls[3][d] * wv;
  }
  q[((size_t)j * 32 + bg * 4 + 0) * 1024 + e] = a0;
  q[((size_t)j * 32 + bg * 4 + 1) * 1024 + e] = a1;
  q[((size_t)j * 32 + bg * 4 + 2) * 1024 + e] = a2;
  q[((size_t)j * 32 + bg * 4 + 3) * 1024 + e] = a3;
}

__global__ __launch_bounds__(256) void att_sc_kernel(const float* q, const float* sent, float* att)
{
  int b = blockIdx.x, j = blockIdx.y;
  __shared__ float qs[1024];
  __shared__ float wsm[256];
  __shared__ float red[8];
  int tid = threadIdx.x, w = tid >> 6, l = tid & 63;
  for (int i = tid; i < 1024; i += 256) qs[i] = q[((size_t)j * 32 + b) * 1024 + i];
  __syncthreads();
  const float4* sp = (const float4*)(sent + ((size_t)b * 256 + tid) * 1024);
  const float4* qs4 = (const float4*)qs;
  float dot = 0;
  for (int k = 0; k < 256; ++k) {
    float4 s4 = sp[k], q4 = qs4[k];
    dot += s4.x * q4.x + s4.y * q4.y + s4.z * q4.z + s4.w * q4.w;
  }
  float v = dot;
  for (int off = 32; off; off >>= 1) v = fmaxf(v, __shfl_xor(v, off));
  if (l == 0) red[w] = v;
  __syncthreads();
  float m = fmaxf(fmaxf(red[0], red[1]), fmaxf(red[2], red[3]));
  float ex = expf(dot - m);
  float sv = ex;
  for (int off = 32; off; off >>= 1) sv += __shfl_xor(sv, off);
  if (l == 0) red[4 + w] = sv;
  __syncthreads();
  float ssum = red[4] + red[5] + red[6] + red[7];
  wsm[tid] = ex / ssum;
  __syncthreads();
  for (int it = 0; it < 4; ++it) {
    int e = it * 256 + tid;
    float a = 0;
    for (int t2 = 0; t2 < 256; ++t2) a += wsm[t2] * sent[((size_t)b * 256 + t2) * 1024 + e];
    att[((size_t)j * 32 + b) * 1024 + e] = a;
  }
}

// ---------------- head ----------------
__global__ void feat_kernel(const float* s1, const float* s2, const float* s3,
                            const float* tok, const float* atop, const float* att, float* feat)
{
  int i = blockIdx.x * 256 + threadIdx.x;
  int b = i >> 13, jj = (i >> 10) & 7, d = i & 1023;
  int sidx = b * 1024 + d;
  float v;
  switch (jj) {
    case 0: v = s1[sidx]; break;
    case 1: v = s2[sidx]; break;
    case 2: v = s3[sidx]; break;
    case 3: v = tok[d]; break;
    case 4: v = atop[sidx]; break;
    default: v = att[((size_t)(jj - 5) * 32 + b) * 1024 + d];
  }
  feat[i] = v;
}
__global__ __launch_bounds__(256) void head_kernel(const float* feat, const float* W,
                                                   const float* bias, float* fbuf)
{
  int i = blockIdx.x * 256 + threadIdx.x;
  int b = i >> 9, h = i & 511;
  const float4* fr = (const float4*)(feat + (size_t)b * 8192);
  const float4* wr = (const float4*)(W + (size_t)h * 8192);
  float a0 = 0, a1 = 0, a2 = 0, a3 = 0;
  for (int k = 0; k < 2048; ++k) {
    float4 f = fr[k], ww = wr[k];
    a0 += f.x * ww.x; a1 += f.y * ww.y; a2 += f.z * ww.z; a3 += f.w * ww.w;
  }
  fbuf[i] = tanhf(bias[h] + ((a0 + a1) + (a2 + a3)));
}
__global__ void logits_kernel(const float* fbuf, const float* W, const float* bias, float* out)
{
  int b = blockIdx.x, tid = threadIdx.x;
  __shared__ float lg[20];
  __shared__ float mred, lsred;
  if (tid < 20) {
    const float* fr = fbuf + b * 512;
    const float* wr = W + tid * 512;
    float a = bias[tid];
    for (int k = 0; k < 512; ++k) a += fr[k] * wr[k];
    lg[tid] = a;
  }
  __syncthreads();
  if (tid == 0) {
    float m = lg[0];
    for (int i = 1; i < 20; ++i) m = fmaxf(m, lg[i]);
    float ssum = 0;
    for (int i = 0; i < 20; ++i) ssum += expf(lg[i] - m);
    mred = m; lsred = logf(ssum);
  }
  __syncthreads();
  if (tid < 20) out[b * 20 + tid] = lg[tid] - mred - lsred;
}

// ---------------- host ----------------
extern "C" void kernel_launch(void* const* d_in, const int* in_sizes, int n_in,
                              void* d_out, int out_size, void* d_ws, size_t ws_size,
                              hipStream_t stream)
{
  const float* sentence = (const float*)d_in[0];
  const int* actions = (const int*)d_in[1];
  const float* token_empty = (const float*)d_in[2];
  const float* leaf_Wi = (const float*)d_in[3];
  const float* leaf_bi = (const float*)d_in[4];
  const float* leaf_Wo = (const float*)d_in[5];
  const float* leaf_bo = (const float*)d_in[6];
  const float* lstm_Wih = (const float*)d_in[7];
  const float* lstm_Whh = (const float*)d_in[8];
  const float* lstm_bih = (const float*)d_in[9];
  const float* lstm_bhh = (const float*)d_in[10];
  const float* stack_h0 = (const float*)d_in[11];
  const float* stack_c0 = (const float*)d_in[12];
  const float* act_emb = (const float*)d_in[13];
  const float* act_Wih = (const float*)d_in[14];
  const float* act_Whh = (const float*)d_in[15];
  const float* act_bih = (const float*)d_in[16];
  const float* act_bhh = (const float*)d_in[17];
  const float* act_h0 = (const float*)d_in[18];
  const float* act_c0 = (const float*)d_in[19];
  const float* red_W = (const float*)d_in[20];
  const float* red_b = (const float*)d_in[21];
  const float* h2f_W = (const float*)d_in[22];
  const float* h2f_b = (const float*)d_in[23];
  const float* f2a_W = (const float*)d_in[24];
  const float* f2a_b = (const float*)d_in[25];
  const float* att_W = (const float*)d_in[26];
  float* out = (float*)d_out;
  (void)in_sizes; (void)n_in; (void)out_size; (void)ws_size;

  char* ws = (char*)d_ws;
  size_t off = 0;
  auto alloc = [&](size_t bytes) -> void* {
    void* ptr = ws + off;
    off += (bytes + 255) & ~(size_t)255;
    return ptr;
  };
  // ---- aliased arena (56 MB): phase 1 holds sent_bf|cell_f32|Wx_r (all dead
  // before init_states); phase 2 holds the three h-history buffers (50.5 MB).
  char* arena = (char*)alloc(58720256);
  __hip_bfloat16* sent_bf = (__hip_bfloat16*)arena;                 // 16 MB
  float* cell_f32 = (float*)(arena + 16777216);                     // 32 MB
  __hip_bfloat16* Wx_r = (__hip_bfloat16*)(arena + 50331648);       //  8 MB
  __hip_bfloat16* sh_hist = (__hip_bfloat16*)arena;                 // [257][32][1024]
  __hip_bfloat16* rh_hist = (__hip_bfloat16*)(arena + 16843008);
  __hip_bfloat16* ah_hist = (__hip_bfloat16*)(arena + 33686016);

  __hip_bfloat16* hid_bf  = (__hip_bfloat16*)alloc(16777216);   // [8192][1024] (t*32+b)
  __hip_bfloat16* lWi_bf = (__hip_bfloat16*)alloc(2097152);
  __hip_bfloat16* lWo_bf = (__hip_bfloat16*)alloc(2097152);
  __hip_bfloat16* Whh_s = (__hip_bfloat16*)alloc(8388608);
  __hip_bfloat16* Wih_s = (__hip_bfloat16*)alloc(8388608);
  __hip_bfloat16* Whh_r = (__hip_bfloat16*)alloc(8388608);
  __hip_bfloat16* Whh_a = (__hip_bfloat16*)alloc(8388608);
  __hip_bfloat16* xgs_blk = (__hip_bfloat16*)alloc(67108864);   // [64][256][2048]
  __hip_bfloat16* xgr_blk = (__hip_bfloat16*)alloc(67108864);
  __hip_bfloat16* cellblk = (__hip_bfloat16*)alloc(16777216);   // [64][256][512]
  float* table = (float*)alloc(327680);
  float* sbias = (float*)alloc(16384);
  float* s1 = (float*)alloc(131072);
  float* s2 = (float*)alloc(131072);
  float* s3 = (float*)alloc(131072);
  float* atop = (float*)alloc(131072);
  unsigned int* flags = (unsigned int*)alloc(16384);  // 3*64 flags, 64B apart
  float* qbuf = (float*)alloc(393216);
  float* attbuf = (float*)alloc(393216);
  float* feat = (float*)alloc(1048576);
  float* fbuf = (float*)alloc(65536);

  // conversions (phase 1 of arena) — vectorized 4 elems/thread
  cast4_kernel<<<8192, 256, 0, stream>>>(sent_bf, sentence, 2097152);
  cast4_kernel<<<1024, 256, 0, stream>>>(lWi_bf, leaf_Wi, 262144);
  cast4_kernel<<<1024, 256, 0, stream>>>(lWo_bf, leaf_Wo, 262144);
  cast4_kernel<<<4096, 256, 0, stream>>>(Whh_s, lstm_Whh, 1048576);
  cast4_kernel<<<4096, 256, 0, stream>>>(Wih_s, lstm_Wih, 1048576);
  cast4_kernel<<<4096, 256, 0, stream>>>(Whh_a, act_Whh, 1048576);
  extract_half4_kernel<<<4096, 256, 0, stream>>>(Whh_r, red_W, 1048576, 0);
  extract_half4_kernel<<<4096, 256, 0, stream>>>(Wx_r, red_W, 1048576, 1024);
  bias_kernel<<<16, 256, 0, stream>>>(sbias, lstm_bih, lstm_bhh, 4096);
  act_table_kernel<<<320, 256, 0, stream>>>(act_emb, act_Wih, act_bih, act_bhh, table);

  // leaf module (consumes sent_bf, produces+consumes cell_f32)
  gemm_bt_kernel<<<dim3(64, 8), 256, 0, stream>>>(sent_bf, lWi_bf, cell_f32, nullptr,
                                                  leaf_bi, nullptr, 8192, 1024, 1024, 1, 0);
  gemm_bt_kernel<<<dim3(64, 8), 256, 0, stream>>>(sent_bf, lWo_bf, nullptr, hid_bf,
                                                  leaf_bo, cell_f32, 8192, 1024, 1024, 1, 2);
  cellblk_kernel<<<256, 256, 0, stream>>>(cell_f32, cellblk);

  // precomputed x-gates in blk layout (bias folded); xg_r consumes Wx_r (arena)
  gemm_bt_kernel<<<dim3(64, 32), 256, 0, stream>>>(hid_bf, Wih_s, nullptr, xgs_blk,
                                                   sbias, nullptr, 8192, 4096, 1024, 0, 3);
  gemm_bt_kernel<<<dim3(64, 32), 256, 0, stream>>>(hid_bf, Wx_r, nullptr, xgr_blk,
                                                   red_b, nullptr, 8192, 4096, 1024, 0, 3);

  // phase 2 of arena begins: overwrite with history slot 0
  init_states_kernel<<<128, 256, 0, stream>>>(stack_h0, act_h0, hid_bf,
                                              sh_hist, ah_hist, rh_hist, flags);

  PP P;
  P.Whh_s = Whh_s; P.Wih_s = Wih_s; P.Whh_r = Whh_r; P.Whh_a = Whh_a;
  P.xgs_blk = xgs_blk; P.xgr_blk = xgr_blk; P.cellblk = cellblk;
  P.table = table; P.actions = actions;
  P.stack_c0 = stack_c0; P.act_c0 = act_c0; P.sbias = sbias;
  P.sh_hist = sh_hist; P.rh_hist = rh_hist; P.ah_hist = ah_hist;
  P.s1 = s1; P.s2 = s2; P.s3 = s3; P.atop = atop;
  P.flags = flags;
  scan_persist<<<192, 256, 0, stream>>>(P);

  // attention: s1, s2, s3
  att_q_kernel<<<dim3(4, 8, 3), 256, 0, stream>>>(s1, s2, s3, att_W, qbuf);
  att_sc_kernel<<<dim3(32, 3), 256, 0, stream>>>(qbuf, sentence, attbuf);

  // head
  feat_kernel<<<1024, 256, 0, stream>>>(s1, s2, s3, token_empty, atop, attbuf, feat);
  head_kernel<<<64, 256, 0, stream>>>(feat, h2f_W, h2f_b, fbuf);
  logits_kernel<<<32, 64, 0, stream>>>(fbuf, f2a_W, f2a_b, out);
}

// Round 15
// 2512.855 us; speedup vs baseline: 1.4879x; 1.0038x over previous
//
#include <hip/hip_runtime.h>
#include <hip/hip_bf16.h>
#include <math.h>

// B=32, T=256, D=1024, A=64, H=512, NA=20
#define DEV __device__ __forceinline__

typedef __bf16 bf16_t;
typedef bf16_t bf16x8 __attribute__((ext_vector_type(8)));
typedef float f32x4 __attribute__((ext_vector_type(4)));
typedef int i32x4 __attribute__((ext_vector_type(4)));

DEV void async16(const void* g, void* l) {
  __builtin_amdgcn_global_load_lds((const __attribute__((address_space(1))) void*)g,
                                   (__attribute__((address_space(3))) void*)l, 16, 0, 0);
}
DEV float sigmoidf_(float x) { return 1.f / (1.f + expf(-x)); }
DEV bf16x8 as_bf(i32x4 v) { union { i32x4 i; bf16x8 b; } u; u.i = v; return u.b; }

// ---- fine-grained device-coherent ops ----
DEV unsigned flag_load(const unsigned* p) {
  unsigned v;
  asm volatile("global_load_dword %0, %1, off sc0 sc1\ns_waitcnt vmcnt(0)"
               : "=v"(v) : "v"(p) : "memory");
  return v;
}
DEV void flag_store(unsigned* p, unsigned v) {
  asm volatile("global_store_dword %0, %1, off sc0 sc1" :: "v"(p), "v"(v) : "memory");
}
DEV void store16_sys(void* p, i32x4 v) {
  asm volatile("global_store_dwordx4 %0, %1, off sc0 sc1" :: "v"(p), "v"(v) : "memory");
}

#define WAITV(N) do { asm volatile("s_waitcnt vmcnt(" #N ")" ::: "memory"); \
                      __builtin_amdgcn_sched_barrier(0); } while (0)

template<int KB>
DEV void loads8(i32x4* dst, const __hip_bfloat16* arow) {
#pragma unroll
  for (int i = 0; i < 8; ++i)
    asm volatile("global_load_dwordx4 %0, %1, off offset:%2"
                 : "=v"(dst[i]) : "v"(arow), "i"((KB + i) * 64));
}
DEV void loads8rt(i32x4* dst, const __hip_bfloat16* arow, int kbase) {
#pragma unroll
  for (int i = 0; i < 8; ++i)
    asm volatile("global_load_dwordx4 %0, %1, off"
                 : "=v"(dst[i]) : "v"(arow + (size_t)(kbase + i) * 32) : "memory");
}

template<int C>
DEV void ldsb8(bf16x8* b0, bf16x8* b1, const __hip_bfloat16* Wl,
               int sw, int kof, int r0, int r1) {
#pragma unroll
  for (int i = 0; i < 8; ++i) {
    const int kk = (C * 8 + i) * 32 + kof;
    b0[i] = *(const bf16x8*)&Wl[r0 * 1024 + (kk ^ sw)];
    b1[i] = *(const bf16x8*)&Wl[r1 * 1024 + (kk ^ sw)];
  }
}
DEV void mfma8x(const i32x4* a, const bf16x8* b0, const bf16x8* b1,
                f32x4& acc0, f32x4& acc1) {
#pragma unroll
  for (int i = 0; i < 8; ++i) {
    bf16x8 av = as_bf(a[i]);
    acc0 = __builtin_amdgcn_mfma_f32_16x16x32_bf16(av, b0[i], acc0, 0, 0, 0);
    acc1 = __builtin_amdgcn_mfma_f32_16x16x32_bf16(av, b1[i], acc1, 0, 0, 0);
  }
}

// full-K step used only in the drained final phase (all vmcnt self-contained)
DEV void mfma_step(const __hip_bfloat16* Ap, const __hip_bfloat16* Wl,
                   int mh, int nh, int l, f32x4& acc0, f32x4& acc1) {
  const __hip_bfloat16* arow = Ap + (mh * 16 + (l & 15)) * 1024 + (l >> 4) * 8;
  const int sw = (l & 7) << 3, kof = (l >> 4) * 8;
  const int r0 = nh * 32 + (l & 15), r1 = r0 + 16;
  i32x4 A0[8], A1[8], A2[8], A3[8];
  bf16x8 Ba0[8], Ba1[8], Bb0[8], Bb1[8];
  loads8<0>(A0, arow);
  loads8<8>(A1, arow);
  loads8<16>(A2, arow);
  loads8<24>(A3, arow);
  ldsb8<0>(Ba0, Ba1, Wl, sw, kof, r0, r1);
  WAITV(24);
  mfma8x(A0, Ba0, Ba1, acc0, acc1);
  ldsb8<1>(Bb0, Bb1, Wl, sw, kof, r0, r1);
  WAITV(16);
  mfma8x(A1, Bb0, Bb1, acc0, acc1);
  ldsb8<2>(Ba0, Ba1, Wl, sw, kof, r0, r1);
  WAITV(8);
  mfma8x(A2, Ba0, Ba1, acc0, acc1);
  ldsb8<3>(Bb0, Bb1, Wl, sw, kof, r0, r1);
  WAITV(0);
  mfma8x(A3, Bb0, Bb1, acc0, acc1);
}

// final-phase pass: A cached loads, W from global (cached)
DEV void mfma_pass_glb(const __hip_bfloat16* Ap, const __hip_bfloat16* __restrict__ Wg,
                       int d0, int mh, int nh, int l, f32x4& acc0, f32x4& acc1) {
  const __hip_bfloat16* arow = Ap + (mh * 16 + (l & 15)) * 1024 + (l >> 4) * 8;
  const size_t g0 = ((size_t)(2 * nh) * 1024 + d0 + (l & 15)) * 1024;
  const size_t g1 = g0 + 1048576;
  const int kof = (l >> 4) * 8;
  i32x4 A[8];
  for (int c = 0; c < 4; ++c) {
    loads8rt(A, arow, c * 8);
    WAITV(0);
#pragma unroll
    for (int i = 0; i < 8; ++i) {
      const int kk = (c * 8 + i) * 32 + kof;
      bf16x8 b0 = *(const bf16x8*)&Wg[g0 + kk];
      bf16x8 b1 = *(const bf16x8*)&Wg[g1 + kk];
      bf16x8 av = as_bf(A[i]);
      acc0 = __builtin_amdgcn_mfma_f32_16x16x32_bf16(av, b0, acc0, 0, 0, 0);
      acc1 = __builtin_amdgcn_mfma_f32_16x16x32_bf16(av, b1, acc1, 0, 0, 0);
    }
  }
}

// ---------------- generic bf16 MFMA GEMM: C[M,N] = A[M,K] @ Bw[N,K]^T + bias ----------------
// mode 0: outF = acc+bias (f32); mode 1: outBF = bf16(acc+bias)
// mode 2: outBF = bf16(sigmoid(acc+bias)*tanh(aux))
// mode 3: outBF is blk layout [slot][256 t][2048] chunk [g*512 + b*16 + dd]; rows must be t*32+b
__global__ __launch_bounds__(256) void gemm_bt_kernel(
    const __hip_bfloat16* __restrict__ A, const __hip_bfloat16* __restrict__ Bw,
    float* __restrict__ outF, __hip_bfloat16* __restrict__ outBF,
    const float* __restrict__ bias, const float* __restrict__ aux,
    int M, int N, int K, int remap, int mode)
{
  __shared__ __hip_bfloat16 As[128 * 64];
  __shared__ __hip_bfloat16 Bs[128 * 64];
  __shared__ __hip_bfloat16 Cs[128 * 128];   // mode-3 staging only
  const int tid = threadIdx.x;
  const int w = tid >> 6, l = tid & 63;
  const int m0 = blockIdx.x * 128, n0 = blockIdx.y * 128;
  const int wm = (w >> 1) * 64, wn = (w & 1) * 64;
  const int row_s = tid >> 3, kc = tid & 7;
  f32x4 acc[4][4] = {};
  for (int k0 = 0; k0 < K; k0 += 64) {
    const __hip_bfloat16* ga = A + (size_t)(m0 + row_s) * K + k0 + kc * 8;
    const __hip_bfloat16* gb = Bw + (size_t)(n0 + row_s) * K + k0 + kc * 8;
    __hip_bfloat16* la = As + w * 512;
    __hip_bfloat16* lb = Bs + w * 512;
#pragma unroll
    for (int p = 0; p < 4; ++p) {
      async16(ga + (size_t)p * 32 * K, la + p * 2048);
      async16(gb + (size_t)p * 32 * K, lb + p * 2048);
    }
    __syncthreads();
#pragma unroll
    for (int kb = 0; kb < 2; ++kb) {
      bf16x8 af[4], bfr[4];
#pragma unroll
      for (int i = 0; i < 4; ++i)
        af[i] = *(const bf16x8*)&As[(wm + i * 16 + (l & 15)) * 64 + kb * 32 + (l >> 4) * 8];
#pragma unroll
      for (int j = 0; j < 4; ++j)
        bfr[j] = *(const bf16x8*)&Bs[(wn + j * 16 + (l & 15)) * 64 + kb * 32 + (l >> 4) * 8];
#pragma unroll
      for (int i = 0; i < 4; ++i)
#pragma unroll
        for (int j = 0; j < 4; ++j)
          acc[i][j] = __builtin_amdgcn_mfma_f32_16x16x32_bf16(af[i], bfr[j], acc[i][j], 0, 0, 0);
    }
    __syncthreads();
  }
  if (mode == 3) {
#pragma unroll
    for (int i = 0; i < 4; ++i)
#pragma unroll
      for (int j = 0; j < 4; ++j) {
        const int ncol = n0 + wn + j * 16 + (l & 15);
        const float bv = bias[ncol];
#pragma unroll
        for (int r = 0; r < 4; ++r) {
          const int lr = wm + i * 16 + (l >> 4) * 4 + r;
          Cs[lr * 128 + wn + j * 16 + (l & 15)] = __float2bfloat16(acc[i][j][r] + bv);
        }
      }
    __syncthreads();
    const int t0 = m0 >> 5, g = n0 >> 10, slot0 = (n0 & 1023) >> 4;
    const int grp = tid >> 6, li = tid & 63;
    const int b = li >> 1, half = li & 1;
#pragma unroll
    for (int sl = 0; sl < 8; ++sl) {
      bf16x8 vv = *(const bf16x8*)&Cs[(grp * 32 + b) * 128 + sl * 16 + half * 8];
      *(bf16x8*)&outBF[(((size_t)(slot0 + sl)) * 256 + t0 + grp) * 2048 +
                       g * 512 + b * 16 + half * 8] = vv;
    }
    return;
  }
#pragma unroll
  for (int i = 0; i < 4; ++i) {
#pragma unroll
    for (int j = 0; j < 4; ++j) {
      const int ncol = n0 + wn + j * 16 + (l & 15);
      const float bv = bias ? bias[ncol] : 0.f;
#pragma unroll
      for (int r = 0; r < 4; ++r) {
        int m = m0 + wm + i * 16 + (l >> 4) * 4 + r;
        int row = remap ? (((m & 255) << 5) | (m >> 8)) : m;
        float v = acc[i][j][r] + bv;
        if (mode == 0) {
          outF[(size_t)row * N + ncol] = v;
        } else if (mode == 1) {
          outBF[(size_t)row * N + ncol] = __float2bfloat16(v);
        } else {
          float cv = aux[(size_t)row * N + ncol];
          outBF[(size_t)row * N + ncol] = __float2bfloat16(sigmoidf_(v) * tanhf(cv));
        }
      }
    }
  }
}

// ---------------- fused leaf: cell = A@Wi^T+bi ; hid = bf16(sigmoid(A@Wo^T+bo)*tanh(cell))
// A staged ONCE for both GEMMs. Output rows remapped (b*256+t) -> (t*32+b).
__global__ __launch_bounds__(256) void leaf_fused_kernel(
    const __hip_bfloat16* __restrict__ A, const __hip_bfloat16* __restrict__ Wi,
    const __hip_bfloat16* __restrict__ Wo,
    const float* __restrict__ bi, const float* __restrict__ bo,
    float* __restrict__ cellF, __hip_bfloat16* __restrict__ hidBF)
{
  __shared__ __hip_bfloat16 As[128 * 64];
  __shared__ __hip_bfloat16 Bis[128 * 64];
  __shared__ __hip_bfloat16 Bos[128 * 64];
  const int tid = threadIdx.x;
  const int w = tid >> 6, l = tid & 63;
  const int m0 = blockIdx.x * 128, n0 = blockIdx.y * 128;
  const int wm = (w >> 1) * 64, wn = (w & 1) * 64;
  const int row_s = tid >> 3, kc = tid & 7;
  f32x4 ai[4][4] = {}, ao[4][4] = {};
  for (int k0 = 0; k0 < 1024; k0 += 64) {
    const __hip_bfloat16* ga = A + (size_t)(m0 + row_s) * 1024 + k0 + kc * 8;
    const __hip_bfloat16* gi = Wi + (size_t)(n0 + row_s) * 1024 + k0 + kc * 8;
    const __hip_bfloat16* go = Wo + (size_t)(n0 + row_s) * 1024 + k0 + kc * 8;
    __hip_bfloat16* la = As + w * 512;
    __hip_bfloat16* lbi = Bis + w * 512;
    __hip_bfloat16* lbo = Bos + w * 512;
#pragma unroll
    for (int p = 0; p < 4; ++p) {
      async16(ga + (size_t)p * 32 * 1024, la + p * 2048);
      async16(gi + (size_t)p * 32 * 1024, lbi + p * 2048);
      async16(go + (size_t)p * 32 * 1024, lbo + p * 2048);
    }
    __syncthreads();
#pragma unroll
    for (int kb = 0; kb < 2; ++kb) {
      bf16x8 af[4], bif[4], bof[4];
#pragma unroll
      for (int i = 0; i < 4; ++i)
        af[i] = *(const bf16x8*)&As[(wm + i * 16 + (l & 15)) * 64 + kb * 32 + (l >> 4) * 8];
#pragma unroll
      for (int j = 0; j < 4; ++j) {
        bif[j] = *(const bf16x8*)&Bis[(wn + j * 16 + (l & 15)) * 64 + kb * 32 + (l >> 4) * 8];
        bof[j] = *(const bf16x8*)&Bos[(wn + j * 16 + (l & 15)) * 64 + kb * 32 + (l >> 4) * 8];
      }
#pragma unroll
      for (int i = 0; i < 4; ++i)
#pragma unroll
        for (int j = 0; j < 4; ++j) {
          ai[i][j] = __builtin_amdgcn_mfma_f32_16x16x32_bf16(af[i], bif[j], ai[i][j], 0, 0, 0);
          ao[i][j] = __builtin_amdgcn_mfma_f32_16x16x32_bf16(af[i], bof[j], ao[i][j], 0, 0, 0);
        }
    }
    __syncthreads();
  }
#pragma unroll
  for (int i = 0; i < 4; ++i) {
#pragma unroll
    for (int j = 0; j < 4; ++j) {
      const int ncol = n0 + wn + j * 16 + (l & 15);
      const float bvi = bi[ncol], bvo = bo[ncol];
#pragma unroll
      for (int r = 0; r < 4; ++r) {
        int m = m0 + wm + i * 16 + (l >> 4) * 4 + r;
        int row = ((m & 255) << 5) | (m >> 8);
        float vi = ai[i][j][r] + bvi;
        float vo = ao[i][j][r] + bvo;
        cellF[(size_t)row * 1024 + ncol] = vi;
        hidBF[(size_t)row * 1024 + ncol] = __float2bfloat16(sigmoidf_(vo) * tanhf(vi));
      }
    }
  }
}

// cell [8192][1024] f32 (rows t*32+b) -> blk [64 slot][256 t][32 b][16 dd] bf16
__global__ __launch_bounds__(256) void cellblk_kernel(const float* __restrict__ cell,
                                                      __hip_bfloat16* __restrict__ blk)
{
  __shared__ __hip_bfloat16 ls[32 * 1024];   // 64 KB
  const int t = blockIdx.x, tid = threadIdx.x;
  for (int i = tid; i < 8192; i += 256) {
    float4 v = ((const float4*)(cell + (size_t)t * 32768))[i];
    __hip_bfloat16* d = &ls[i * 4];
    d[0] = __float2bfloat16(v.x); d[1] = __float2bfloat16(v.y);
    d[2] = __float2bfloat16(v.z); d[3] = __float2bfloat16(v.w);
  }
  __syncthreads();
  const int e = tid * 2;
  const int b = e >> 4, dd = e & 15;
  for (int sl = 0; sl < 64; ++sl) {
    union { __hip_bfloat16 h[2]; unsigned u; } pk;
    pk.h[0] = ls[b * 1024 + sl * 16 + dd];
    pk.h[1] = ls[b * 1024 + sl * 16 + dd + 1];
    *(unsigned*)&blk[((size_t)sl * 256 + t) * 512 + e] = pk.u;
  }
}

// ---------------- persistent scan ----------------
struct PP {
  const __hip_bfloat16 *Whh_s, *Wih_s, *Whh_r, *Whh_a;  // [4096][1024]
  const __hip_bfloat16 *xgs_blk, *xgr_blk;  // [64][256][2048] blk-layout x-gates
  const __hip_bfloat16* cellblk; // [64][256][512] blk-layout bf16 cell
  const float* table;            // [20][4096]
  const int* actions;            // [32][256]
  const float *stack_c0, *act_c0, *sbias;
  __hip_bfloat16 *sh_hist, *rh_hist, *ah_hist;  // [257][32][1024] h history
  float *s1, *s2, *s3, *atop;    // [32][1024] f32
  unsigned int* flags;           // [scan*1024 + slot*16]: per-block flags, 64B apart
};

__global__ __launch_bounds__(256, 1) void scan_persist(PP P)
{
  __shared__ __hip_bfloat16 Wl[64 * 1024];             // 128 KB, XOR-swizzled
  __shared__ float gsm2[4][32][17];                    // gate exchange, conflict-free layout
  __shared__ __align__(16) __hip_bfloat16 hstage[32][16];  // 1 KB packed h staging
  const int bid = blockIdx.x;
  const int scan = bid >> 6;                 // 0 stack, 1 reduce, 2 action
  const int slot = bid & 63;
  const int d0 = slot * 16;
  const int tid = threadIdx.x;
  const int l = tid & 63, w = tid >> 6;
  const int mh = w >> 1, nh = w & 1;

  const __hip_bfloat16* Wg = (scan == 0) ? P.Whh_s : ((scan == 1) ? P.Whh_r : P.Whh_a);
  for (int idx = tid; idx < 64 * 128; idx += 256) {
    int r = idx >> 7, k = (idx & 127) * 8;
    int grow = ((r >> 4) << 10) + d0 + (r & 15);
    bf16x8 v = *(const bf16x8*)&Wg[(size_t)grow * 1024 + k];
    *(bf16x8*)&Wl[r * 1024 + (k ^ ((r & 7) << 3))] = v;
  }
  const int e0 = tid, e1 = tid + 256;
  const int b0_ = e0 >> 4, dd0 = e0 & 15, b1_ = e1 >> 4, dd1 = e1 & 15;
  float creg0, creg1;
  if (scan == 0)      { creg0 = P.stack_c0[d0 + dd0]; creg1 = P.stack_c0[d0 + dd1]; }
  else if (scan == 1) {
    creg0 = __bfloat162float(P.cellblk[(size_t)slot * 256 * 512 + b0_ * 16 + dd0]);
    creg1 = __bfloat162float(P.cellblk[(size_t)slot * 256 * 512 + b1_ * 16 + dd1]);
  }
  else                { creg0 = P.act_c0[d0 + dd0]; creg1 = P.act_c0[d0 + dd1]; }
  __syncthreads();

  __hip_bfloat16* hist = (scan == 0) ? P.sh_hist : ((scan == 1) ? P.rh_hist : P.ah_hist);
  unsigned int* Fb = P.flags + scan * 1024;   // 64 flags, 64B apart
  const int Ns = (scan == 1) ? 255 : 256;
  const int mbase = mh * 16 + (l >> 4) * 4;
  const int sw = (l & 7) << 3, kof = (l >> 4) * 8;
  const int r0 = nh * 32 + (l & 15), r1 = r0 + 16;

  for (int s = 0; s < Ns; ++s) {
    const __hip_bfloat16* Ap = hist + (size_t)s * 32768;
    __hip_bfloat16* Hout = hist + (size_t)(s + 1) * 32768;

    // ---- prefix gate prefetch: plain loads, compiler-managed waits ----
    __hip_bfloat16 pg0, pg1, pg2, pg3, pg4, pg5, pg6, pg7;
    __hip_bfloat16 pcb0, pcb1;
    int pa0 = 0, pa1 = 0;
    pg0 = pg1 = pg2 = pg3 = pg4 = pg5 = pg6 = pg7 = __float2bfloat16(0.f);
    pcb0 = pcb1 = __float2bfloat16(0.f);
    if (scan == 0) {
      const __hip_bfloat16* x0 = P.xgs_blk + ((size_t)slot * 256 + s) * 2048 + b0_ * 16 + dd0;
      const __hip_bfloat16* x1 = P.xgs_blk + ((size_t)slot * 256 + s) * 2048 + b1_ * 16 + dd1;
      pg0 = x0[0]; pg1 = x0[512]; pg2 = x0[1024]; pg3 = x0[1536];
      pg4 = x1[0]; pg5 = x1[512]; pg6 = x1[1024]; pg7 = x1[1536];
    } else if (scan == 1) {
      const __hip_bfloat16* x0 = P.xgr_blk + ((size_t)slot * 256 + s + 1) * 2048 + b0_ * 16 + dd0;
      const __hip_bfloat16* x1 = P.xgr_blk + ((size_t)slot * 256 + s + 1) * 2048 + b1_ * 16 + dd1;
      pg0 = x0[0]; pg1 = x0[512]; pg2 = x0[1024]; pg3 = x0[1536];
      pg4 = x1[0]; pg5 = x1[512]; pg6 = x1[1024]; pg7 = x1[1536];
      pcb0 = P.cellblk[((size_t)slot * 256 + s + 1) * 512 + b0_ * 16 + dd0];
      pcb1 = P.cellblk[((size_t)slot * 256 + s + 1) * 512 + b1_ * 16 + dd1];
    } else {
      pa0 = P.actions[b0_ * 256 + s];
      pa1 = P.actions[b1_ * 256 + s];
    }
    __builtin_amdgcn_sched_barrier(0);

    // ---- barrier phase A: slots 0-31 (h d 0..511 of hist[s] ready) ----
    if (s > 0 && tid < 32) {
      const unsigned tgt = (unsigned)s;
      if (flag_load(Fb + tid * 16) < tgt)
        while (flag_load(Fb + tid * 16) < tgt) __builtin_amdgcn_s_sleep(1);
    }
    __syncthreads();

    // issue A-loads for k 0..511 (covered by slots 0-31)
    const __hip_bfloat16* arow = Ap + (mh * 16 + (l & 15)) * 1024 + kof;
    i32x4 A0[8], A1[8], A2[8], A3[8];
    loads8<0>(A0, arow);
    loads8<8>(A1, arow);

    // ---- barrier phase B: slots 32-63; poll's vmcnt(0) drains A0/A1 in parallel ----
    if (s > 0 && tid < 32) {
      const unsigned tgt = (unsigned)s;
      if (flag_load(Fb + (32 + tid) * 16) < tgt)
        while (flag_load(Fb + (32 + tid) * 16) < tgt) __builtin_amdgcn_s_sleep(1);
    }
    __syncthreads();
    WAITV(0);                        // all lanes: A0/A1 resident
    loads8<16>(A2, arow);
    loads8<24>(A3, arow);

    f32x4 acc0 = {}, acc1 = {};
    bf16x8 Ba0[8], Ba1[8], Bb0[8], Bb1[8];
    ldsb8<0>(Ba0, Ba1, Wl, sw, kof, r0, r1);
    mfma8x(A0, Ba0, Ba1, acc0, acc1);
    ldsb8<1>(Bb0, Bb1, Wl, sw, kof, r0, r1);
    mfma8x(A1, Bb0, Bb1, acc0, acc1);
    ldsb8<2>(Ba0, Ba1, Wl, sw, kof, r0, r1);
    WAITV(8);
    mfma8x(A2, Ba0, Ba1, acc0, acc1);
    ldsb8<3>(Bb0, Bb1, Wl, sw, kof, r0, r1);
    WAITV(0);
    mfma8x(A3, Bb0, Bb1, acc0, acc1);

#pragma unroll
    for (int r = 0; r < 4; ++r) {
      gsm2[nh * 2 + 0][mbase + r][l & 15] = acc0[r];
      gsm2[nh * 2 + 1][mbase + r][l & 15] = acc1[r];
    }
    __syncthreads();
#pragma unroll
    for (int q = 0; q < 2; ++q) {
      const int b = q ? b1_ : b0_, dd = q ? dd1 : dd0;
      const int d = d0 + dd;
      float& creg = q ? creg1 : creg0;
      float g0 = gsm2[0][b][dd], g1 = gsm2[1][b][dd], g2 = gsm2[2][b][dd], g3 = gsm2[3][b][dd];
      if (scan == 1) {
        float ig = sigmoidf_(g0 + __bfloat162float(q ? pg4 : pg0));
        float lg = sigmoidf_(g1 + __bfloat162float(q ? pg5 : pg1));
        float rg = sigmoidf_(g2 + __bfloat162float(q ? pg6 : pg2));
        float cand = tanhf(g3 + __bfloat162float(q ? pg7 : pg3));
        float rcv = __bfloat162float(q ? pcb1 : pcb0);
        float c2 = ig * cand + lg * creg + rg * rcv;
        creg = c2;
        hstage[b][dd] = __float2bfloat16(tanhf(c2));
      } else {
        float bi0, bi1, bi2, bi3;
        if (scan == 0) {
          bi0 = __bfloat162float(q ? pg4 : pg0); bi1 = __bfloat162float(q ? pg5 : pg1);
          bi2 = __bfloat162float(q ? pg6 : pg2); bi3 = __bfloat162float(q ? pg7 : pg3);
        } else {
          int a = q ? pa1 : pa0;
          const float* tb = P.table + a * 4096;
          bi0 = tb[d]; bi1 = tb[1024 + d]; bi2 = tb[2048 + d]; bi3 = tb[3072 + d];
        }
        float c2 = sigmoidf_(g1 + bi1) * creg + sigmoidf_(g0 + bi0) * tanhf(g2 + bi2);
        float h2 = sigmoidf_(g3 + bi3) * tanhf(c2);
        creg = c2;
        hstage[b][dd] = __float2bfloat16(h2);
        if (scan == 0 && s == 254) P.s3[b * 1024 + d] = h2;
        if (scan == 0 && s == 255) P.s2[b * 1024 + d] = h2;
        if (scan == 2 && s == 255) P.atop[b * 1024 + d] = h2;
      }
    }
    __syncthreads();
    // ---- packed 16B device-coherent h stores (wave 0 only) ----
    if (tid < 64) {
      const int bb = tid >> 1, hf = tid & 1;
      union { bf16x8 b8; i32x4 i4; } u;
      u.b8 = *(const bf16x8*)&hstage[bb][hf * 8];
      store16_sys(Hout + bb * 1024 + d0 + hf * 8, u.i4);
    }
    asm volatile("s_waitcnt vmcnt(0)" ::: "memory");
    __syncthreads();
    if (tid == 0) flag_store(Fb + slot * 16, (unsigned)(s + 1));
  }

  if (scan == 0) {
    // need all stack flags == 256 (sh_hist[256] complete) and reduce flags == 255
    if (tid < 64) {
      while (flag_load(P.flags + tid * 16) < 256u) __builtin_amdgcn_s_sleep(1);
      while (flag_load(P.flags + 1024 + tid * 16) < 255u) __builtin_amdgcn_s_sleep(1);
    }
    __syncthreads();
    f32x4 acc0 = {}, acc1 = {};
    mfma_step(P.sh_hist + (size_t)256 * 32768, Wl, mh, nh, l, acc0, acc1);       // hf @ Whh^T
    mfma_pass_glb(P.rh_hist + (size_t)255 * 32768, P.Wih_s, d0, mh, nh, l, acc0, acc1); // red_h @ Wih^T
#pragma unroll
    for (int r = 0; r < 4; ++r) {
      gsm2[nh * 2 + 0][mbase + r][l & 15] = acc0[r];
      gsm2[nh * 2 + 1][mbase + r][l & 15] = acc1[r];
    }
    __syncthreads();
#pragma unroll
    for (int q = 0; q < 2; ++q) {
      const int b = q ? b1_ : b0_, dd = q ? dd1 : dd0;
      const int d = d0 + dd;
      float creg = q ? creg1 : creg0;   // cf
      float g0 = gsm2[0][b][dd], g1 = gsm2[1][b][dd], g2 = gsm2[2][b][dd], g3 = gsm2[3][b][dd];
      float bi0 = P.sbias[d], bi1 = P.sbias[1024 + d], bi2 = P.sbias[2048 + d], bi3 = P.sbias[3072 + d];
      float c2 = sigmoidf_(g1 + bi1) * creg + sigmoidf_(g0 + bi0) * tanhf(g2 + bi2);
      float h2 = sigmoidf_(g3 + bi3) * tanhf(c2);
      P.s1[b * 1024 + d] = h2;
    }
  }
}

// ---------------- small utility kernels ----------------
__global__ void cast4_kernel(__hip_bfloat16* dst, const float* src, int n4) {
  int i = blockIdx.x * 256 + threadIdx.x;
  if (i < n4) {
    float4 v = ((const float4*)src)[i];
    union { __hip_bfloat16 h[4]; unsigned long long u; } pk;
    pk.h[0] = __float2bfloat16(v.x); pk.h[1] = __float2bfloat16(v.y);
    pk.h[2] = __float2bfloat16(v.z); pk.h[3] = __float2bfloat16(v.w);
    *(unsigned long long*)&dst[i * 4] = pk.u;
  }
}
__global__ void extract_half4_kernel(__hip_bfloat16* dst, const float* src, int n4,
                                     int src_off) {
  int i = blockIdx.x * 256 + threadIdx.x;   // n4 = 4096*1024/4
  if (i < n4) {
    int r = i >> 8, k4 = i & 255;
    float4 v = *(const float4*)(src + (size_t)r * 2048 + src_off + k4 * 4);
    union { __hip_bfloat16 h[4]; unsigned long long u; } pk;
    pk.h[0] = __float2bfloat16(v.x); pk.h[1] = __float2bfloat16(v.y);
    pk.h[2] = __float2bfloat16(v.z); pk.h[3] = __float2bfloat16(v.w);
    *(unsigned long long*)&dst[i * 4] = pk.u;
  }
}
__global__ void bias_kernel(float* dst, const float* a, const float* b, int n) {
  int i = blockIdx.x * 256 + threadIdx.x;
  if (i < n) dst[i] = a[i] + b[i];
}
__global__ void act_table_kernel(const float* emb, const float* Wih, const float* bih,
                                 const float* bhh, float* table) {
  int i = blockIdx.x * 256 + threadIdx.x;
  int a = i >> 12, n = i & 4095;
  float acc = bih[n] + bhh[n];
  const float* er = emb + a * 64;
  const float* wr = Wih + (size_t)n * 64;
  for (int k = 0; k < 64; ++k) acc += er[k] * wr[k];
  table[i] = acc;
}
__global__ void init_states_kernel(const float* stack_h0, const float* act_h0,
                                   const __hip_bfloat16* hid,
                                   __hip_bfloat16* sh0, __hip_bfloat16* ah0,
                                   __hip_bfloat16* rh0, unsigned int* flags)
{
  int i = blockIdx.x * 256 + threadIdx.x;  // 32768
  int d = i & 1023;
  sh0[i] = __float2bfloat16(stack_h0[d]);
  ah0[i] = __float2bfloat16(act_h0[d]);
  rh0[i] = hid[i];
  if (i < 4096) flags[i] = 0u;
}

// ---------------- attention ----------------
__global__ __launch_bounds__(256) void att_q_kernel(
    const float* s1, const float* s2, const float* s3, const float* attW, float* q)
{
  int eb = blockIdx.x, bg = blockIdx.y, j = blockIdx.z;
  const float* sj = (j == 0) ? s1 : ((j == 1) ? s2 : s3);
  __shared__ float ls[4][1024];
  int tid = threadIdx.x;
  for (int i = tid; i < 4096; i += 256)
    ls[i >> 10][i & 1023] = sj[(size_t)(bg * 4 + (i >> 10)) * 1024 + (i & 1023)];
  __syncthreads();
  int e = eb * 256 + tid;
  const float* Wj = attW + (size_t)j * 1024 * 1024;
  float a0 = 0, a1 = 0, a2 = 0, a3 = 0;
  for (int d = 0; d < 1024; ++d) {
    float wv = Wj[(size_t)d * 1024 + e];
    a0 += ls[0][d] * wv; a1 += ls[1][d] * wv; a2 += ls[2][d] * wv; a3 += ls[3][d] * wv;
  }
  q[((size_t)j * 32 + bg * 4 + 0) * 1024 + e] = a0;
  q[((size_t)j * 32 + bg * 4 + 1) * 1024 + e] = a1;
  q[((size_t)j * 32 + bg * 4 + 2) * 1024 + e] = a2;
  q[((size_t)j * 32 + bg * 4 + 3) * 1024 + e] = a3;
}

__global__ __launch_bounds__(256) void att_sc_kernel(const float* q, const float* sent, float* att)
{
  int b = blockIdx.x, j = blockIdx.y;
  __shared__ float qs[1024];
  __shared__ float wsm[256];
  __shared__ float red[8];
  int tid = threadIdx.x, w = tid >> 6, l = tid & 63;
  for (int i = tid; i < 1024; i += 256) qs[i] = q[((size_t)j * 32 + b) * 1024 + i];
  __syncthreads();
  const float4* sp = (const float4*)(sent + ((size_t)b * 256 + tid) * 1024);
  const float4* qs4 = (const float4*)qs;
  float dot = 0;
  for (int k = 0; k < 256; ++k) {
    float4 s4 = sp[k], q4 = qs4[k];
    dot += s4.x * q4.x + s4.y * q4.y + s4.z * q4.z + s4.w * q4.w;
  }
  float v = dot;
  for (int off = 32; off; off >>= 1) v = fmaxf(v, __shfl_xor(v, off));
  if (l == 0) red[w] = v;
  __syncthreads();
  float m = fmaxf(fmaxf(red[0], red[1]), fmaxf(red[2], red[3]));
  float ex = expf(dot - m);
  float sv = ex;
  for (int off = 32; off; off >>= 1) sv += __shfl_xor(sv, off);
  if (l == 0) red[4 + w] = sv;
  __syncthreads();
  float ssum = red[4] + red[5] + red[6] + red[7];
  wsm[tid] = ex / ssum;
  __syncthreads();
  for (int it = 0; it < 4; ++it) {
    int e = it * 256 + tid;
    float a = 0;
    for (int t2 = 0; t2 < 256; ++t2) a += wsm[t2] * sent[((size_t)b * 256 + t2) * 1024 + e];
    att[((size_t)j * 32 + b) * 1024 + e] = a;
  }
}

// ---------------- head ----------------
__global__ void feat_kernel(const float* s1, const float* s2, const float* s3,
                            const float* tok, const float* atop, const float* att, float* feat)
{
  int i = blockIdx.x * 256 + threadIdx.x;
  int b = i >> 13, jj = (i >> 10) & 7, d = i & 1023;
  int sidx = b * 1024 + d;
  float v;
  switch (jj) {
    case 0: v = s1[sidx]; break;
    case 1: v = s2[sidx]; break;
    case 2: v = s3[sidx]; break;
    case 3: v = tok[d]; break;
    case 4: v = atop[sidx]; break;
    default: v = att[((size_t)(jj - 5) * 32 + b) * 1024 + d];
  }
  feat[i] = v;
}
__global__ __launch_bounds__(256) void head_kernel(const float* feat, const float* W,
                                                   const float* bias, float* fbuf)
{
  int i = blockIdx.x * 256 + threadIdx.x;
  int b = i >> 9, h = i & 511;
  const float4* fr = (const float4*)(feat + (size_t)b * 8192);
  const float4* wr = (const float4*)(W + (size_t)h * 8192);
  float a0 = 0, a1 = 0, a2 = 0, a3 = 0;
  for (int k = 0; k < 2048; ++k) {
    float4 f = fr[k], ww = wr[k];
    a0 += f.x * ww.x; a1 += f.y * ww.y; a2 += f.z * ww.z; a3 += f.w * ww.w;
  }
  fbuf[i] = tanhf(bias[h] + ((a0 + a1) + (a2 + a3)));
}
__global__ void logits_kernel(const float* fbuf, const float* W, const float* bias, float* out)
{
  int b = blockIdx.x, tid = threadIdx.x;
  __shared__ float lg[20];
  __shared__ float mred, lsred;
  if (tid < 20) {
    const float* fr = fbuf + b * 512;
    const float* wr = W + tid * 512;
    float a = bias[tid];
    for (int k = 0; k < 512; ++k) a += fr[k] * wr[k];
    lg[tid] = a;
  }
  __syncthreads();
  if (tid == 0) {
    float m = lg[0];
    for (int i = 1; i < 20; ++i) m = fmaxf(m, lg[i]);
    float ssum = 0;
    for (int i = 0; i < 20; ++i) ssum += expf(lg[i] - m);
    mred = m; lsred = logf(ssum);
  }
  __syncthreads();
  if (tid < 20) out[b * 20 + tid] = lg[tid] - mred - lsred;
}

// ---------------- host ----------------
extern "C" void kernel_launch(void* const* d_in, const int* in_sizes, int n_in,
                              void* d_out, int out_size, void* d_ws, size_t ws_size,
                              hipStream_t stream)
{
  const float* sentence = (const float*)d_in[0];
  const int* actions = (const int*)d_in[1];
  const float* token_empty = (const float*)d_in[2];
  const float* leaf_Wi = (const float*)d_in[3];
  const float* leaf_bi = (const float*)d_in[4];
  const float* leaf_Wo = (const float*)d_in[5];
  const float* leaf_bo = (const float*)d_in[6];
  const float* lstm_Wih = (const float*)d_in[7];
  const float* lstm_Whh = (const float*)d_in[8];
  const float* lstm_bih = (const float*)d_in[9];
  const float* lstm_bhh = (const float*)d_in[10];
  const float* stack_h0 = (const float*)d_in[11];
  const float* stack_c0 = (const float*)d_in[12];
  const float* act_emb = (const float*)d_in[13];
  const float* act_Wih = (const float*)d_in[14];
  const float* act_Whh = (const float*)d_in[15];
  const float* act_bih = (const float*)d_in[16];
  const float* act_bhh = (const float*)d_in[17];
  const float* act_h0 = (const float*)d_in[18];
  const float* act_c0 = (const float*)d_in[19];
  const float* red_W = (const float*)d_in[20];
  const float* red_b = (const float*)d_in[21];
  const float* h2f_W = (const float*)d_in[22];
  const float* h2f_b = (const float*)d_in[23];
  const float* f2a_W = (const float*)d_in[24];
  const float* f2a_b = (const float*)d_in[25];
  const float* att_W = (const float*)d_in[26];
  float* out = (float*)d_out;
  (void)in_sizes; (void)n_in; (void)out_size; (void)ws_size;

  char* ws = (char*)d_ws;
  size_t off = 0;
  auto alloc = [&](size_t bytes) -> void* {
    void* ptr = ws + off;
    off += (bytes + 255) & ~(size_t)255;
    return ptr;
  };
  // ---- aliased arena (56 MB): phase 1 holds sent_bf|cell_f32|Wx_r (all dead
  // before init_states); phase 2 holds the three h-history buffers (50.5 MB).
  char* arena = (char*)alloc(58720256);
  __hip_bfloat16* sent_bf = (__hip_bfloat16*)arena;                 // 16 MB
  float* cell_f32 = (float*)(arena + 16777216);                     // 32 MB
  __hip_bfloat16* Wx_r = (__hip_bfloat16*)(arena + 50331648);       //  8 MB
  __hip_bfloat16* sh_hist = (__hip_bfloat16*)arena;                 // [257][32][1024]
  __hip_bfloat16* rh_hist = (__hip_bfloat16*)(arena + 16843008);
  __hip_bfloat16* ah_hist = (__hip_bfloat16*)(arena + 33686016);

  __hip_bfloat16* hid_bf  = (__hip_bfloat16*)alloc(16777216);   // [8192][1024] (t*32+b)
  __hip_bfloat16* lWi_bf = (__hip_bfloat16*)alloc(2097152);
  __hip_bfloat16* lWo_bf = (__hip_bfloat16*)alloc(2097152);
  __hip_bfloat16* Whh_s = (__hip_bfloat16*)alloc(8388608);
  __hip_bfloat16* Wih_s = (__hip_bfloat16*)alloc(8388608);
  __hip_bfloat16* Whh_r = (__hip_bfloat16*)alloc(8388608);
  __hip_bfloat16* Whh_a = (__hip_bfloat16*)alloc(8388608);
  __hip_bfloat16* xgs_blk = (__hip_bfloat16*)alloc(67108864);   // [64][256][2048]
  __hip_bfloat16* xgr_blk = (__hip_bfloat16*)alloc(67108864);
  __hip_bfloat16* cellblk = (__hip_bfloat16*)alloc(16777216);   // [64][256][512]
  float* table = (float*)alloc(327680);
  float* sbias = (float*)alloc(16384);
  float* s1 = (float*)alloc(131072);
  float* s2 = (float*)alloc(131072);
  float* s3 = (float*)alloc(131072);
  float* atop = (float*)alloc(131072);
  unsigned int* flags = (unsigned int*)alloc(16384);  // 3*64 flags, 64B apart
  float* qbuf = (float*)alloc(393216);
  float* attbuf = (float*)alloc(393216);
  float* feat = (float*)alloc(1048576);
  float* fbuf = (float*)alloc(65536);

  // conversions (phase 1 of arena) — vectorized 4 elems/thread
  cast4_kernel<<<8192, 256, 0, stream>>>(sent_bf, sentence, 2097152);
  cast4_kernel<<<1024, 256, 0, stream>>>(lWi_bf, leaf_Wi, 262144);
  cast4_kernel<<<1024, 256, 0, stream>>>(lWo_bf, leaf_Wo, 262144);
  cast4_kernel<<<4096, 256, 0, stream>>>(Whh_s, lstm_Whh, 1048576);
  cast4_kernel<<<4096, 256, 0, stream>>>(Wih_s, lstm_Wih, 1048576);
  cast4_kernel<<<4096, 256, 0, stream>>>(Whh_a, act_Whh, 1048576);
  extract_half4_kernel<<<4096, 256, 0, stream>>>(Whh_r, red_W, 1048576, 0);
  extract_half4_kernel<<<4096, 256, 0, stream>>>(Wx_r, red_W, 1048576, 1024);
  bias_kernel<<<16, 256, 0, stream>>>(sbias, lstm_bih, lstm_bhh, 4096);
  act_table_kernel<<<320, 256, 0, stream>>>(act_emb, act_Wih, act_bih, act_bhh, table);

  // fused leaf module: one A-pass produces cell (f32) and hid (bf16)
  leaf_fused_kernel<<<dim3(64, 8), 256, 0, stream>>>(sent_bf, lWi_bf, lWo_bf,
                                                     leaf_bi, leaf_bo, cell_f32, hid_bf);
  cellblk_kernel<<<256, 256, 0, stream>>>(cell_f32, cellblk);

  // precomputed x-gates in blk layout (bias folded); xg_r consumes Wx_r (arena)
  gemm_bt_kernel<<<dim3(64, 32), 256, 0, stream>>>(hid_bf, Wih_s, nullptr, xgs_blk,
                                                   sbias, nullptr, 8192, 4096, 1024, 0, 3);
  gemm_bt_kernel<<<dim3(64, 32), 256, 0, stream>>>(hid_bf, Wx_r, nullptr, xgr_blk,
                                                   red_b, nullptr, 8192, 4096, 1024, 0, 3);

  // phase 2 of arena begins: overwrite with history slot 0
  init_states_kernel<<<128, 256, 0, stream>>>(stack_h0, act_h0, hid_bf,
                                              sh_hist, ah_hist, rh_hist, flags);

  PP P;
  P.Whh_s = Whh_s; P.Wih_s = Wih_s; P.Whh_r = Whh_r; P.Whh_a = Whh_a;
  P.xgs_blk = xgs_blk; P.xgr_blk = xgr_blk; P.cellblk = cellblk;
  P.table = table; P.actions = actions;
  P.stack_c0 = stack_c0; P.act_c0 = act_c0; P.sbias = sbias;
  P.sh_hist = sh_hist; P.rh_hist = rh_hist; P.ah_hist = ah_hist;
  P.s1 = s1; P.s2 = s2; P.s3 = s3; P.atop = atop;
  P.flags = flags;
  scan_persist<<<192, 256, 0, stream>>>(P);

  // attention: s1, s2, s3
  att_q_kernel<<<dim3(4, 8, 3), 256, 0, stream>>>(s1, s2, s3, att_W, qbuf);
  att_sc_kernel<<<dim3(32, 3), 256, 0, stream>>>(qbuf, sentence, attbuf);

  // head
  feat_kernel<<<1024, 256, 0, stream>>>(s1, s2, s3, token_empty, atop, attbuf, feat);
  head_kernel<<<64, 256, 0, stream>>>(feat, h2f_W, h2f_b, fbuf);
  logits_kernel<<<32, 64, 0, stream>>>(fbuf, f2a_W, f2a_b, out);
}